// Round 2
// baseline (1715.700 us; speedup 1.0000x reference)
//
#include <hip/hip_runtime.h>
#include <cstdint>
#include <cstddef>

typedef unsigned short u16;

#define DEV __device__ __forceinline__

DEV float bf2f(u16 u){ union{unsigned int i; float f;} c; c.i = ((unsigned)u)<<16; return c.f; }
DEV u16 f2bf(float f){ union{float f;unsigned int i;} c; c.f=f; unsigned int r = c.i + 0x7FFFu + ((c.i>>16)&1u); return (u16)(r>>16); }

// ---------------- workspace layout (bytes) ----------------
static constexpr size_t OFF_SCORE = 0;                                   // [128][1024] f32
static constexpr size_t OFF_XW    = OFF_SCORE + (size_t)128*1024*4;      // [128][16] f32
static constexpr size_t OFF_WHX1  = OFF_XW    + (size_t)128*16*4;        // [128][1200] f32
static constexpr size_t OFF_WHX2  = OFF_WHX1  + (size_t)128*1200*4;      // [128][1600] f32
static constexpr size_t OFF_O1600 = OFF_WHX2  + (size_t)128*1600*4;      // [128][1600] f32
static constexpr size_t OFF_WHX3  = OFF_O1600 + (size_t)128*1600*4;      // [128][1200] f32
static constexpr size_t OFF_W21   = OFF_WHX3  + (size_t)128*1200*4;      // conv1 w [ci][9][co] f32
static constexpr size_t OFF_W22   = OFF_W21   + (size_t)1*32*9*4;
static constexpr size_t OFF_W23   = OFF_W22   + (size_t)32*64*9*4;
static constexpr size_t OFF_W24   = OFF_W23   + (size_t)64*64*9*4;
static constexpr size_t OFF_W25   = OFF_W24   + (size_t)64*64*9*4;
static constexpr size_t OFF_W26   = OFF_W25   + (size_t)64*32*9*4;
static constexpr size_t OFF_PAR   = OFF_W26   + (size_t)32*1*9*4;        // 6 x 768B: bias/scale/beta f32
// ---- zero-initialized region starts here ----
static constexpr size_t OFF_HT    = OFF_PAR   + (size_t)6*768;           // [128][300] f32 (atomic acc)
static constexpr size_t OFF_CT    = OFF_HT    + (size_t)128*300*4;       // [128][300] f32
static constexpr size_t OFF_A32   = OFF_CT    + (size_t)128*300*4;       // [128][42*42][32] bf16
static constexpr size_t OFF_B64   = OFF_A32   + (size_t)128*1764*32*2;   // [128][42*42][64] bf16
static constexpr size_t OFF_C64   = OFF_B64   + (size_t)128*1764*64*2;   // [128][42*42][64] bf16
static constexpr size_t OFF_P0    = OFF_C64   + (size_t)128*1764*64*2;   // [128][42*42] bf16 (pre, padded)
static constexpr size_t OFF_Y6    = OFF_P0    + (size_t)128*1764*2;      // [128][42*42] bf16 (c6 out, padded)
static constexpr size_t OFF_END   = OFF_Y6    + (size_t)128*1764*2;
static constexpr size_t ZERO_BYTES = OFF_END - OFF_HT;

// ---------------- zero init ----------------
__global__ void zero_k(uint4* __restrict__ p, size_t n){
  size_t i = (size_t)blockIdx.x*blockDim.x + threadIdx.x;
  uint4 z; z.x=0; z.y=0; z.z=0; z.w=0;
  for (; i < n; i += (size_t)gridDim.x*blockDim.x) p[i] = z;
}

// ---------------- xW[b][k] = sum_d x[b,d]*Wx[k,d] ----------------
__global__ __launch_bounds__(64) void xw_k(const float* __restrict__ x, const float* __restrict__ Wx,
                                           float* __restrict__ xw){
  int id = blockIdx.x;           // 128*10
  int b = id/10, k = id%10;
  int lane = threadIdx.x;
  float a = 0.f;
  for (int d = lane; d < 300; d += 64)
    a = fmaf(x[b*300+d], Wx[k*300+d], a);
  #pragma unroll
  for (int off=1; off<64; off<<=1) a += __shfl_xor(a, off);
  if (lane==0) xw[b*16+k] = a;
}

// ---------------- attention logits: score[b,t] = sum_k v_k tanh(Wh.h + Wht.pht + xW) ----------------
__global__ __launch_bounds__(256) void score_k(const float* __restrict__ hs, const float* __restrict__ pht,
    const float* __restrict__ Wh, const float* __restrict__ Wht, const float* __restrict__ v,
    const float* __restrict__ xw, float* __restrict__ score){
  __shared__ float wsm[6000];                      // [20][300]: Wh rows then Wht rows
  for (int i = threadIdx.x; i < 6000; i += 256)
    wsm[i] = (i < 3000 ? Wh[i] : Wht[i-3000]);
  __syncthreads();
  float vv[10];
  #pragma unroll
  for (int k=0;k<10;k++) vv[k] = v[k];
  int lane = threadIdx.x & 63;
  int gw = blockIdx.x*4 + (threadIdx.x>>6);        // 8192 waves, 16 rows each
  for (int rr = gw*16; rr < gw*16+16; rr++){       // rr = b*1024 + t
    int b = rr >> 10;
    const float* hr = hs  + (size_t)rr*300;
    const float* pr = pht + (size_t)rr*300;
    float acc[20];
    #pragma unroll
    for (int k=0;k<20;k++) acc[k]=0.f;
    #pragma unroll
    for (int i=0;i<5;i++){
      int d = lane + i*64;
      if (d < 300){
        float hv = hr[d], pv = pr[d];
        #pragma unroll
        for (int k=0;k<10;k++){
          acc[k]    = fmaf(hv, wsm[k*300+d],        acc[k]);
          acc[10+k] = fmaf(pv, wsm[3000 + k*300+d], acc[10+k]);
        }
      }
    }
    #pragma unroll
    for (int k=0;k<20;k++){
      float a = acc[k];
      a += __shfl_xor(a,1);  a += __shfl_xor(a,2);  a += __shfl_xor(a,4);
      a += __shfl_xor(a,8);  a += __shfl_xor(a,16); a += __shfl_xor(a,32);
      acc[k]=a;
    }
    float sc = 0.f;
    #pragma unroll
    for (int k=0;k<10;k++) sc += vv[k]*tanhf(acc[k]+acc[10+k]+xw[b*16+k]);
    if (lane==0) score[rr] = sc;
  }
}

// ---------------- softmax over T=1024, in-place ----------------
__global__ __launch_bounds__(256) void softmax_k(float* __restrict__ score){
  int b = blockIdx.x, tid = threadIdx.x;
  float* row = score + (size_t)b*1024;
  __shared__ float red[256];
  float m = -3.0e38f;
  #pragma unroll
  for (int j=0;j<4;j++) m = fmaxf(m, row[tid + j*256]);
  red[tid]=m; __syncthreads();
  for (int s=128;s>0;s>>=1){ if(tid<s) red[tid]=fmaxf(red[tid],red[tid+s]); __syncthreads(); }
  m = red[0]; __syncthreads();
  float vals[4], sum=0.f;
  #pragma unroll
  for (int j=0;j<4;j++){ vals[j] = expf(row[tid + j*256] - m); sum += vals[j]; }
  red[tid]=sum; __syncthreads();
  for (int s=128;s>0;s>>=1){ if(tid<s) red[tid]+=red[tid+s]; __syncthreads(); }
  float inv = 1.f/red[0];
  #pragma unroll
  for (int j=0;j<4;j++) row[tid + j*256] = vals[j]*inv;
}

// ---------------- ht = sum_t s*h ; ct = sum_t s*c (atomic partials) ----------------
__global__ __launch_bounds__(128) void wsum_k(const float* __restrict__ hs, const float* __restrict__ pc,
    const float* __restrict__ s, float* __restrict__ ht, float* __restrict__ ct){
  int b = blockIdx.x, chunk = blockIdx.y;
  int wave = threadIdx.x>>6, lane = threadIdx.x&63;
  float ah[4]={0,0,0,0}, ac[4]={0,0,0,0}, ah2[4]={0,0,0,0}, ac2[4]={0,0,0,0};
  int d1 = lane*4, d2 = 256 + lane*4;
  bool has2 = d2 < 300;                    // lanes 0..10
  int t0 = chunk*128;
  for (int t = t0 + wave; t < t0+128; t += 2){
    float sv = s[b*1024 + t];
    const float* hr = hs + ((size_t)(b*1024 + t))*300;
    const float* cr = pc + ((size_t)(b*1024 + t))*300;
    float4 h4 = *(const float4*)(hr + d1);
    float4 c4 = *(const float4*)(cr + d1);
    ah[0]=fmaf(sv,h4.x,ah[0]); ah[1]=fmaf(sv,h4.y,ah[1]);
    ah[2]=fmaf(sv,h4.z,ah[2]); ah[3]=fmaf(sv,h4.w,ah[3]);
    ac[0]=fmaf(sv,c4.x,ac[0]); ac[1]=fmaf(sv,c4.y,ac[1]);
    ac[2]=fmaf(sv,c4.z,ac[2]); ac[3]=fmaf(sv,c4.w,ac[3]);
    if (has2){
      float4 h5 = *(const float4*)(hr + d2);
      float4 c5 = *(const float4*)(cr + d2);
      ah2[0]=fmaf(sv,h5.x,ah2[0]); ah2[1]=fmaf(sv,h5.y,ah2[1]);
      ah2[2]=fmaf(sv,h5.z,ah2[2]); ah2[3]=fmaf(sv,h5.w,ah2[3]);
      ac2[0]=fmaf(sv,c5.x,ac2[0]); ac2[1]=fmaf(sv,c5.y,ac2[1]);
      ac2[2]=fmaf(sv,c5.z,ac2[2]); ac2[3]=fmaf(sv,c5.w,ac2[3]);
    }
  }
  #pragma unroll
  for (int j=0;j<4;j++){
    atomicAdd(&ht[b*300 + d1 + j], ah[j]);
    atomicAdd(&ct[b*300 + d1 + j], ac[j]);
  }
  if (has2){
    #pragma unroll
    for (int j=0;j<4;j++){
      atomicAdd(&ht[b*300 + d2 + j], ah2[j]);
      atomicAdd(&ct[b*300 + d2 + j], ac2[j]);
    }
  }
}

// ---------------- generic dense layer: out[b,n] = sum_k in(b,k)*W[n,k] + bias[n] ----------------
// mode 0: in = concat(ht, x); mode 1: in = inA
__global__ __launch_bounds__(256) void gemm_k(int mode, int K, int N,
    const float* __restrict__ inA, const float* __restrict__ inX,
    const float* __restrict__ W, const float* __restrict__ bias, float* __restrict__ out){
  __shared__ float aL[32][65];
  __shared__ float wL[32][65];
  int n0 = blockIdx.x*32, b0 = blockIdx.y*32;
  int tid = threadIdx.x;
  int lr = tid>>3, lk = (tid&7)*8;
  int bi = tid>>4, ni = tid&15;
  float a00=0,a01=0,a10=0,a11=0;
  for (int kc=0; kc<K; kc+=64){
    int brow = b0+lr;
    #pragma unroll
    for (int j=0;j<8;j++){
      int k = kc+lk+j;
      float vv = 0.f;
      if (k<K){
        if (mode==0) vv = (k<300) ? inA[brow*300+k] : inX[brow*300 + (k-300)];
        else         vv = inA[(size_t)brow*K + k];
      }
      aL[lr][lk+j] = vv;
    }
    int nrow = n0+lr;
    #pragma unroll
    for (int j=0;j<8;j++){
      int k = kc+lk+j;
      float vv = 0.f;
      if (nrow<N && k<K) vv = W[(size_t)nrow*K + k];
      wL[lr][lk+j] = vv;
    }
    __syncthreads();
    #pragma unroll
    for (int kk=0;kk<64;kk++){
      float x0 = aL[2*bi][kk], x1 = aL[2*bi+1][kk];
      float y0 = wL[2*ni][kk], y1 = wL[2*ni+1][kk];
      a00 = fmaf(x0,y0,a00); a01 = fmaf(x0,y1,a01);
      a10 = fmaf(x1,y0,a10); a11 = fmaf(x1,y1,a11);
    }
    __syncthreads();
  }
  int b = b0 + 2*bi, n = n0 + 2*ni;
  if (n < N){
    float bb = bias[n];
    out[(size_t)b*N+n]     = a00+bb;
    out[(size_t)(b+1)*N+n] = a10+bb;
  }
  if (n+1 < N){
    float bb = bias[n+1];
    out[(size_t)b*N+n+1]     = a01+bb;
    out[(size_t)(b+1)*N+n+1] = a11+bb;
  }
}

// ---------------- scatter pre (whx2) into padded P0 (bf16) ----------------
__global__ __launch_bounds__(256) void scat_k(const float* __restrict__ whx2, u16* __restrict__ p0){
  int id = blockIdx.x*256 + threadIdx.x;          // 128*1600
  int b = id/1600, p = id%1600;
  int y = p/40, x = p%40;
  p0[(size_t)b*1764 + (y+1)*42 + (x+1)] = f2bf(whx2[id]);
}

// ---------------- conv weight repack: w2[ci][k][co] f32 + per-channel params ----------------
__global__ void repack_k(const float* __restrict__ w, const float* __restrict__ bb,
                         const float* __restrict__ g, const float* __restrict__ be,
                         float* __restrict__ w2, float* __restrict__ par, int CI, int CO){
  int id = blockIdx.x*256 + threadIdx.x;
  int tot = CI*CO*9;
  if (id < tot){
    int co = id % CO;
    int rem = id / CO;
    int k = rem % 9, ci = rem / 9;
    w2[id] = w[(co*CI + ci)*9 + k];
  }
  if (id < CO){
    par[id]      = bb[id];
    par[CO+id]   = g[id] * (1.0f/sqrtf(1.00001f));
    par[2*CO+id] = be[id];
  }
}

// ---------------- direct conv 3x3 SAME + bias + relu + bn (NHWC padded 42x42, bf16) ----------------
// lane = output channel; wave computes a 5x5 pixel tile (TT: two tiles/wave for CO=32)
template<int CI, int CO, bool TT>
__global__ __launch_bounds__(256) void conv_main(const u16* __restrict__ in, u16* __restrict__ out,
    const float* __restrict__ w2, const float* __restrict__ par){
  int b = blockIdx.x;
  int wave = threadIdx.x >> 6;
  int lane = threadIdx.x & 63;
  int tile, co;
  if (TT){ tile = blockIdx.y*8 + wave*2 + (lane>>5); co = lane & 31; }
  else   { tile = blockIdx.y*4 + wave;               co = lane; }
  int y0 = (tile >> 3)*5, x0 = (tile & 7)*5;          // padded window origin
  const u16* inb = in + (size_t)b*1764*CI;
  float acc[25];
  #pragma unroll
  for (int p=0;p<25;p++) acc[p]=0.f;
  for (int ci=0; ci<CI; ci++){
    float win[49];
    #pragma unroll
    for (int r=0;r<7;r++)
      #pragma unroll
      for (int c=0;c<7;c++)
        win[r*7+c] = bf2f(inb[ ((y0+r)*42 + (x0+c))*CI + ci ]);
    float wk[9];
    #pragma unroll
    for (int k=0;k<9;k++) wk[k] = w2[(ci*9+k)*CO + co];
    #pragma unroll
    for (int py=0;py<5;py++)
      #pragma unroll
      for (int px=0;px<5;px++){
        float s = acc[py*5+px];
        #pragma unroll
        for (int dy=0;dy<3;dy++)
          #pragma unroll
          for (int dx=0;dx<3;dx++)
            s = fmaf(wk[dy*3+dx], win[(py+dy)*7 + (px+dx)], s);
        acc[py*5+px] = s;
      }
  }
  float bia = par[co], sc = par[CO+co], be = par[2*CO+co];
  u16* outb = out + (size_t)b*1764*CO;
  #pragma unroll
  for (int py=0;py<5;py++)
    #pragma unroll
    for (int px=0;px<5;px++){
      float vv = fmaxf(acc[py*5+px] + bia, 0.f)*sc + be;
      outb[ ((y0+py+1)*42 + (x0+px+1))*CO + co ] = f2bf(vv);
    }
}

// ---------------- c6: 32 -> 1 channel ----------------
__global__ __launch_bounds__(256) void conv_c6(const u16* __restrict__ in, u16* __restrict__ y6,
    const float* __restrict__ w6, const float* __restrict__ par6){
  int id = blockIdx.x*256 + threadIdx.x;          // 128*1600
  int b = id/1600, p = id%1600;
  int y = p/40, x = p%40;
  const u16* inb = in + (size_t)b*1764*32;
  float acc = 0.f;
  #pragma unroll
  for (int dy=0;dy<3;dy++)
    #pragma unroll
    for (int dx=0;dx<3;dx++){
      const u16* q = inb + ((y+dy)*42 + (x+dx))*32;
      #pragma unroll
      for (int ci=0;ci<32;ci++)
        acc = fmaf(w6[ci*9 + dy*3+dx], bf2f(q[ci]), acc);
    }
  float vv = fmaxf(acc + par6[0], 0.f)*par6[1] + par6[2];
  y6[(size_t)b*1764 + (y+1)*42 + (x+1)] = f2bf(vv);
}

// ---------------- pc: concat(pre, y6) 2 -> 1 channel, no relu ----------------
__global__ __launch_bounds__(256) void conv_pc(const u16* __restrict__ p0, const u16* __restrict__ y6,
    const float* __restrict__ pcw, const float* __restrict__ pcb,
    const float* __restrict__ pcg, const float* __restrict__ pcbe,
    float* __restrict__ out1600){
  int id = blockIdx.x*256 + threadIdx.x;          // 128*1600
  int b = id/1600, p = id%1600;
  int y = p/40, x = p%40;
  float acc = 0.f;
  #pragma unroll
  for (int dy=0;dy<3;dy++)
    #pragma unroll
    for (int dx=0;dx<3;dx++){
      size_t o = (size_t)b*1764 + (y+dy)*42 + (x+dx);
      acc = fmaf(pcw[dy*3+dx],     bf2f(p0[o]), acc);
      acc = fmaf(pcw[9 + dy*3+dx], bf2f(y6[o]), acc);
    }
  float sc = pcg[0] * (1.0f/sqrtf(1.00001f));
  out1600[id] = (acc + pcb[0])*sc + pcbe[0];
}

// ---------------- LSTM gating ----------------
__global__ __launch_bounds__(256) void gate_k(const float* __restrict__ whx3, const float* __restrict__ ct,
                                              float* __restrict__ outp){
  int id = blockIdx.x*256 + threadIdx.x;          // 128*300
  if (id >= 38400) return;
  int b = id/300, d = id%300;
  const float* r = whx3 + (size_t)b*1200;
  float ft = 1.f/(1.f+expf(-r[d]));
  float ot = 1.f/(1.f+expf(-r[300+d]));
  float it = 1.f/(1.f+expf(-r[600+d]));
  float ch = tanhf(r[900+d]);
  float c  = ft*ct[id] + it*ch;
  outp[id] = ot*tanhf(c);
}

extern "C" void kernel_launch(void* const* d_in, const int* in_sizes, int n_in,
                              void* d_out, int out_size, void* d_ws, size_t ws_size,
                              hipStream_t stream){
  const float* x    = (const float*)d_in[0];
  const float* hs   = (const float*)d_in[1];
  const float* pht  = (const float*)d_in[2];
  const float* pc   = (const float*)d_in[3];
  const float* W    = (const float*)d_in[4];
  const float* bb   = (const float*)d_in[5];
  const float* Wh   = (const float*)d_in[6];
  const float* Wx   = (const float*)d_in[7];
  const float* Wht  = (const float*)d_in[8];
  const float* v    = (const float*)d_in[9];
  const float* rbw  = (const float*)d_in[10];
  const float* rbb  = (const float*)d_in[11];
  const float* rpw  = (const float*)d_in[12];
  const float* rpb  = (const float*)d_in[13];
  const float *cw[6], *cb[6], *cg[6], *cbe[6];
  for (int i=0;i<6;i++){
    cw[i]=(const float*)d_in[14+4*i]; cb[i]=(const float*)d_in[15+4*i];
    cg[i]=(const float*)d_in[16+4*i]; cbe[i]=(const float*)d_in[17+4*i];
  }
  const float* pcw = (const float*)d_in[38];
  const float* pcb = (const float*)d_in[39];
  const float* pcg = (const float*)d_in[40];
  const float* pcbe= (const float*)d_in[41];

  char* ws = (char*)d_ws;
  float* score = (float*)(ws + OFF_SCORE);
  float* xw    = (float*)(ws + OFF_XW);
  float* whx1  = (float*)(ws + OFF_WHX1);
  float* whx2  = (float*)(ws + OFF_WHX2);
  float* o1600 = (float*)(ws + OFF_O1600);
  float* whx3  = (float*)(ws + OFF_WHX3);
  float* w21   = (float*)(ws + OFF_W21);
  float* w22   = (float*)(ws + OFF_W22);
  float* w23   = (float*)(ws + OFF_W23);
  float* w24   = (float*)(ws + OFF_W24);
  float* w25   = (float*)(ws + OFF_W25);
  float* w26   = (float*)(ws + OFF_W26);
  float* par[6];
  for (int i=0;i<6;i++) par[i] = (float*)(ws + OFF_PAR + (size_t)i*768);
  float* ht = (float*)(ws + OFF_HT);
  float* ct = (float*)(ws + OFF_CT);
  u16* A32 = (u16*)(ws + OFF_A32);
  u16* B64 = (u16*)(ws + OFF_B64);
  u16* C64 = (u16*)(ws + OFF_C64);
  u16* P0  = (u16*)(ws + OFF_P0);
  u16* Y6  = (u16*)(ws + OFF_Y6);

  // 0) zero atomic accumulators + padded conv buffers (borders must be 0 every call)
  zero_k<<<4096,256,0,stream>>>((uint4*)(ws + OFF_HT), ZERO_BYTES/16);

  // 1) attention
  xw_k<<<1280,64,0,stream>>>(x, Wx, xw);
  score_k<<<2048,256,0,stream>>>(hs, pht, Wh, Wht, v, xw, score);
  softmax_k<<<128,256,0,stream>>>(score);
  wsum_k<<<dim3(128,8),128,0,stream>>>(hs, pc, score, ht, ct);

  // 2) dense layers to pre
  gemm_k<<<dim3(38,4),256,0,stream>>>(0,  600, 1200, ht, x,      W,   bb,  whx1);
  gemm_k<<<dim3(50,4),256,0,stream>>>(1, 1200, 1600, whx1, nullptr, rbw, rbb, whx2);
  scat_k<<<800,256,0,stream>>>(whx2, P0);

  // 3) conv block
  repack_k<<<2,  256,0,stream>>>(cw[0],cb[0],cg[0],cbe[0], w21, par[0],  1, 32);
  repack_k<<<72, 256,0,stream>>>(cw[1],cb[1],cg[1],cbe[1], w22, par[1], 32, 64);
  repack_k<<<144,256,0,stream>>>(cw[2],cb[2],cg[2],cbe[2], w23, par[2], 64, 64);
  repack_k<<<144,256,0,stream>>>(cw[3],cb[3],cg[3],cbe[3], w24, par[3], 64, 64);
  repack_k<<<72, 256,0,stream>>>(cw[4],cb[4],cg[4],cbe[4], w25, par[4], 64, 32);
  repack_k<<<2,  256,0,stream>>>(cw[5],cb[5],cg[5],cbe[5], w26, par[5], 32,  1);

  conv_main<1,32,true  ><<<dim3(128,8), 256,0,stream>>>(P0,  A32, w21, par[0]);
  conv_main<32,64,false><<<dim3(128,16),256,0,stream>>>(A32, B64, w22, par[1]);
  conv_main<64,64,false><<<dim3(128,16),256,0,stream>>>(B64, C64, w23, par[2]);
  conv_main<64,64,false><<<dim3(128,16),256,0,stream>>>(C64, B64, w24, par[3]);
  conv_main<64,32,true ><<<dim3(128,8), 256,0,stream>>>(B64, A32, w25, par[4]);
  conv_c6<<<800,256,0,stream>>>(A32, Y6, w26, par[5]);
  conv_pc<<<800,256,0,stream>>>(P0, Y6, pcw, pcb, pcg, pcbe, o1600);

  // 4) final projection + gating
  gemm_k<<<dim3(38,4),256,0,stream>>>(1, 1600, 1200, o1600, nullptr, rpw, rpb, whx3);
  gate_k<<<150,256,0,stream>>>(whx3, ct, (float*)d_out);
}

// Round 3
// 1010.387 us; speedup vs baseline: 1.6981x; 1.6981x over previous
//
#include <hip/hip_runtime.h>
#include <cstdint>
#include <cstddef>

typedef unsigned short u16;

#define DEV __device__ __forceinline__

DEV float bf2f(u16 u){ union{unsigned int i; float f;} c; c.i = ((unsigned)u)<<16; return c.f; }
DEV u16 f2bf(float f){ union{float f;unsigned int i;} c; c.f=f; unsigned int r = c.i + 0x7FFFu + ((c.i>>16)&1u); return (u16)(r>>16); }

typedef __attribute__((ext_vector_type(8))) short bf16x8;
typedef __attribute__((ext_vector_type(4))) float f32x4;
typedef __attribute__((ext_vector_type(8))) unsigned short us8v;

// ---------------- workspace layout (bytes) ----------------
static constexpr size_t OFF_SCORE = 0;                                   // [128][1024] f32
static constexpr size_t OFF_XW    = OFF_SCORE + (size_t)128*1024*4;      // [128][16] f32
static constexpr size_t OFF_WHX1  = OFF_XW    + (size_t)128*16*4;        // [128][1200] f32
static constexpr size_t OFF_WHX2  = OFF_WHX1  + (size_t)128*1200*4;      // [128][1600] f32
static constexpr size_t OFF_O1600 = OFF_WHX2  + (size_t)128*1600*4;      // [128][1600] f32
static constexpr size_t OFF_WHX3  = OFF_O1600 + (size_t)128*1600*4;      // [128][1200] f32
static constexpr size_t OFF_W21   = OFF_WHX3  + (size_t)128*1200*4;      // conv1 w [ci][9][co] f32 (direct)
static constexpr size_t OFF_WB2   = OFF_W21   + (size_t)1*32*9*4;        // conv2 w [co=64][9][ci=32] bf16
static constexpr size_t OFF_WB3   = OFF_WB2   + (size_t)64*9*32*2;       // conv3 w [64][9][64] bf16
static constexpr size_t OFF_WB4   = OFF_WB3   + (size_t)64*9*64*2;       // conv4 w [64][9][64] bf16
static constexpr size_t OFF_WB5   = OFF_WB4   + (size_t)64*9*64*2;       // conv5 w [co=32][9][ci=64] bf16
static constexpr size_t OFF_W26   = OFF_WB5   + (size_t)32*9*64*2;       // conv6 w [ci][9][co=1] f32 (direct)
static constexpr size_t OFF_PAR   = OFF_W26   + (size_t)32*1*9*4;        // 6 x 768B: bias/scale/beta f32
// ---- zero-initialized region starts here ----
static constexpr size_t OFF_HT    = OFF_PAR   + (size_t)6*768;           // [128][300] f32 (atomic acc)
static constexpr size_t OFF_CT    = OFF_HT    + (size_t)128*300*4;       // [128][300] f32
static constexpr size_t OFF_A32   = OFF_CT    + (size_t)128*300*4;       // [128][42*42][32] bf16
static constexpr size_t OFF_B64   = OFF_A32   + (size_t)128*1764*32*2;   // [128][42*42][64] bf16
static constexpr size_t OFF_C64   = OFF_B64   + (size_t)128*1764*64*2;   // [128][42*42][64] bf16
static constexpr size_t OFF_P0    = OFF_C64   + (size_t)128*1764*64*2;   // [128][42*42] bf16 (pre, padded)
static constexpr size_t OFF_Y6    = OFF_P0    + (size_t)128*1764*2;      // [128][42*42] bf16 (c6 out, padded)
static constexpr size_t OFF_END   = OFF_Y6    + (size_t)128*1764*2;
static constexpr size_t ZERO_BYTES = OFF_END - OFF_HT;

// ---------------- zero init ----------------
__global__ void zero_k(uint4* __restrict__ p, size_t n){
  size_t i = (size_t)blockIdx.x*blockDim.x + threadIdx.x;
  uint4 z; z.x=0; z.y=0; z.z=0; z.w=0;
  for (; i < n; i += (size_t)gridDim.x*blockDim.x) p[i] = z;
}

// ---------------- xW[b][k] = sum_d x[b,d]*Wx[k,d] ----------------
__global__ __launch_bounds__(64) void xw_k(const float* __restrict__ x, const float* __restrict__ Wx,
                                           float* __restrict__ xw){
  int id = blockIdx.x;           // 128*10
  int b = id/10, k = id%10;
  int lane = threadIdx.x;
  float a = 0.f;
  for (int d = lane; d < 300; d += 64)
    a = fmaf(x[b*300+d], Wx[k*300+d], a);
  #pragma unroll
  for (int off=1; off<64; off<<=1) a += __shfl_xor(a, off);
  if (lane==0) xw[b*16+k] = a;
}

// ---------------- attention logits ----------------
__global__ __launch_bounds__(256) void score_k(const float* __restrict__ hs, const float* __restrict__ pht,
    const float* __restrict__ Wh, const float* __restrict__ Wht, const float* __restrict__ v,
    const float* __restrict__ xw, float* __restrict__ score){
  __shared__ float wsm[6000];                      // [20][300]: Wh rows then Wht rows
  for (int i = threadIdx.x; i < 6000; i += 256)
    wsm[i] = (i < 3000 ? Wh[i] : Wht[i-3000]);
  __syncthreads();
  float vv[10];
  #pragma unroll
  for (int k=0;k<10;k++) vv[k] = v[k];
  int lane = threadIdx.x & 63;
  int gw = blockIdx.x*4 + (threadIdx.x>>6);        // 8192 waves, 16 rows each
  for (int rr = gw*16; rr < gw*16+16; rr++){       // rr = b*1024 + t
    int b = rr >> 10;
    const float* hr = hs  + (size_t)rr*300;
    const float* pr = pht + (size_t)rr*300;
    float acc[20];
    #pragma unroll
    for (int k=0;k<20;k++) acc[k]=0.f;
    #pragma unroll
    for (int i=0;i<5;i++){
      int d = lane + i*64;
      if (d < 300){
        float hv = hr[d], pv = pr[d];
        #pragma unroll
        for (int k=0;k<10;k++){
          acc[k]    = fmaf(hv, wsm[k*300+d],        acc[k]);
          acc[10+k] = fmaf(pv, wsm[3000 + k*300+d], acc[10+k]);
        }
      }
    }
    #pragma unroll
    for (int k=0;k<20;k++){
      float a = acc[k];
      a += __shfl_xor(a,1);  a += __shfl_xor(a,2);  a += __shfl_xor(a,4);
      a += __shfl_xor(a,8);  a += __shfl_xor(a,16); a += __shfl_xor(a,32);
      acc[k]=a;
    }
    float sc = 0.f;
    #pragma unroll
    for (int k=0;k<10;k++) sc += vv[k]*tanhf(acc[k]+acc[10+k]+xw[b*16+k]);
    if (lane==0) score[rr] = sc;
  }
}

// ---------------- softmax over T=1024, in-place ----------------
__global__ __launch_bounds__(256) void softmax_k(float* __restrict__ score){
  int b = blockIdx.x, tid = threadIdx.x;
  float* row = score + (size_t)b*1024;
  __shared__ float red[256];
  float m = -3.0e38f;
  #pragma unroll
  for (int j=0;j<4;j++) m = fmaxf(m, row[tid + j*256]);
  red[tid]=m; __syncthreads();
  for (int s=128;s>0;s>>=1){ if(tid<s) red[tid]=fmaxf(red[tid],red[tid+s]); __syncthreads(); }
  m = red[0]; __syncthreads();
  float vals[4], sum=0.f;
  #pragma unroll
  for (int j=0;j<4;j++){ vals[j] = expf(row[tid + j*256] - m); sum += vals[j]; }
  red[tid]=sum; __syncthreads();
  for (int s=128;s>0;s>>=1){ if(tid<s) red[tid]+=red[tid+s]; __syncthreads(); }
  float inv = 1.f/red[0];
  #pragma unroll
  for (int j=0;j<4;j++) row[tid + j*256] = vals[j]*inv;
}

// ---------------- ht = sum_t s*h ; ct = sum_t s*c (atomic partials) ----------------
__global__ __launch_bounds__(128) void wsum_k(const float* __restrict__ hs, const float* __restrict__ pc,
    const float* __restrict__ s, float* __restrict__ ht, float* __restrict__ ct){
  int b = blockIdx.x, chunk = blockIdx.y;
  int wave = threadIdx.x>>6, lane = threadIdx.x&63;
  float ah[4]={0,0,0,0}, ac[4]={0,0,0,0}, ah2[4]={0,0,0,0}, ac2[4]={0,0,0,0};
  int d1 = lane*4, d2 = 256 + lane*4;
  bool has2 = d2 < 300;                    // lanes 0..10
  int t0 = chunk*128;
  for (int t = t0 + wave; t < t0+128; t += 2){
    float sv = s[b*1024 + t];
    const float* hr = hs + ((size_t)(b*1024 + t))*300;
    const float* cr = pc + ((size_t)(b*1024 + t))*300;
    float4 h4 = *(const float4*)(hr + d1);
    float4 c4 = *(const float4*)(cr + d1);
    ah[0]=fmaf(sv,h4.x,ah[0]); ah[1]=fmaf(sv,h4.y,ah[1]);
    ah[2]=fmaf(sv,h4.z,ah[2]); ah[3]=fmaf(sv,h4.w,ah[3]);
    ac[0]=fmaf(sv,c4.x,ac[0]); ac[1]=fmaf(sv,c4.y,ac[1]);
    ac[2]=fmaf(sv,c4.z,ac[2]); ac[3]=fmaf(sv,c4.w,ac[3]);
    if (has2){
      float4 h5 = *(const float4*)(hr + d2);
      float4 c5 = *(const float4*)(cr + d2);
      ah2[0]=fmaf(sv,h5.x,ah2[0]); ah2[1]=fmaf(sv,h5.y,ah2[1]);
      ah2[2]=fmaf(sv,h5.z,ah2[2]); ah2[3]=fmaf(sv,h5.w,ah2[3]);
      ac2[0]=fmaf(sv,c5.x,ac2[0]); ac2[1]=fmaf(sv,c5.y,ac2[1]);
      ac2[2]=fmaf(sv,c5.z,ac2[2]); ac2[3]=fmaf(sv,c5.w,ac2[3]);
    }
  }
  #pragma unroll
  for (int j=0;j<4;j++){
    atomicAdd(&ht[b*300 + d1 + j], ah[j]);
    atomicAdd(&ct[b*300 + d1 + j], ac[j]);
  }
  if (has2){
    #pragma unroll
    for (int j=0;j<4;j++){
      atomicAdd(&ht[b*300 + d2 + j], ah2[j]);
      atomicAdd(&ct[b*300 + d2 + j], ac2[j]);
    }
  }
}

// ---------------- generic dense layer ----------------
__global__ __launch_bounds__(256) void gemm_k(int mode, int K, int N,
    const float* __restrict__ inA, const float* __restrict__ inX,
    const float* __restrict__ W, const float* __restrict__ bias, float* __restrict__ out){
  __shared__ float aL[32][65];
  __shared__ float wL[32][65];
  int n0 = blockIdx.x*32, b0 = blockIdx.y*32;
  int tid = threadIdx.x;
  int lr = tid>>3, lk = (tid&7)*8;
  int bi = tid>>4, ni = tid&15;
  float a00=0,a01=0,a10=0,a11=0;
  for (int kc=0; kc<K; kc+=64){
    int brow = b0+lr;
    #pragma unroll
    for (int j=0;j<8;j++){
      int k = kc+lk+j;
      float vv = 0.f;
      if (k<K){
        if (mode==0) vv = (k<300) ? inA[brow*300+k] : inX[brow*300 + (k-300)];
        else         vv = inA[(size_t)brow*K + k];
      }
      aL[lr][lk+j] = vv;
    }
    int nrow = n0+lr;
    #pragma unroll
    for (int j=0;j<8;j++){
      int k = kc+lk+j;
      float vv = 0.f;
      if (nrow<N && k<K) vv = W[(size_t)nrow*K + k];
      wL[lr][lk+j] = vv;
    }
    __syncthreads();
    #pragma unroll
    for (int kk=0;kk<64;kk++){
      float x0 = aL[2*bi][kk], x1 = aL[2*bi+1][kk];
      float y0 = wL[2*ni][kk], y1 = wL[2*ni+1][kk];
      a00 = fmaf(x0,y0,a00); a01 = fmaf(x0,y1,a01);
      a10 = fmaf(x1,y0,a10); a11 = fmaf(x1,y1,a11);
    }
    __syncthreads();
  }
  int b = b0 + 2*bi, n = n0 + 2*ni;
  if (n < N){
    float bb = bias[n];
    out[(size_t)b*N+n]     = a00+bb;
    out[(size_t)(b+1)*N+n] = a10+bb;
  }
  if (n+1 < N){
    float bb = bias[n+1];
    out[(size_t)b*N+n+1]     = a01+bb;
    out[(size_t)(b+1)*N+n+1] = a11+bb;
  }
}

// ---------------- scatter pre (whx2) into padded P0 (bf16) ----------------
__global__ __launch_bounds__(256) void scat_k(const float* __restrict__ whx2, u16* __restrict__ p0){
  int id = blockIdx.x*256 + threadIdx.x;          // 128*1600
  int b = id/1600, p = id%1600;
  int y = p/40, x = p%40;
  p0[(size_t)b*1764 + (y+1)*42 + (x+1)] = f2bf(whx2[id]);
}

// ---------------- conv weight repack (direct kernels): w2[ci][k][co] f32 ----------------
__global__ void repack_k(const float* __restrict__ w, const float* __restrict__ bb,
                         const float* __restrict__ g, const float* __restrict__ be,
                         float* __restrict__ w2, float* __restrict__ par, int CI, int CO){
  int id = blockIdx.x*256 + threadIdx.x;
  int tot = CI*CO*9;
  if (id < tot){
    int co = id % CO;
    int rem = id / CO;
    int k = rem % 9, ci = rem / 9;
    w2[id] = w[(co*CI + ci)*9 + k];
  }
  if (id < CO){
    par[id]      = bb[id];
    par[CO+id]   = g[id] * (1.0f/sqrtf(1.00001f));
    par[2*CO+id] = be[id];
  }
}

// ---------------- conv weight repack (MFMA kernels): wB[co][dydx][ci] bf16 ----------------
__global__ void repack_mfma_k(const float* __restrict__ w, const float* __restrict__ bb,
                              const float* __restrict__ g, const float* __restrict__ be,
                              u16* __restrict__ wB, float* __restrict__ par, int CI, int CO){
  int id = blockIdx.x*256 + threadIdx.x;
  int tot = CI*CO*9;
  if (id < tot){
    int ci = id % CI;
    int rem = id / CI;
    int dydx = rem % 9, co = rem / 9;
    wB[id] = f2bf(w[(co*CI + ci)*9 + dydx]);
  }
  if (id < CO){
    par[id]      = bb[id];
    par[CO+id]   = g[id] * (1.0f/sqrtf(1.00001f));
    par[2*CO+id] = be[id];
  }
}

// ---------------- implicit-GEMM MFMA conv 3x3 SAME + bias + relu + bn ----------------
// D[cout][pixel] = W x X.  A = weights [co][dydx][ci] bf16, B = NHWC input.
// block: 1 batch x 64 pixels x all couts; wave w handles pixels [tile*64+w*16, +16).
// mfma_f32_16x16x32_bf16 fragment maps (guide §3, m89-verified):
//   A: lane holds row=l&15, k=(l>>4)*8+j   B: lane holds col=l&15, k=(l>>4)*8+j
//   D: lane holds col=l&15, row=(l>>4)*4+r  -> 4 consecutive couts => ushort4 NHWC store
template<int CI, int CO>
__global__ __launch_bounds__(256) void conv_mfma(const u16* __restrict__ in, u16* __restrict__ out,
    const u16* __restrict__ wB, const float* __restrict__ par){
  constexpr int MF = CO/16;          // M-frags (cout groups)
  constexpr int KROW = CI*9;         // A row length in elems
  int b = blockIdx.x;
  int tile = blockIdx.y;             // 0..24
  int w = threadIdx.x>>6, l = threadIdx.x&63;
  int col = l & 15;
  int kg  = (l>>4)*8;
  int p = tile*64 + w*16 + col;      // output pixel 0..1599
  int y = p/40, x = p%40;
  const u16* inb = in + (size_t)b*1764*CI;
  f32x4 acc[MF];
  #pragma unroll
  for (int m=0;m<MF;m++) acc[m] = (f32x4){0.f,0.f,0.f,0.f};
  #pragma unroll
  for (int dy=0;dy<3;dy++)
  #pragma unroll
  for (int dx=0;dx<3;dx++){
    int dydx = dy*3+dx;
    // padded coords: output (y,x) -> window rows y+dy (0..41), cols x+dx
    const u16* bp = inb + (size_t)((y+dy)*42 + (x+dx))*CI + kg;
    const u16* ap = wB + (size_t)col*KROW + dydx*CI + kg;
    #pragma unroll
    for (int kc=0; kc<CI; kc+=32){
      bf16x8 bf = *(const bf16x8*)(bp + kc);
      #pragma unroll
      for (int m=0;m<MF;m++){
        bf16x8 af = *(const bf16x8*)(ap + (size_t)m*16*KROW + kc);
        acc[m] = __builtin_amdgcn_mfma_f32_16x16x32_bf16(af, bf, acc[m], 0, 0, 0);
      }
    }
  }
  u16* ob = out + (size_t)b*1764*CO + (size_t)((y+1)*42 + (x+1))*CO;
  #pragma unroll
  for (int m=0;m<MF;m++){
    int co0 = m*16 + (l>>4)*4;
    const float4 bia = *(const float4*)(par + co0);
    const float4 sc  = *(const float4*)(par + CO + co0);
    const float4 be  = *(const float4*)(par + 2*CO + co0);
    ushort4 s;
    s.x = f2bf(fmaxf(acc[m][0]+bia.x,0.f)*sc.x + be.x);
    s.y = f2bf(fmaxf(acc[m][1]+bia.y,0.f)*sc.y + be.y);
    s.z = f2bf(fmaxf(acc[m][2]+bia.z,0.f)*sc.z + be.z);
    s.w = f2bf(fmaxf(acc[m][3]+bia.w,0.f)*sc.w + be.w);
    *(ushort4*)(ob + co0) = s;
  }
}

// ---------------- conv1 direct 1->32 (tiny K, keep direct) ----------------
template<int CI, int CO, bool TT>
__global__ __launch_bounds__(256) void conv_main(const u16* __restrict__ in, u16* __restrict__ out,
    const float* __restrict__ w2, const float* __restrict__ par){
  int b = blockIdx.x;
  int wave = threadIdx.x >> 6;
  int lane = threadIdx.x & 63;
  int tile, co;
  if (TT){ tile = blockIdx.y*8 + wave*2 + (lane>>5); co = lane & 31; }
  else   { tile = blockIdx.y*4 + wave;               co = lane; }
  int y0 = (tile >> 3)*5, x0 = (tile & 7)*5;          // padded window origin
  const u16* inb = in + (size_t)b*1764*CI;
  float acc[25];
  #pragma unroll
  for (int p=0;p<25;p++) acc[p]=0.f;
  for (int ci=0; ci<CI; ci++){
    float win[49];
    #pragma unroll
    for (int r=0;r<7;r++)
      #pragma unroll
      for (int c=0;c<7;c++)
        win[r*7+c] = bf2f(inb[ ((y0+r)*42 + (x0+c))*CI + ci ]);
    float wk[9];
    #pragma unroll
    for (int k=0;k<9;k++) wk[k] = w2[(ci*9+k)*CO + co];
    #pragma unroll
    for (int py=0;py<5;py++)
      #pragma unroll
      for (int px=0;px<5;px++){
        float s = acc[py*5+px];
        #pragma unroll
        for (int dy=0;dy<3;dy++)
          #pragma unroll
          for (int dx=0;dx<3;dx++)
            s = fmaf(wk[dy*3+dx], win[(py+dy)*7 + (px+dx)], s);
        acc[py*5+px] = s;
      }
  }
  float bia = par[co], sc = par[CO+co], be = par[2*CO+co];
  u16* outb = out + (size_t)b*1764*CO;
  #pragma unroll
  for (int py=0;py<5;py++)
    #pragma unroll
    for (int px=0;px<5;px++){
      float vv = fmaxf(acc[py*5+px] + bia, 0.f)*sc + be;
      outb[ ((y0+py+1)*42 + (x0+px+1))*CO + co ] = f2bf(vv);
    }
}

// ---------------- c6: 32 -> 1 channel (vectorized input loads) ----------------
__global__ __launch_bounds__(256) void conv_c6(const u16* __restrict__ in, u16* __restrict__ y6,
    const float* __restrict__ w6, const float* __restrict__ par6){
  int id = blockIdx.x*256 + threadIdx.x;          // 128*1600
  int b = id/1600, p = id%1600;
  int y = p/40, x = p%40;
  const u16* inb = in + (size_t)b*1764*32;
  float acc = 0.f;
  #pragma unroll
  for (int dy=0;dy<3;dy++)
    #pragma unroll
    for (int dx=0;dx<3;dx++){
      const u16* q = inb + ((y+dy)*42 + (x+dx))*32;
      int k = dy*3+dx;
      #pragma unroll
      for (int g=0; g<4; g++){
        us8v vv8 = *(const us8v*)(q + g*8);
        #pragma unroll
        for (int j=0;j<8;j++)
          acc = fmaf(w6[(g*8+j)*9 + k], bf2f(vv8[j]), acc);  // w6 uniform -> s_load
      }
    }
  float vv = fmaxf(acc + par6[0], 0.f)*par6[1] + par6[2];
  y6[(size_t)b*1764 + (y+1)*42 + (x+1)] = f2bf(vv);
}

// ---------------- pc: concat(pre, y6) 2 -> 1 channel, no relu ----------------
__global__ __launch_bounds__(256) void conv_pc(const u16* __restrict__ p0, const u16* __restrict__ y6,
    const float* __restrict__ pcw, const float* __restrict__ pcb,
    const float* __restrict__ pcg, const float* __restrict__ pcbe,
    float* __restrict__ out1600){
  int id = blockIdx.x*256 + threadIdx.x;          // 128*1600
  int b = id/1600, p = id%1600;
  int y = p/40, x = p%40;
  float acc = 0.f;
  #pragma unroll
  for (int dy=0;dy<3;dy++)
    #pragma unroll
    for (int dx=0;dx<3;dx++){
      size_t o = (size_t)b*1764 + (y+dy)*42 + (x+dx);
      acc = fmaf(pcw[dy*3+dx],     bf2f(p0[o]), acc);
      acc = fmaf(pcw[9 + dy*3+dx], bf2f(y6[o]), acc);
    }
  float sc = pcg[0] * (1.0f/sqrtf(1.00001f));
  out1600[id] = (acc + pcb[0])*sc + pcbe[0];
}

// ---------------- LSTM gating ----------------
__global__ __launch_bounds__(256) void gate_k(const float* __restrict__ whx3, const float* __restrict__ ct,
                                              float* __restrict__ outp){
  int id = blockIdx.x*256 + threadIdx.x;          // 128*300
  if (id >= 38400) return;
  int b = id/300, d = id%300;
  const float* r = whx3 + (size_t)b*1200;
  float ft = 1.f/(1.f+expf(-r[d]));
  float ot = 1.f/(1.f+expf(-r[300+d]));
  float it = 1.f/(1.f+expf(-r[600+d]));
  float ch = tanhf(r[900+d]);
  float c  = ft*ct[id] + it*ch;
  outp[id] = ot*tanhf(c);
}

extern "C" void kernel_launch(void* const* d_in, const int* in_sizes, int n_in,
                              void* d_out, int out_size, void* d_ws, size_t ws_size,
                              hipStream_t stream){
  const float* x    = (const float*)d_in[0];
  const float* hs   = (const float*)d_in[1];
  const float* pht  = (const float*)d_in[2];
  const float* pc   = (const float*)d_in[3];
  const float* W    = (const float*)d_in[4];
  const float* bb   = (const float*)d_in[5];
  const float* Wh   = (const float*)d_in[6];
  const float* Wx   = (const float*)d_in[7];
  const float* Wht  = (const float*)d_in[8];
  const float* v    = (const float*)d_in[9];
  const float* rbw  = (const float*)d_in[10];
  const float* rbb  = (const float*)d_in[11];
  const float* rpw  = (const float*)d_in[12];
  const float* rpb  = (const float*)d_in[13];
  const float *cw[6], *cb[6], *cg[6], *cbe[6];
  for (int i=0;i<6;i++){
    cw[i]=(const float*)d_in[14+4*i]; cb[i]=(const float*)d_in[15+4*i];
    cg[i]=(const float*)d_in[16+4*i]; cbe[i]=(const float*)d_in[17+4*i];
  }
  const float* pcw = (const float*)d_in[38];
  const float* pcb = (const float*)d_in[39];
  const float* pcg = (const float*)d_in[40];
  const float* pcbe= (const float*)d_in[41];

  char* ws = (char*)d_ws;
  float* score = (float*)(ws + OFF_SCORE);
  float* xw    = (float*)(ws + OFF_XW);
  float* whx1  = (float*)(ws + OFF_WHX1);
  float* whx2  = (float*)(ws + OFF_WHX2);
  float* o1600 = (float*)(ws + OFF_O1600);
  float* whx3  = (float*)(ws + OFF_WHX3);
  float* w21   = (float*)(ws + OFF_W21);
  u16*   wb2   = (u16*)  (ws + OFF_WB2);
  u16*   wb3   = (u16*)  (ws + OFF_WB3);
  u16*   wb4   = (u16*)  (ws + OFF_WB4);
  u16*   wb5   = (u16*)  (ws + OFF_WB5);
  float* w26   = (float*)(ws + OFF_W26);
  float* par[6];
  for (int i=0;i<6;i++) par[i] = (float*)(ws + OFF_PAR + (size_t)i*768);
  float* ht = (float*)(ws + OFF_HT);
  float* ct = (float*)(ws + OFF_CT);
  u16* A32 = (u16*)(ws + OFF_A32);
  u16* B64 = (u16*)(ws + OFF_B64);
  u16* C64 = (u16*)(ws + OFF_C64);
  u16* P0  = (u16*)(ws + OFF_P0);
  u16* Y6  = (u16*)(ws + OFF_Y6);

  // 0) zero atomic accumulators + padded conv buffers (borders must be 0 every call)
  zero_k<<<4096,256,0,stream>>>((uint4*)(ws + OFF_HT), ZERO_BYTES/16);

  // 1) attention
  xw_k<<<1280,64,0,stream>>>(x, Wx, xw);
  score_k<<<2048,256,0,stream>>>(hs, pht, Wh, Wht, v, xw, score);
  softmax_k<<<128,256,0,stream>>>(score);
  wsum_k<<<dim3(128,8),128,0,stream>>>(hs, pc, score, ht, ct);

  // 2) dense layers to pre
  gemm_k<<<dim3(38,4),256,0,stream>>>(0,  600, 1200, ht, x,      W,   bb,  whx1);
  gemm_k<<<dim3(50,4),256,0,stream>>>(1, 1200, 1600, whx1, nullptr, rbw, rbb, whx2);
  scat_k<<<800,256,0,stream>>>(whx2, P0);

  // 3) conv block
  repack_k<<<2,  256,0,stream>>>(cw[0],cb[0],cg[0],cbe[0], w21, par[0],  1, 32);
  repack_mfma_k<<<72, 256,0,stream>>>(cw[1],cb[1],cg[1],cbe[1], wb2, par[1], 32, 64);
  repack_mfma_k<<<144,256,0,stream>>>(cw[2],cb[2],cg[2],cbe[2], wb3, par[2], 64, 64);
  repack_mfma_k<<<144,256,0,stream>>>(cw[3],cb[3],cg[3],cbe[3], wb4, par[3], 64, 64);
  repack_mfma_k<<<72, 256,0,stream>>>(cw[4],cb[4],cg[4],cbe[4], wb5, par[4], 64, 32);
  repack_k<<<2,  256,0,stream>>>(cw[5],cb[5],cg[5],cbe[5], w26, par[5], 32,  1);

  conv_main<1,32,true><<<dim3(128,8),256,0,stream>>>(P0, A32, w21, par[0]);
  conv_mfma<32,64><<<dim3(128,25),256,0,stream>>>(A32, B64, wb2, par[1]);
  conv_mfma<64,64><<<dim3(128,25),256,0,stream>>>(B64, C64, wb3, par[2]);
  conv_mfma<64,64><<<dim3(128,25),256,0,stream>>>(C64, B64, wb4, par[3]);
  conv_mfma<64,32><<<dim3(128,25),256,0,stream>>>(B64, A32, wb5, par[4]);
  conv_c6<<<800,256,0,stream>>>(A32, Y6, w26, par[5]);
  conv_pc<<<800,256,0,stream>>>(P0, Y6, pcw, pcb, pcg, pcbe, o1600);

  // 4) final projection + gating
  gemm_k<<<dim3(38,4),256,0,stream>>>(1, 1600, 1200, o1600, nullptr, rpw, rpb, whx3);
  gate_k<<<150,256,0,stream>>>(whx3, ct, (float*)d_out);
}

// Round 4
// 949.458 us; speedup vs baseline: 1.8070x; 1.0642x over previous
//
#include <hip/hip_runtime.h>
#include <cstdint>
#include <cstddef>

typedef unsigned short u16;

#define DEV __device__ __forceinline__

DEV float bf2f(u16 u){ union{unsigned int i; float f;} c; c.i = ((unsigned)u)<<16; return c.f; }
DEV u16 f2bf(float f){ union{float f;unsigned int i;} c; c.f=f; unsigned int r = c.i + 0x7FFFu + ((c.i>>16)&1u); return (u16)(r>>16); }

typedef __attribute__((ext_vector_type(8))) short bf16x8;
typedef __attribute__((ext_vector_type(4))) float f32x4;
typedef __attribute__((ext_vector_type(8))) unsigned short us8v;

// ---------------- workspace layout (bytes) ----------------
static constexpr size_t OFF_SCORE = 0;                                   // [128][1024] f32
static constexpr size_t OFF_XW    = OFF_SCORE + (size_t)128*1024*4;      // [128][16] f32
static constexpr size_t OFF_WHX1  = OFF_XW    + (size_t)128*16*4;        // [128][1200] f32
static constexpr size_t OFF_WHX2  = OFF_WHX1  + (size_t)128*1200*4;      // [128][1600] f32
static constexpr size_t OFF_O1600 = OFF_WHX2  + (size_t)128*1600*4;      // [128][1600] f32
static constexpr size_t OFF_WHX3  = OFF_O1600 + (size_t)128*1600*4;      // [128][1200] f32
static constexpr size_t OFF_W21   = OFF_WHX3  + (size_t)128*1200*4;      // conv1 w [ci][9][co] f32 (direct)
static constexpr size_t OFF_WB2   = OFF_W21   + (size_t)1*32*9*4;        // conv2 w [co=64][9][ci=32] bf16
static constexpr size_t OFF_WB3   = OFF_WB2   + (size_t)64*9*32*2;       // conv3 w [64][9][64] bf16
static constexpr size_t OFF_WB4   = OFF_WB3   + (size_t)64*9*64*2;       // conv4 w [64][9][64] bf16
static constexpr size_t OFF_WB5   = OFF_WB4   + (size_t)64*9*64*2;       // conv5 w [co=32][9][ci=64] bf16
static constexpr size_t OFF_W26   = OFF_WB5   + (size_t)32*9*64*2;       // conv6 w [ci][9][co=1] f32 (direct)
static constexpr size_t OFF_PAR   = OFF_W26   + (size_t)32*1*9*4;        // 6 x 768B: bias/scale/beta f32
static constexpr size_t OFF_HT    = OFF_PAR   + (size_t)6*768;           // [128][300] f32 (atomic acc, zeroed)
static constexpr size_t OFF_CT    = OFF_HT    + (size_t)128*300*4;       // [128][300] f32 (atomic acc, zeroed)
static constexpr size_t OFF_A32   = OFF_CT    + (size_t)128*300*4;       // [128][42*42][32] bf16 (border-zeroed)
static constexpr size_t OFF_B64   = OFF_A32   + (size_t)128*1764*32*2;   // [128][42*42][64] bf16 (border-zeroed)
static constexpr size_t OFF_C64   = OFF_B64   + (size_t)128*1764*64*2;   // [128][42*42][64] bf16 (border-zeroed)
static constexpr size_t OFF_P0    = OFF_C64   + (size_t)128*1764*64*2;   // [128][42*42] bf16 (pre, fully zeroed)
static constexpr size_t OFF_Y6    = OFF_P0    + (size_t)128*1764*2;      // [128][42*42] bf16 (fully zeroed)
static constexpr size_t OFF_END   = OFF_Y6    + (size_t)128*1764*2;
static constexpr size_t ZB1 = OFF_A32 - OFF_HT;     // HT+CT
static constexpr size_t ZB2 = OFF_END - OFF_P0;     // P0+Y6

// ---------------- zero init (grid-stride uint4) ----------------
__global__ void zero_k(uint4* __restrict__ p, size_t n){
  size_t i = (size_t)blockIdx.x*blockDim.x + threadIdx.x;
  uint4 z; z.x=0; z.y=0; z.z=0; z.w=0;
  for (; i < n; i += (size_t)gridDim.x*blockDim.x) p[i] = z;
}

// ---------------- zero the border ring of a [128][42][42][C] bf16 buffer ----------------
template<int C>
__global__ __launch_bounds__(256) void border_k(u16* __restrict__ buf){
  constexpr int CH = C/8;                       // 16B chunks per pixel
  int id = blockIdx.x*256 + threadIdx.x;
  int tot = 128*164*CH;
  if (id >= tot) return;
  int c8  = id % CH;
  int rem = id / CH;
  int i = rem % 164, b = rem / 164;
  int y, x;
  if      (i < 42){ y = 0;        x = i; }
  else if (i < 84){ y = 41;       x = i-42; }
  else if (i < 124){ y = i-84+1;  x = 0; }
  else             { y = i-124+1; x = 41; }
  us8v z = {0,0,0,0,0,0,0,0};
  *(us8v*)(buf + ((size_t)b*1764 + y*42 + x)*C + c8*8) = z;
}

// ---------------- xW[b][k] = sum_d x[b,d]*Wx[k,d] ----------------
__global__ __launch_bounds__(64) void xw_k(const float* __restrict__ x, const float* __restrict__ Wx,
                                           float* __restrict__ xw){
  int id = blockIdx.x;           // 128*10
  int b = id/10, k = id%10;
  int lane = threadIdx.x;
  float a = 0.f;
  for (int d = lane; d < 300; d += 64)
    a = fmaf(x[b*300+d], Wx[k*300+d], a);
  #pragma unroll
  for (int off=1; off<64; off<<=1) a += __shfl_xor(a, off);
  if (lane==0) xw[b*16+k] = a;
}

// ---------------- attention logits: lane owns one (b,t) row ----------------
// Weights read wave-uniformly -> s_load; FMA = v_fma(vdst, s_w, v_h). No shfl, no LDS.
__global__ __launch_bounds__(256) void score_k(const float* __restrict__ hs, const float* __restrict__ pht,
    const float* __restrict__ Wh, const float* __restrict__ Wht, const float* __restrict__ v,
    const float* __restrict__ xw, float* __restrict__ score){
  int rr = blockIdx.x*256 + threadIdx.x;         // 0..131071, grid 512
  int b = rr >> 10;
  const float* hr = hs  + (size_t)rr*300;
  const float* pr = pht + (size_t)rr*300;
  float acc[20];
  #pragma unroll
  for (int k=0;k<20;k++) acc[k]=0.f;
  #pragma unroll 1
  for (int d0=0; d0<288; d0+=16){
    float hv[16], pv[16];
    #pragma unroll
    for (int j=0;j<4;j++){
      float4 h4 = *(const float4*)(hr + d0 + 4*j);
      float4 p4 = *(const float4*)(pr + d0 + 4*j);
      hv[4*j]=h4.x; hv[4*j+1]=h4.y; hv[4*j+2]=h4.z; hv[4*j+3]=h4.w;
      pv[4*j]=p4.x; pv[4*j+1]=p4.y; pv[4*j+2]=p4.z; pv[4*j+3]=p4.w;
    }
    #pragma unroll
    for (int k=0;k<10;k++){
      #pragma unroll
      for (int j=0;j<16;j++)
        acc[k] = fmaf(hv[j], Wh[k*300 + d0 + j], acc[k]);
      #pragma unroll
      for (int j=0;j<16;j++)
        acc[10+k] = fmaf(pv[j], Wht[k*300 + d0 + j], acc[10+k]);
    }
  }
  { // tail d = 288..299
    float hv[12], pv[12];
    #pragma unroll
    for (int j=0;j<3;j++){
      float4 h4 = *(const float4*)(hr + 288 + 4*j);
      float4 p4 = *(const float4*)(pr + 288 + 4*j);
      hv[4*j]=h4.x; hv[4*j+1]=h4.y; hv[4*j+2]=h4.z; hv[4*j+3]=h4.w;
      pv[4*j]=p4.x; pv[4*j+1]=p4.y; pv[4*j+2]=p4.z; pv[4*j+3]=p4.w;
    }
    #pragma unroll
    for (int k=0;k<10;k++){
      #pragma unroll
      for (int j=0;j<12;j++){
        acc[k]    = fmaf(hv[j], Wh [k*300 + 288 + j], acc[k]);
        acc[10+k] = fmaf(pv[j], Wht[k*300 + 288 + j], acc[10+k]);
      }
    }
  }
  float sc = 0.f;
  #pragma unroll
  for (int k=0;k<10;k++) sc += v[k]*tanhf(acc[k] + acc[10+k] + xw[b*16+k]);
  score[rr] = sc;
}

// ---------------- softmax over T=1024, in-place ----------------
__global__ __launch_bounds__(256) void softmax_k(float* __restrict__ score){
  int b = blockIdx.x, tid = threadIdx.x;
  float* row = score + (size_t)b*1024;
  __shared__ float red[256];
  float m = -3.0e38f;
  #pragma unroll
  for (int j=0;j<4;j++) m = fmaxf(m, row[tid + j*256]);
  red[tid]=m; __syncthreads();
  for (int s=128;s>0;s>>=1){ if(tid<s) red[tid]=fmaxf(red[tid],red[tid+s]); __syncthreads(); }
  m = red[0]; __syncthreads();
  float vals[4], sum=0.f;
  #pragma unroll
  for (int j=0;j<4;j++){ vals[j] = expf(row[tid + j*256] - m); sum += vals[j]; }
  red[tid]=sum; __syncthreads();
  for (int s=128;s>0;s>>=1){ if(tid<s) red[tid]+=red[tid+s]; __syncthreads(); }
  float inv = 1.f/red[0];
  #pragma unroll
  for (int j=0;j<4;j++) row[tid + j*256] = vals[j]*inv;
}

// ---------------- ht = sum_t s*h ; ct = sum_t s*c (atomic partials) ----------------
__global__ __launch_bounds__(128) void wsum_k(const float* __restrict__ hs, const float* __restrict__ pc,
    const float* __restrict__ s, float* __restrict__ ht, float* __restrict__ ct){
  int b = blockIdx.x, chunk = blockIdx.y;
  int wave = threadIdx.x>>6, lane = threadIdx.x&63;
  float ah[4]={0,0,0,0}, ac[4]={0,0,0,0}, ah2[4]={0,0,0,0}, ac2[4]={0,0,0,0};
  int d1 = lane*4, d2 = 256 + lane*4;
  bool has2 = d2 < 300;                    // lanes 0..10
  int t0 = chunk*128;
  for (int t = t0 + wave; t < t0+128; t += 2){
    float sv = s[b*1024 + t];
    const float* hr = hs + ((size_t)(b*1024 + t))*300;
    const float* cr = pc + ((size_t)(b*1024 + t))*300;
    float4 h4 = *(const float4*)(hr + d1);
    float4 c4 = *(const float4*)(cr + d1);
    ah[0]=fmaf(sv,h4.x,ah[0]); ah[1]=fmaf(sv,h4.y,ah[1]);
    ah[2]=fmaf(sv,h4.z,ah[2]); ah[3]=fmaf(sv,h4.w,ah[3]);
    ac[0]=fmaf(sv,c4.x,ac[0]); ac[1]=fmaf(sv,c4.y,ac[1]);
    ac[2]=fmaf(sv,c4.z,ac[2]); ac[3]=fmaf(sv,c4.w,ac[3]);
    if (has2){
      float4 h5 = *(const float4*)(hr + d2);
      float4 c5 = *(const float4*)(cr + d2);
      ah2[0]=fmaf(sv,h5.x,ah2[0]); ah2[1]=fmaf(sv,h5.y,ah2[1]);
      ah2[2]=fmaf(sv,h5.z,ah2[2]); ah2[3]=fmaf(sv,h5.w,ah2[3]);
      ac2[0]=fmaf(sv,c5.x,ac2[0]); ac2[1]=fmaf(sv,c5.y,ac2[1]);
      ac2[2]=fmaf(sv,c5.z,ac2[2]); ac2[3]=fmaf(sv,c5.w,ac2[3]);
    }
  }
  #pragma unroll
  for (int j=0;j<4;j++){
    atomicAdd(&ht[b*300 + d1 + j], ah[j]);
    atomicAdd(&ct[b*300 + d1 + j], ac[j]);
  }
  if (has2){
    #pragma unroll
    for (int j=0;j<4;j++){
      atomicAdd(&ht[b*300 + d2 + j], ah2[j]);
      atomicAdd(&ct[b*300 + d2 + j], ac2[j]);
    }
  }
}

// ---------------- generic dense layer ----------------
__global__ __launch_bounds__(256) void gemm_k(int mode, int K, int N,
    const float* __restrict__ inA, const float* __restrict__ inX,
    const float* __restrict__ W, const float* __restrict__ bias, float* __restrict__ out){
  __shared__ float aL[32][65];
  __shared__ float wL[32][65];
  int n0 = blockIdx.x*32, b0 = blockIdx.y*32;
  int tid = threadIdx.x;
  int lr = tid>>3, lk = (tid&7)*8;
  int bi = tid>>4, ni = tid&15;
  float a00=0,a01=0,a10=0,a11=0;
  for (int kc=0; kc<K; kc+=64){
    int brow = b0+lr;
    #pragma unroll
    for (int j=0;j<8;j++){
      int k = kc+lk+j;
      float vv = 0.f;
      if (k<K){
        if (mode==0) vv = (k<300) ? inA[brow*300+k] : inX[brow*300 + (k-300)];
        else         vv = inA[(size_t)brow*K + k];
      }
      aL[lr][lk+j] = vv;
    }
    int nrow = n0+lr;
    #pragma unroll
    for (int j=0;j<8;j++){
      int k = kc+lk+j;
      float vv = 0.f;
      if (nrow<N && k<K) vv = W[(size_t)nrow*K + k];
      wL[lr][lk+j] = vv;
    }
    __syncthreads();
    #pragma unroll
    for (int kk=0;kk<64;kk++){
      float x0 = aL[2*bi][kk], x1 = aL[2*bi+1][kk];
      float y0 = wL[2*ni][kk], y1 = wL[2*ni+1][kk];
      a00 = fmaf(x0,y0,a00); a01 = fmaf(x0,y1,a01);
      a10 = fmaf(x1,y0,a10); a11 = fmaf(x1,y1,a11);
    }
    __syncthreads();
  }
  int b = b0 + 2*bi, n = n0 + 2*ni;
  if (n < N){
    float bb = bias[n];
    out[(size_t)b*N+n]     = a00+bb;
    out[(size_t)(b+1)*N+n] = a10+bb;
  }
  if (n+1 < N){
    float bb = bias[n+1];
    out[(size_t)b*N+n+1]     = a01+bb;
    out[(size_t)(b+1)*N+n+1] = a11+bb;
  }
}

// ---------------- scatter pre (whx2) into padded P0 (bf16) ----------------
__global__ __launch_bounds__(256) void scat_k(const float* __restrict__ whx2, u16* __restrict__ p0){
  int id = blockIdx.x*256 + threadIdx.x;          // 128*1600
  int b = id/1600, p = id%1600;
  int y = p/40, x = p%40;
  p0[(size_t)b*1764 + (y+1)*42 + (x+1)] = f2bf(whx2[id]);
}

// ---------------- conv weight repack (direct kernels): w2[ci][k][co] f32 ----------------
__global__ void repack_k(const float* __restrict__ w, const float* __restrict__ bb,
                         const float* __restrict__ g, const float* __restrict__ be,
                         float* __restrict__ w2, float* __restrict__ par, int CI, int CO){
  int id = blockIdx.x*256 + threadIdx.x;
  int tot = CI*CO*9;
  if (id < tot){
    int co = id % CO;
    int rem = id / CO;
    int k = rem % 9, ci = rem / 9;
    w2[id] = w[(co*CI + ci)*9 + k];
  }
  if (id < CO){
    par[id]      = bb[id];
    par[CO+id]   = g[id] * (1.0f/sqrtf(1.00001f));
    par[2*CO+id] = be[id];
  }
}

// ---------------- conv weight repack (MFMA kernels): wB[co][dydx][ci] bf16 ----------------
__global__ void repack_mfma_k(const float* __restrict__ w, const float* __restrict__ bb,
                              const float* __restrict__ g, const float* __restrict__ be,
                              u16* __restrict__ wB, float* __restrict__ par, int CI, int CO){
  int id = blockIdx.x*256 + threadIdx.x;
  int tot = CI*CO*9;
  if (id < tot){
    int ci = id % CI;
    int rem = id / CI;
    int dydx = rem % 9, co = rem / 9;
    wB[id] = f2bf(w[(co*CI + ci)*9 + dydx]);
  }
  if (id < CO){
    par[id]      = bb[id];
    par[CO+id]   = g[id] * (1.0f/sqrtf(1.00001f));
    par[2*CO+id] = be[id];
  }
}

// ---------------- implicit-GEMM MFMA conv 3x3 SAME + bias + relu + bn ----------------
// D[cout][pixel] = W x X.  A = weights [co][dydx][ci] bf16, B = NHWC input.
// grid (25 tiles, 128 batches): same-batch tiles launch-adjacent -> image L2-resident for 9x reuse.
template<int CI, int CO>
__global__ __launch_bounds__(256) void conv_mfma(const u16* __restrict__ in, u16* __restrict__ out,
    const u16* __restrict__ wB, const float* __restrict__ par){
  constexpr int MF = CO/16;          // M-frags (cout groups)
  constexpr int KROW = CI*9;         // A row length in elems
  int tile = blockIdx.x;             // 0..24
  int b = blockIdx.y;
  int w = threadIdx.x>>6, l = threadIdx.x&63;
  int col = l & 15;
  int kg  = (l>>4)*8;
  int p = tile*64 + w*16 + col;      // output pixel 0..1599
  int y = p/40, x = p%40;
  const u16* inb = in + (size_t)b*1764*CI;
  f32x4 acc[MF];
  #pragma unroll
  for (int m=0;m<MF;m++) acc[m] = (f32x4){0.f,0.f,0.f,0.f};
  #pragma unroll
  for (int dy=0;dy<3;dy++)
  #pragma unroll
  for (int dx=0;dx<3;dx++){
    int dydx = dy*3+dx;
    const u16* bp = inb + (size_t)((y+dy)*42 + (x+dx))*CI + kg;
    const u16* ap = wB + (size_t)col*KROW + dydx*CI + kg;
    #pragma unroll
    for (int kc=0; kc<CI; kc+=32){
      bf16x8 bf = *(const bf16x8*)(bp + kc);
      #pragma unroll
      for (int m=0;m<MF;m++){
        bf16x8 af = *(const bf16x8*)(ap + (size_t)m*16*KROW + kc);
        acc[m] = __builtin_amdgcn_mfma_f32_16x16x32_bf16(af, bf, acc[m], 0, 0, 0);
      }
    }
  }
  u16* ob = out + (size_t)b*1764*CO + (size_t)((y+1)*42 + (x+1))*CO;
  #pragma unroll
  for (int m=0;m<MF;m++){
    int co0 = m*16 + (l>>4)*4;
    const float4 bia = *(const float4*)(par + co0);
    const float4 sc  = *(const float4*)(par + CO + co0);
    const float4 be  = *(const float4*)(par + 2*CO + co0);
    ushort4 s;
    s.x = f2bf(fmaxf(acc[m][0]+bia.x,0.f)*sc.x + be.x);
    s.y = f2bf(fmaxf(acc[m][1]+bia.y,0.f)*sc.y + be.y);
    s.z = f2bf(fmaxf(acc[m][2]+bia.z,0.f)*sc.z + be.z);
    s.w = f2bf(fmaxf(acc[m][3]+bia.w,0.f)*sc.w + be.w);
    *(ushort4*)(ob + co0) = s;
  }
}

// ---------------- conv1 direct 1->32 (tiny K, keep direct) ----------------
template<int CI, int CO, bool TT>
__global__ __launch_bounds__(256) void conv_main(const u16* __restrict__ in, u16* __restrict__ out,
    const float* __restrict__ w2, const float* __restrict__ par){
  int b = blockIdx.x;
  int wave = threadIdx.x >> 6;
  int lane = threadIdx.x & 63;
  int tile, co;
  if (TT){ tile = blockIdx.y*8 + wave*2 + (lane>>5); co = lane & 31; }
  else   { tile = blockIdx.y*4 + wave;               co = lane; }
  int y0 = (tile >> 3)*5, x0 = (tile & 7)*5;          // padded window origin
  const u16* inb = in + (size_t)b*1764*CI;
  float acc[25];
  #pragma unroll
  for (int p=0;p<25;p++) acc[p]=0.f;
  for (int ci=0; ci<CI; ci++){
    float win[49];
    #pragma unroll
    for (int r=0;r<7;r++)
      #pragma unroll
      for (int c=0;c<7;c++)
        win[r*7+c] = bf2f(inb[ ((y0+r)*42 + (x0+c))*CI + ci ]);
    float wk[9];
    #pragma unroll
    for (int k=0;k<9;k++) wk[k] = w2[(ci*9+k)*CO + co];
    #pragma unroll
    for (int py=0;py<5;py++)
      #pragma unroll
      for (int px=0;px<5;px++){
        float s = acc[py*5+px];
        #pragma unroll
        for (int dy=0;dy<3;dy++)
          #pragma unroll
          for (int dx=0;dx<3;dx++)
            s = fmaf(wk[dy*3+dx], win[(py+dy)*7 + (px+dx)], s);
        acc[py*5+px] = s;
      }
  }
  float bia = par[co], sc = par[CO+co], be = par[2*CO+co];
  u16* outb = out + (size_t)b*1764*CO;
  #pragma unroll
  for (int py=0;py<5;py++)
    #pragma unroll
    for (int px=0;px<5;px++){
      float vv = fmaxf(acc[py*5+px] + bia, 0.f)*sc + be;
      outb[ ((y0+py+1)*42 + (x0+px+1))*CO + co ] = f2bf(vv);
    }
}

// ---------------- c6: 32 -> 1 channel (vectorized input loads) ----------------
__global__ __launch_bounds__(256) void conv_c6(const u16* __restrict__ in, u16* __restrict__ y6,
    const float* __restrict__ w6, const float* __restrict__ par6){
  int id = blockIdx.x*256 + threadIdx.x;          // 128*1600
  int b = id/1600, p = id%1600;
  int y = p/40, x = p%40;
  const u16* inb = in + (size_t)b*1764*32;
  float acc = 0.f;
  #pragma unroll
  for (int dy=0;dy<3;dy++)
    #pragma unroll
    for (int dx=0;dx<3;dx++){
      const u16* q = inb + ((y+dy)*42 + (x+dx))*32;
      int k = dy*3+dx;
      #pragma unroll
      for (int g=0; g<4; g++){
        us8v vv8 = *(const us8v*)(q + g*8);
        #pragma unroll
        for (int j=0;j<8;j++)
          acc = fmaf(w6[(g*8+j)*9 + k], bf2f(vv8[j]), acc);
      }
    }
  float vv = fmaxf(acc + par6[0], 0.f)*par6[1] + par6[2];
  y6[(size_t)b*1764 + (y+1)*42 + (x+1)] = f2bf(vv);
}

// ---------------- pc: concat(pre, y6) 2 -> 1 channel, no relu ----------------
__global__ __launch_bounds__(256) void conv_pc(const u16* __restrict__ p0, const u16* __restrict__ y6,
    const float* __restrict__ pcw, const float* __restrict__ pcb,
    const float* __restrict__ pcg, const float* __restrict__ pcbe,
    float* __restrict__ out1600){
  int id = blockIdx.x*256 + threadIdx.x;          // 128*1600
  int b = id/1600, p = id%1600;
  int y = p/40, x = p%40;
  float acc = 0.f;
  #pragma unroll
  for (int dy=0;dy<3;dy++)
    #pragma unroll
    for (int dx=0;dx<3;dx++){
      size_t o = (size_t)b*1764 + (y+dy)*42 + (x+dx);
      acc = fmaf(pcw[dy*3+dx],     bf2f(p0[o]), acc);
      acc = fmaf(pcw[9 + dy*3+dx], bf2f(y6[o]), acc);
    }
  float sc = pcg[0] * (1.0f/sqrtf(1.00001f));
  out1600[id] = (acc + pcb[0])*sc + pcbe[0];
}

// ---------------- LSTM gating ----------------
__global__ __launch_bounds__(256) void gate_k(const float* __restrict__ whx3, const float* __restrict__ ct,
                                              float* __restrict__ outp){
  int id = blockIdx.x*256 + threadIdx.x;          // 128*300
  if (id >= 38400) return;
  int b = id/300, d = id%300;
  const float* r = whx3 + (size_t)b*1200;
  float ft = 1.f/(1.f+expf(-r[d]));
  float ot = 1.f/(1.f+expf(-r[300+d]));
  float it = 1.f/(1.f+expf(-r[600+d]));
  float ch = tanhf(r[900+d]);
  float c  = ft*ct[id] + it*ch;
  outp[id] = ot*tanhf(c);
}

extern "C" void kernel_launch(void* const* d_in, const int* in_sizes, int n_in,
                              void* d_out, int out_size, void* d_ws, size_t ws_size,
                              hipStream_t stream){
  const float* x    = (const float*)d_in[0];
  const float* hs   = (const float*)d_in[1];
  const float* pht  = (const float*)d_in[2];
  const float* pc   = (const float*)d_in[3];
  const float* W    = (const float*)d_in[4];
  const float* bb   = (const float*)d_in[5];
  const float* Wh   = (const float*)d_in[6];
  const float* Wx   = (const float*)d_in[7];
  const float* Wht  = (const float*)d_in[8];
  const float* v    = (const float*)d_in[9];
  const float* rbw  = (const float*)d_in[10];
  const float* rbb  = (const float*)d_in[11];
  const float* rpw  = (const float*)d_in[12];
  const float* rpb  = (const float*)d_in[13];
  const float *cw[6], *cb[6], *cg[6], *cbe[6];
  for (int i=0;i<6;i++){
    cw[i]=(const float*)d_in[14+4*i]; cb[i]=(const float*)d_in[15+4*i];
    cg[i]=(const float*)d_in[16+4*i]; cbe[i]=(const float*)d_in[17+4*i];
  }
  const float* pcw = (const float*)d_in[38];
  const float* pcb = (const float*)d_in[39];
  const float* pcg = (const float*)d_in[40];
  const float* pcbe= (const float*)d_in[41];

  char* ws = (char*)d_ws;
  float* score = (float*)(ws + OFF_SCORE);
  float* xw    = (float*)(ws + OFF_XW);
  float* whx1  = (float*)(ws + OFF_WHX1);
  float* whx2  = (float*)(ws + OFF_WHX2);
  float* o1600 = (float*)(ws + OFF_O1600);
  float* whx3  = (float*)(ws + OFF_WHX3);
  float* w21   = (float*)(ws + OFF_W21);
  u16*   wb2   = (u16*)  (ws + OFF_WB2);
  u16*   wb3   = (u16*)  (ws + OFF_WB3);
  u16*   wb4   = (u16*)  (ws + OFF_WB4);
  u16*   wb5   = (u16*)  (ws + OFF_WB5);
  float* w26   = (float*)(ws + OFF_W26);
  float* par[6];
  for (int i=0;i<6;i++) par[i] = (float*)(ws + OFF_PAR + (size_t)i*768);
  float* ht = (float*)(ws + OFF_HT);
  float* ct = (float*)(ws + OFF_CT);
  u16* A32 = (u16*)(ws + OFF_A32);
  u16* B64 = (u16*)(ws + OFF_B64);
  u16* C64 = (u16*)(ws + OFF_C64);
  u16* P0  = (u16*)(ws + OFF_P0);
  u16* Y6  = (u16*)(ws + OFF_Y6);

  // 0) zero: atomic accumulators, P0/Y6 (fully), border rings of NHWC bufs
  zero_k<<<75, 256,0,stream>>>((uint4*)(ws + OFF_HT), ZB1/16);
  zero_k<<<221,256,0,stream>>>((uint4*)(ws + OFF_P0), ZB2/16);
  border_k<32><<<(128*164*4 +255)/256,256,0,stream>>>(A32);
  border_k<64><<<(128*164*8 +255)/256,256,0,stream>>>(B64);
  border_k<64><<<(128*164*8 +255)/256,256,0,stream>>>(C64);

  // 1) attention
  xw_k<<<1280,64,0,stream>>>(x, Wx, xw);
  score_k<<<512,256,0,stream>>>(hs, pht, Wh, Wht, v, xw, score);
  softmax_k<<<128,256,0,stream>>>(score);
  wsum_k<<<dim3(128,8),128,0,stream>>>(hs, pc, score, ht, ct);

  // 2) dense layers to pre
  gemm_k<<<dim3(38,4),256,0,stream>>>(0,  600, 1200, ht, x,      W,   bb,  whx1);
  gemm_k<<<dim3(50,4),256,0,stream>>>(1, 1200, 1600, whx1, nullptr, rbw, rbb, whx2);
  scat_k<<<800,256,0,stream>>>(whx2, P0);

  // 3) conv block
  repack_k<<<2,  256,0,stream>>>(cw[0],cb[0],cg[0],cbe[0], w21, par[0],  1, 32);
  repack_mfma_k<<<72, 256,0,stream>>>(cw[1],cb[1],cg[1],cbe[1], wb2, par[1], 32, 64);
  repack_mfma_k<<<144,256,0,stream>>>(cw[2],cb[2],cg[2],cbe[2], wb3, par[2], 64, 64);
  repack_mfma_k<<<144,256,0,stream>>>(cw[3],cb[3],cg[3],cbe[3], wb4, par[3], 64, 64);
  repack_mfma_k<<<72, 256,0,stream>>>(cw[4],cb[4],cg[4],cbe[4], wb5, par[4], 64, 32);
  repack_k<<<2,  256,0,stream>>>(cw[5],cb[5],cg[5],cbe[5], w26, par[5], 32,  1);

  conv_main<1,32,true><<<dim3(128,8),256,0,stream>>>(P0, A32, w21, par[0]);
  conv_mfma<32,64><<<dim3(25,128),256,0,stream>>>(A32, B64, wb2, par[1]);
  conv_mfma<64,64><<<dim3(25,128),256,0,stream>>>(B64, C64, wb3, par[2]);
  conv_mfma<64,64><<<dim3(25,128),256,0,stream>>>(C64, B64, wb4, par[3]);
  conv_mfma<64,32><<<dim3(25,128),256,0,stream>>>(B64, A32, wb5, par[4]);
  conv_c6<<<800,256,0,stream>>>(A32, Y6, w26, par[5]);
  conv_pc<<<800,256,0,stream>>>(P0, Y6, pcw, pcb, pcg, pcbe, o1600);

  // 4) final projection + gating
  gemm_k<<<dim3(38,4),256,0,stream>>>(1, 1600, 1200, o1600, nullptr, rpw, rpb, whx3);
  gate_k<<<150,256,0,stream>>>(whx3, ct, (float*)d_out);
}

// Round 5
// 861.060 us; speedup vs baseline: 1.9925x; 1.1027x over previous
//
#include <hip/hip_runtime.h>
#include <cstdint>
#include <cstddef>

typedef unsigned short u16;

#define DEV __device__ __forceinline__

DEV float bf2f(u16 u){ union{unsigned int i; float f;} c; c.i = ((unsigned)u)<<16; return c.f; }
DEV u16 f2bf(float f){ union{float f;unsigned int i;} c; c.f=f; unsigned int r = c.i + 0x7FFFu + ((c.i>>16)&1u); return (u16)(r>>16); }

typedef __attribute__((ext_vector_type(8))) short bf16x8;
typedef __attribute__((ext_vector_type(4))) float f32x4;
typedef __attribute__((ext_vector_type(8))) unsigned short us8v;

// ---------------- workspace layout (bytes) ----------------
static constexpr size_t OFF_SCORE = 0;                                   // [128][1024] f32
static constexpr size_t OFF_XW    = OFF_SCORE + (size_t)128*1024*4;      // [128][16] f32
static constexpr size_t OFF_WHX1  = OFF_XW    + (size_t)128*16*4;        // [128][1200] f32
static constexpr size_t OFF_WHX2  = OFF_WHX1  + (size_t)128*1200*4;      // [128][1600] f32
static constexpr size_t OFF_O1600 = OFF_WHX2  + (size_t)128*1600*4;      // [128][1600] f32
static constexpr size_t OFF_WHX3  = OFF_O1600 + (size_t)128*1600*4;      // [128][1200] f32
static constexpr size_t OFF_W21   = OFF_WHX3  + (size_t)128*1200*4;      // conv1 w [ci][9][co] f32 (direct)
static constexpr size_t OFF_WB2   = OFF_W21   + (size_t)1*32*9*4;        // conv2 w [co=64][9][ci=32] bf16
static constexpr size_t OFF_WB3   = OFF_WB2   + (size_t)64*9*32*2;       // conv3 w [64][9][64] bf16
static constexpr size_t OFF_WB4   = OFF_WB3   + (size_t)64*9*64*2;       // conv4 w [64][9][64] bf16
static constexpr size_t OFF_WB5   = OFF_WB4   + (size_t)64*9*64*2;       // conv5 w [co=32][9][ci=64] bf16
static constexpr size_t OFF_W26   = OFF_WB5   + (size_t)32*9*64*2;       // conv6 w [ci][9][co=1] f32 (direct)
static constexpr size_t OFF_PAR   = OFF_W26   + (size_t)32*1*9*4;        // 6 x 768B: bias/scale/beta f32
static constexpr size_t OFF_HT    = OFF_PAR   + (size_t)6*768;           // [128][300] f32 (atomic acc, zeroed)
static constexpr size_t OFF_CT    = OFF_HT    + (size_t)128*300*4;       // [128][300] f32 (atomic acc, zeroed)
static constexpr size_t OFF_A32   = OFF_CT    + (size_t)128*300*4;       // [128][42*42][32] bf16 (border-zeroed)
static constexpr size_t OFF_B64   = OFF_A32   + (size_t)128*1764*32*2;   // [128][42*42][64] bf16 (border-zeroed)
static constexpr size_t OFF_C64   = OFF_B64   + (size_t)128*1764*64*2;   // [128][42*42][64] bf16 (border-zeroed)
static constexpr size_t OFF_P0    = OFF_C64   + (size_t)128*1764*64*2;   // [128][42*42] bf16 (pre, fully zeroed)
static constexpr size_t OFF_Y6    = OFF_P0    + (size_t)128*1764*2;      // [128][42*42] bf16 (fully zeroed)
static constexpr size_t OFF_END   = OFF_Y6    + (size_t)128*1764*2;
static constexpr size_t ZB1 = OFF_A32 - OFF_HT;     // HT+CT
static constexpr size_t ZB2 = OFF_END - OFF_P0;     // P0+Y6

// ---------------- zero init (grid-stride uint4) ----------------
__global__ void zero_k(uint4* __restrict__ p, size_t n){
  size_t i = (size_t)blockIdx.x*blockDim.x + threadIdx.x;
  uint4 z; z.x=0; z.y=0; z.z=0; z.w=0;
  for (; i < n; i += (size_t)gridDim.x*blockDim.x) p[i] = z;
}

// ---------------- zero the border ring of a [128][42][42][C] bf16 buffer ----------------
template<int C>
__global__ __launch_bounds__(256) void border_k(u16* __restrict__ buf){
  constexpr int CH = C/8;                       // 16B chunks per pixel
  int id = blockIdx.x*256 + threadIdx.x;
  int tot = 128*164*CH;
  if (id >= tot) return;
  int c8  = id % CH;
  int rem = id / CH;
  int i = rem % 164, b = rem / 164;
  int y, x;
  if      (i < 42){ y = 0;        x = i; }
  else if (i < 84){ y = 41;       x = i-42; }
  else if (i < 124){ y = i-84+1;  x = 0; }
  else             { y = i-124+1; x = 41; }
  us8v z = {0,0,0,0,0,0,0,0};
  *(us8v*)(buf + ((size_t)b*1764 + y*42 + x)*C + c8*8) = z;
}

// ---------------- xW[b][k] = sum_d x[b,d]*Wx[k,d] ----------------
__global__ __launch_bounds__(64) void xw_k(const float* __restrict__ x, const float* __restrict__ Wx,
                                           float* __restrict__ xw){
  int id = blockIdx.x;           // 128*10
  int b = id/10, k = id%10;
  int lane = threadIdx.x;
  float a = 0.f;
  for (int d = lane; d < 300; d += 64)
    a = fmaf(x[b*300+d], Wx[k*300+d], a);
  #pragma unroll
  for (int off=1; off<64; off<<=1) a += __shfl_xor(a, off);
  if (lane==0) xw[b*16+k] = a;
}

// ---------------- attention logits: LDS-transposed staging + lane-owns-row compute ----------------
// Stage: 4 consecutive lanes share one row's 64B segment (16 lines/instr, fully consumed).
// LDS [16][260] transposed: writes 2-way (free), reads stride-1 (free).
// Compute: lane owns row tid; weights via wave-uniform s_load; zero shfl.
__global__ __launch_bounds__(256) void score_k(const float* __restrict__ hs, const float* __restrict__ pht,
    const float* __restrict__ Wh, const float* __restrict__ Wht, const float* __restrict__ v,
    const float* __restrict__ xw, float* __restrict__ score){
  __shared__ float HL[16][260];
  __shared__ float PL[16][260];
  int tid = threadIdx.x;
  int q = tid & 3, rg = tid >> 2;          // quad 0..3, rowgroup 0..63
  int rr0 = blockIdx.x*256;
  int b = rr0 >> 10;                        // 256-row blocks never straddle batches
  float acc[20];
  #pragma unroll
  for (int k=0;k<20;k++) acc[k]=0.f;
  float4 ph[4], pp[4];
  #pragma unroll
  for (int i=0;i<4;i++){                    // prefetch chunk 0
    size_t r = (size_t)(rr0 + rg + 64*i)*300 + q*4;
    ph[i] = *(const float4*)(hs  + r);
    pp[i] = *(const float4*)(pht + r);
  }
  #pragma unroll 1
  for (int c=0; c<19; c++){
    int d0 = (c<18) ? c*16 : 284;           // tail overlaps; j<4 skipped there
    __syncthreads();
    #pragma unroll
    for (int i=0;i<4;i++){
      int col = rg + 64*i;
      HL[q*4+0][col]=ph[i].x; HL[q*4+1][col]=ph[i].y; HL[q*4+2][col]=ph[i].z; HL[q*4+3][col]=ph[i].w;
      PL[q*4+0][col]=pp[i].x; PL[q*4+1][col]=pp[i].y; PL[q*4+2][col]=pp[i].z; PL[q*4+3][col]=pp[i].w;
    }
    __syncthreads();
    if (c < 18){                            // prefetch next chunk (hides HBM under FMAs below)
      int d1 = (c<17) ? (c+1)*16 : 284;
      #pragma unroll
      for (int i=0;i<4;i++){
        size_t r = (size_t)(rr0 + rg + 64*i)*300 + d1 + q*4;
        ph[i] = *(const float4*)(hs  + r);
        pp[i] = *(const float4*)(pht + r);
      }
    }
    float hv[16], pv[16];
    #pragma unroll
    for (int j=0;j<16;j++){ hv[j]=HL[j][tid]; pv[j]=PL[j][tid]; }
    if (c < 18){
      #pragma unroll
      for (int k=0;k<10;k++){
        #pragma unroll
        for (int j=0;j<16;j++){
          acc[k]    = fmaf(hv[j], Wh [k*300+d0+j], acc[k]);
          acc[10+k] = fmaf(pv[j], Wht[k*300+d0+j], acc[10+k]);
        }
      }
    } else {
      #pragma unroll
      for (int k=0;k<10;k++){
        #pragma unroll
        for (int j=4;j<16;j++){
          acc[k]    = fmaf(hv[j], Wh [k*300+d0+j], acc[k]);
          acc[10+k] = fmaf(pv[j], Wht[k*300+d0+j], acc[10+k]);
        }
      }
    }
  }
  float sc = 0.f;
  #pragma unroll
  for (int k=0;k<10;k++) sc += v[k]*tanhf(acc[k] + acc[10+k] + xw[b*16+k]);
  score[rr0 + tid] = sc;
}

// ---------------- softmax over T=1024, in-place ----------------
__global__ __launch_bounds__(256) void softmax_k(float* __restrict__ score){
  int b = blockIdx.x, tid = threadIdx.x;
  float* row = score + (size_t)b*1024;
  __shared__ float red[256];
  float m = -3.0e38f;
  #pragma unroll
  for (int j=0;j<4;j++) m = fmaxf(m, row[tid + j*256]);
  red[tid]=m; __syncthreads();
  for (int s=128;s>0;s>>=1){ if(tid<s) red[tid]=fmaxf(red[tid],red[tid+s]); __syncthreads(); }
  m = red[0]; __syncthreads();
  float vals[4], sum=0.f;
  #pragma unroll
  for (int j=0;j<4;j++){ vals[j] = expf(row[tid + j*256] - m); sum += vals[j]; }
  red[tid]=sum; __syncthreads();
  for (int s=128;s>0;s>>=1){ if(tid<s) red[tid]+=red[tid+s]; __syncthreads(); }
  float inv = 1.f/red[0];
  #pragma unroll
  for (int j=0;j<4;j++) row[tid + j*256] = vals[j]*inv;
}

// ---------------- ht = sum_t s*h ; ct = sum_t s*c (atomic partials) ----------------
__global__ __launch_bounds__(128) void wsum_k(const float* __restrict__ hs, const float* __restrict__ pc,
    const float* __restrict__ s, float* __restrict__ ht, float* __restrict__ ct){
  int b = blockIdx.x, chunk = blockIdx.y;
  int wave = threadIdx.x>>6, lane = threadIdx.x&63;
  float ah[4]={0,0,0,0}, ac[4]={0,0,0,0}, ah2[4]={0,0,0,0}, ac2[4]={0,0,0,0};
  int d1 = lane*4, d2 = 256 + lane*4;
  bool has2 = d2 < 300;                    // lanes 0..10
  int t0 = chunk*128;
  for (int t = t0 + wave; t < t0+128; t += 2){
    float sv = s[b*1024 + t];
    const float* hr = hs + ((size_t)(b*1024 + t))*300;
    const float* cr = pc + ((size_t)(b*1024 + t))*300;
    float4 h4 = *(const float4*)(hr + d1);
    float4 c4 = *(const float4*)(cr + d1);
    ah[0]=fmaf(sv,h4.x,ah[0]); ah[1]=fmaf(sv,h4.y,ah[1]);
    ah[2]=fmaf(sv,h4.z,ah[2]); ah[3]=fmaf(sv,h4.w,ah[3]);
    ac[0]=fmaf(sv,c4.x,ac[0]); ac[1]=fmaf(sv,c4.y,ac[1]);
    ac[2]=fmaf(sv,c4.z,ac[2]); ac[3]=fmaf(sv,c4.w,ac[3]);
    if (has2){
      float4 h5 = *(const float4*)(hr + d2);
      float4 c5 = *(const float4*)(cr + d2);
      ah2[0]=fmaf(sv,h5.x,ah2[0]); ah2[1]=fmaf(sv,h5.y,ah2[1]);
      ah2[2]=fmaf(sv,h5.z,ah2[2]); ah2[3]=fmaf(sv,h5.w,ah2[3]);
      ac2[0]=fmaf(sv,c5.x,ac2[0]); ac2[1]=fmaf(sv,c5.y,ac2[1]);
      ac2[2]=fmaf(sv,c5.z,ac2[2]); ac2[3]=fmaf(sv,c5.w,ac2[3]);
    }
  }
  #pragma unroll
  for (int j=0;j<4;j++){
    atomicAdd(&ht[b*300 + d1 + j], ah[j]);
    atomicAdd(&ct[b*300 + d1 + j], ac[j]);
  }
  if (has2){
    #pragma unroll
    for (int j=0;j<4;j++){
      atomicAdd(&ht[b*300 + d2 + j], ah2[j]);
      atomicAdd(&ct[b*300 + d2 + j], ac2[j]);
    }
  }
}

// ---------------- generic dense layer ----------------
__global__ __launch_bounds__(256) void gemm_k(int mode, int K, int N,
    const float* __restrict__ inA, const float* __restrict__ inX,
    const float* __restrict__ W, const float* __restrict__ bias, float* __restrict__ out){
  __shared__ float aL[32][65];
  __shared__ float wL[32][65];
  int n0 = blockIdx.x*32, b0 = blockIdx.y*32;
  int tid = threadIdx.x;
  int lr = tid>>3, lk = (tid&7)*8;
  int bi = tid>>4, ni = tid&15;
  float a00=0,a01=0,a10=0,a11=0;
  for (int kc=0; kc<K; kc+=64){
    int brow = b0+lr;
    #pragma unroll
    for (int j=0;j<8;j++){
      int k = kc+lk+j;
      float vv = 0.f;
      if (k<K){
        if (mode==0) vv = (k<300) ? inA[brow*300+k] : inX[brow*300 + (k-300)];
        else         vv = inA[(size_t)brow*K + k];
      }
      aL[lr][lk+j] = vv;
    }
    int nrow = n0+lr;
    #pragma unroll
    for (int j=0;j<8;j++){
      int k = kc+lk+j;
      float vv = 0.f;
      if (nrow<N && k<K) vv = W[(size_t)nrow*K + k];
      wL[lr][lk+j] = vv;
    }
    __syncthreads();
    #pragma unroll
    for (int kk=0;kk<64;kk++){
      float x0 = aL[2*bi][kk], x1 = aL[2*bi+1][kk];
      float y0 = wL[2*ni][kk], y1 = wL[2*ni+1][kk];
      a00 = fmaf(x0,y0,a00); a01 = fmaf(x0,y1,a01);
      a10 = fmaf(x1,y0,a10); a11 = fmaf(x1,y1,a11);
    }
    __syncthreads();
  }
  int b = b0 + 2*bi, n = n0 + 2*ni;
  if (n < N){
    float bb = bias[n];
    out[(size_t)b*N+n]     = a00+bb;
    out[(size_t)(b+1)*N+n] = a10+bb;
  }
  if (n+1 < N){
    float bb = bias[n+1];
    out[(size_t)b*N+n+1]     = a01+bb;
    out[(size_t)(b+1)*N+n+1] = a11+bb;
  }
}

// ---------------- scatter pre (whx2) into padded P0 (bf16) ----------------
__global__ __launch_bounds__(256) void scat_k(const float* __restrict__ whx2, u16* __restrict__ p0){
  int id = blockIdx.x*256 + threadIdx.x;          // 128*1600
  int b = id/1600, p = id%1600;
  int y = p/40, x = p%40;
  p0[(size_t)b*1764 + (y+1)*42 + (x+1)] = f2bf(whx2[id]);
}

// ---------------- conv weight repack (direct kernels): w2[ci][k][co] f32 ----------------
__global__ void repack_k(const float* __restrict__ w, const float* __restrict__ bb,
                         const float* __restrict__ g, const float* __restrict__ be,
                         float* __restrict__ w2, float* __restrict__ par, int CI, int CO){
  int id = blockIdx.x*256 + threadIdx.x;
  int tot = CI*CO*9;
  if (id < tot){
    int co = id % CO;
    int rem = id / CO;
    int k = rem % 9, ci = rem / 9;
    w2[id] = w[(co*CI + ci)*9 + k];
  }
  if (id < CO){
    par[id]      = bb[id];
    par[CO+id]   = g[id] * (1.0f/sqrtf(1.00001f));
    par[2*CO+id] = be[id];
  }
}

// ---------------- conv weight repack (MFMA kernels): wB[co][dydx][ci] bf16 ----------------
__global__ void repack_mfma_k(const float* __restrict__ w, const float* __restrict__ bb,
                              const float* __restrict__ g, const float* __restrict__ be,
                              u16* __restrict__ wB, float* __restrict__ par, int CI, int CO){
  int id = blockIdx.x*256 + threadIdx.x;
  int tot = CI*CO*9;
  if (id < tot){
    int ci = id % CI;
    int rem = id / CI;
    int dydx = rem % 9, co = rem / 9;
    wB[id] = f2bf(w[(co*CI + ci)*9 + dydx]);
  }
  if (id < CO){
    par[id]      = bb[id];
    par[CO+id]   = g[id] * (1.0f/sqrtf(1.00001f));
    par[2*CO+id] = be[id];
  }
}

// ---------------- implicit-GEMM MFMA conv 3x3 SAME + bias + relu + bn ----------------
template<int CI, int CO>
__global__ __launch_bounds__(256) void conv_mfma(const u16* __restrict__ in, u16* __restrict__ out,
    const u16* __restrict__ wB, const float* __restrict__ par){
  constexpr int MF = CO/16;          // M-frags (cout groups)
  constexpr int KROW = CI*9;         // A row length in elems
  int tile = blockIdx.x;             // 0..24
  int b = blockIdx.y;
  int w = threadIdx.x>>6, l = threadIdx.x&63;
  int col = l & 15;
  int kg  = (l>>4)*8;
  int p = tile*64 + w*16 + col;      // output pixel 0..1599
  int y = p/40, x = p%40;
  const u16* inb = in + (size_t)b*1764*CI;
  f32x4 acc[MF];
  #pragma unroll
  for (int m=0;m<MF;m++) acc[m] = (f32x4){0.f,0.f,0.f,0.f};
  #pragma unroll
  for (int dy=0;dy<3;dy++)
  #pragma unroll
  for (int dx=0;dx<3;dx++){
    int dydx = dy*3+dx;
    const u16* bp = inb + (size_t)((y+dy)*42 + (x+dx))*CI + kg;
    const u16* ap = wB + (size_t)col*KROW + dydx*CI + kg;
    #pragma unroll
    for (int kc=0; kc<CI; kc+=32){
      bf16x8 bf = *(const bf16x8*)(bp + kc);
      #pragma unroll
      for (int m=0;m<MF;m++){
        bf16x8 af = *(const bf16x8*)(ap + (size_t)m*16*KROW + kc);
        acc[m] = __builtin_amdgcn_mfma_f32_16x16x32_bf16(af, bf, acc[m], 0, 0, 0);
      }
    }
  }
  u16* ob = out + (size_t)b*1764*CO + (size_t)((y+1)*42 + (x+1))*CO;
  #pragma unroll
  for (int m=0;m<MF;m++){
    int co0 = m*16 + (l>>4)*4;
    const float4 bia = *(const float4*)(par + co0);
    const float4 sc  = *(const float4*)(par + CO + co0);
    const float4 be  = *(const float4*)(par + 2*CO + co0);
    ushort4 s;
    s.x = f2bf(fmaxf(acc[m][0]+bia.x,0.f)*sc.x + be.x);
    s.y = f2bf(fmaxf(acc[m][1]+bia.y,0.f)*sc.y + be.y);
    s.z = f2bf(fmaxf(acc[m][2]+bia.z,0.f)*sc.z + be.z);
    s.w = f2bf(fmaxf(acc[m][3]+bia.w,0.f)*sc.w + be.w);
    *(ushort4*)(ob + co0) = s;
  }
}

// ---------------- conv1 direct 1->32 (tiny K, keep direct) ----------------
template<int CI, int CO, bool TT>
__global__ __launch_bounds__(256) void conv_main(const u16* __restrict__ in, u16* __restrict__ out,
    const float* __restrict__ w2, const float* __restrict__ par){
  int b = blockIdx.x;
  int wave = threadIdx.x >> 6;
  int lane = threadIdx.x & 63;
  int tile, co;
  if (TT){ tile = blockIdx.y*8 + wave*2 + (lane>>5); co = lane & 31; }
  else   { tile = blockIdx.y*4 + wave;               co = lane; }
  int y0 = (tile >> 3)*5, x0 = (tile & 7)*5;          // padded window origin
  const u16* inb = in + (size_t)b*1764*CI;
  float acc[25];
  #pragma unroll
  for (int p=0;p<25;p++) acc[p]=0.f;
  for (int ci=0; ci<CI; ci++){
    float win[49];
    #pragma unroll
    for (int r=0;r<7;r++)
      #pragma unroll
      for (int c=0;c<7;c++)
        win[r*7+c] = bf2f(inb[ ((y0+r)*42 + (x0+c))*CI + ci ]);
    float wk[9];
    #pragma unroll
    for (int k=0;k<9;k++) wk[k] = w2[(ci*9+k)*CO + co];
    #pragma unroll
    for (int py=0;py<5;py++)
      #pragma unroll
      for (int px=0;px<5;px++){
        float s = acc[py*5+px];
        #pragma unroll
        for (int dy=0;dy<3;dy++)
          #pragma unroll
          for (int dx=0;dx<3;dx++)
            s = fmaf(wk[dy*3+dx], win[(py+dy)*7 + (px+dx)], s);
        acc[py*5+px] = s;
      }
  }
  float bia = par[co], sc = par[CO+co], be = par[2*CO+co];
  u16* outb = out + (size_t)b*1764*CO;
  #pragma unroll
  for (int py=0;py<5;py++)
    #pragma unroll
    for (int px=0;px<5;px++){
      float vv = fmaxf(acc[py*5+px] + bia, 0.f)*sc + be;
      outb[ ((y0+py+1)*42 + (x0+px+1))*CO + co ] = f2bf(vv);
    }
}

// ---------------- c6: 32 -> 1 channel (vectorized input loads) ----------------
__global__ __launch_bounds__(256) void conv_c6(const u16* __restrict__ in, u16* __restrict__ y6,
    const float* __restrict__ w6, const float* __restrict__ par6){
  int id = blockIdx.x*256 + threadIdx.x;          // 128*1600
  int b = id/1600, p = id%1600;
  int y = p/40, x = p%40;
  const u16* inb = in + (size_t)b*1764*32;
  float acc = 0.f;
  #pragma unroll
  for (int dy=0;dy<3;dy++)
    #pragma unroll
    for (int dx=0;dx<3;dx++){
      const u16* q = inb + ((y+dy)*42 + (x+dx))*32;
      int k = dy*3+dx;
      #pragma unroll
      for (int g=0; g<4; g++){
        us8v vv8 = *(const us8v*)(q + g*8);
        #pragma unroll
        for (int j=0;j<8;j++)
          acc = fmaf(w6[(g*8+j)*9 + k], bf2f(vv8[j]), acc);
      }
    }
  float vv = fmaxf(acc + par6[0], 0.f)*par6[1] + par6[2];
  y6[(size_t)b*1764 + (y+1)*42 + (x+1)] = f2bf(vv);
}

// ---------------- pc: concat(pre, y6) 2 -> 1 channel, no relu ----------------
__global__ __launch_bounds__(256) void conv_pc(const u16* __restrict__ p0, const u16* __restrict__ y6,
    const float* __restrict__ pcw, const float* __restrict__ pcb,
    const float* __restrict__ pcg, const float* __restrict__ pcbe,
    float* __restrict__ out1600){
  int id = blockIdx.x*256 + threadIdx.x;          // 128*1600
  int b = id/1600, p = id%1600;
  int y = p/40, x = p%40;
  float acc = 0.f;
  #pragma unroll
  for (int dy=0;dy<3;dy++)
    #pragma unroll
    for (int dx=0;dx<3;dx++){
      size_t o = (size_t)b*1764 + (y+dy)*42 + (x+dx);
      acc = fmaf(pcw[dy*3+dx],     bf2f(p0[o]), acc);
      acc = fmaf(pcw[9 + dy*3+dx], bf2f(y6[o]), acc);
    }
  float sc = pcg[0] * (1.0f/sqrtf(1.00001f));
  out1600[id] = (acc + pcb[0])*sc + pcbe[0];
}

// ---------------- LSTM gating ----------------
__global__ __launch_bounds__(256) void gate_k(const float* __restrict__ whx3, const float* __restrict__ ct,
                                              float* __restrict__ outp){
  int id = blockIdx.x*256 + threadIdx.x;          // 128*300
  if (id >= 38400) return;
  int b = id/300, d = id%300;
  const float* r = whx3 + (size_t)b*1200;
  float ft = 1.f/(1.f+expf(-r[d]));
  float ot = 1.f/(1.f+expf(-r[300+d]));
  float it = 1.f/(1.f+expf(-r[600+d]));
  float ch = tanhf(r[900+d]);
  float c  = ft*ct[id] + it*ch;
  outp[id] = ot*tanhf(c);
}

extern "C" void kernel_launch(void* const* d_in, const int* in_sizes, int n_in,
                              void* d_out, int out_size, void* d_ws, size_t ws_size,
                              hipStream_t stream){
  const float* x    = (const float*)d_in[0];
  const float* hs   = (const float*)d_in[1];
  const float* pht  = (const float*)d_in[2];
  const float* pc   = (const float*)d_in[3];
  const float* W    = (const float*)d_in[4];
  const float* bb   = (const float*)d_in[5];
  const float* Wh   = (const float*)d_in[6];
  const float* Wx   = (const float*)d_in[7];
  const float* Wht  = (const float*)d_in[8];
  const float* v    = (const float*)d_in[9];
  const float* rbw  = (const float*)d_in[10];
  const float* rbb  = (const float*)d_in[11];
  const float* rpw  = (const float*)d_in[12];
  const float* rpb  = (const float*)d_in[13];
  const float *cw[6], *cb[6], *cg[6], *cbe[6];
  for (int i=0;i<6;i++){
    cw[i]=(const float*)d_in[14+4*i]; cb[i]=(const float*)d_in[15+4*i];
    cg[i]=(const float*)d_in[16+4*i]; cbe[i]=(const float*)d_in[17+4*i];
  }
  const float* pcw = (const float*)d_in[38];
  const float* pcb = (const float*)d_in[39];
  const float* pcg = (const float*)d_in[40];
  const float* pcbe= (const float*)d_in[41];

  char* ws = (char*)d_ws;
  float* score = (float*)(ws + OFF_SCORE);
  float* xw    = (float*)(ws + OFF_XW);
  float* whx1  = (float*)(ws + OFF_WHX1);
  float* whx2  = (float*)(ws + OFF_WHX2);
  float* o1600 = (float*)(ws + OFF_O1600);
  float* whx3  = (float*)(ws + OFF_WHX3);
  float* w21   = (float*)(ws + OFF_W21);
  u16*   wb2   = (u16*)  (ws + OFF_WB2);
  u16*   wb3   = (u16*)  (ws + OFF_WB3);
  u16*   wb4   = (u16*)  (ws + OFF_WB4);
  u16*   wb5   = (u16*)  (ws + OFF_WB5);
  float* w26   = (float*)(ws + OFF_W26);
  float* par[6];
  for (int i=0;i<6;i++) par[i] = (float*)(ws + OFF_PAR + (size_t)i*768);
  float* ht = (float*)(ws + OFF_HT);
  float* ct = (float*)(ws + OFF_CT);
  u16* A32 = (u16*)(ws + OFF_A32);
  u16* B64 = (u16*)(ws + OFF_B64);
  u16* C64 = (u16*)(ws + OFF_C64);
  u16* P0  = (u16*)(ws + OFF_P0);
  u16* Y6  = (u16*)(ws + OFF_Y6);

  // 0) zero: atomic accumulators, P0/Y6 (fully), border rings of NHWC bufs
  zero_k<<<75, 256,0,stream>>>((uint4*)(ws + OFF_HT), ZB1/16);
  zero_k<<<221,256,0,stream>>>((uint4*)(ws + OFF_P0), ZB2/16);
  border_k<32><<<(128*164*4 +255)/256,256,0,stream>>>(A32);
  border_k<64><<<(128*164*8 +255)/256,256,0,stream>>>(B64);
  border_k<64><<<(128*164*8 +255)/256,256,0,stream>>>(C64);

  // 1) attention
  xw_k<<<1280,64,0,stream>>>(x, Wx, xw);
  score_k<<<512,256,0,stream>>>(hs, pht, Wh, Wht, v, xw, score);
  softmax_k<<<128,256,0,stream>>>(score);
  wsum_k<<<dim3(128,8),128,0,stream>>>(hs, pc, score, ht, ct);

  // 2) dense layers to pre
  gemm_k<<<dim3(38,4),256,0,stream>>>(0,  600, 1200, ht, x,      W,   bb,  whx1);
  gemm_k<<<dim3(50,4),256,0,stream>>>(1, 1200, 1600, whx1, nullptr, rbw, rbb, whx2);
  scat_k<<<800,256,0,stream>>>(whx2, P0);

  // 3) conv block
  repack_k<<<2,  256,0,stream>>>(cw[0],cb[0],cg[0],cbe[0], w21, par[0],  1, 32);
  repack_mfma_k<<<72, 256,0,stream>>>(cw[1],cb[1],cg[1],cbe[1], wb2, par[1], 32, 64);
  repack_mfma_k<<<144,256,0,stream>>>(cw[2],cb[2],cg[2],cbe[2], wb3, par[2], 64, 64);
  repack_mfma_k<<<144,256,0,stream>>>(cw[3],cb[3],cg[3],cbe[3], wb4, par[3], 64, 64);
  repack_mfma_k<<<72, 256,0,stream>>>(cw[4],cb[4],cg[4],cbe[4], wb5, par[4], 64, 32);
  repack_k<<<2,  256,0,stream>>>(cw[5],cb[5],cg[5],cbe[5], w26, par[5], 32,  1);

  conv_main<1,32,true><<<dim3(128,8),256,0,stream>>>(P0, A32, w21, par[0]);
  conv_mfma<32,64><<<dim3(25,128),256,0,stream>>>(A32, B64, wb2, par[1]);
  conv_mfma<64,64><<<dim3(25,128),256,0,stream>>>(B64, C64, wb3, par[2]);
  conv_mfma<64,64><<<dim3(25,128),256,0,stream>>>(C64, B64, wb4, par[3]);
  conv_mfma<64,32><<<dim3(25,128),256,0,stream>>>(B64, A32, wb5, par[4]);
  conv_c6<<<800,256,0,stream>>>(A32, Y6, w26, par[5]);
  conv_pc<<<800,256,0,stream>>>(P0, Y6, pcw, pcb, pcg, pcbe, o1600);

  // 4) final projection + gating
  gemm_k<<<dim3(38,4),256,0,stream>>>(1, 1600, 1200, o1600, nullptr, rpw, rpb, whx3);
  gate_k<<<150,256,0,stream>>>(whx3, ct, (float*)d_out);
}

// Round 6
// 855.019 us; speedup vs baseline: 2.0066x; 1.0071x over previous
//
#include <hip/hip_runtime.h>
#include <hip/hip_bf16.h>
#include <cstdint>
#include <cstddef>

typedef unsigned short u16;

#define DEV __device__ __forceinline__

DEV float bf2f(u16 u){ union{unsigned int i; float f;} c; c.i = ((unsigned)u)<<16; return c.f; }
DEV u16 f2bf(float f){ union{float f;unsigned int i;} c; c.f=f; unsigned int r = c.i + 0x7FFFu + ((c.i>>16)&1u); return (u16)(r>>16); }
DEV unsigned int pk2(float a, float b){
  __hip_bfloat162 t = __float22bfloat162_rn(float2{a,b});   // v_cvt_pk_bf16_f32; .x = low half
  union { __hip_bfloat162 h; unsigned int u; } cv; cv.h = t; return cv.u;
}

typedef __attribute__((ext_vector_type(8))) short bf16x8;
typedef __attribute__((ext_vector_type(4))) float f32x4;
typedef __attribute__((ext_vector_type(8))) unsigned short us8v;

// ---------------- workspace layout (bytes) ----------------
static constexpr size_t OFF_SCORE = 0;                                   // [128][1024] f32
static constexpr size_t OFF_XW    = OFF_SCORE + (size_t)128*1024*4;      // [128][16] f32
static constexpr size_t OFF_WHX1  = OFF_XW    + (size_t)128*16*4;        // [128][1200] f32
static constexpr size_t OFF_WHX2  = OFF_WHX1  + (size_t)128*1200*4;      // [128][1600] f32
static constexpr size_t OFF_O1600 = OFF_WHX2  + (size_t)128*1600*4;      // [128][1600] f32
static constexpr size_t OFF_WHX3  = OFF_O1600 + (size_t)128*1600*4;      // [128][1200] f32
static constexpr size_t OFF_W21   = OFF_WHX3  + (size_t)128*1200*4;      // conv1 w [ci][9][co] f32 (direct)
static constexpr size_t OFF_WB2   = OFF_W21   + (size_t)1*32*9*4;        // conv2 w [co=64][9][ci=32] bf16
static constexpr size_t OFF_WB3   = OFF_WB2   + (size_t)64*9*32*2;       // conv3 w [64][9][64] bf16
static constexpr size_t OFF_WB4   = OFF_WB3   + (size_t)64*9*64*2;       // conv4 w [64][9][64] bf16
static constexpr size_t OFF_WB5   = OFF_WB4   + (size_t)64*9*64*2;       // conv5 w [co=32][9][ci=64] bf16
static constexpr size_t OFF_W26   = OFF_WB5   + (size_t)32*9*64*2;       // conv6 w [ci][9][co=1] f32 (direct)
static constexpr size_t OFF_PAR   = OFF_W26   + (size_t)32*1*9*4;        // 6 x 768B: bias/scale/beta f32
static constexpr size_t OFF_WPACK = OFF_PAR   + (size_t)6*768;           // score B-frags: 2x10x4x16x8 bf16
static constexpr size_t OFF_HT    = OFF_WPACK + (size_t)20480*2;         // [128][300] f32 (atomic acc, zeroed)
static constexpr size_t OFF_CT    = OFF_HT    + (size_t)128*300*4;       // [128][300] f32 (atomic acc, zeroed)
static constexpr size_t OFF_A32   = OFF_CT    + (size_t)128*300*4;       // [128][42*42][32] bf16 (border-zeroed)
static constexpr size_t OFF_B64   = OFF_A32   + (size_t)128*1764*32*2;   // [128][42*42][64] bf16 (border-zeroed)
static constexpr size_t OFF_C64   = OFF_B64   + (size_t)128*1764*64*2;   // [128][42*42][64] bf16 (border-zeroed)
static constexpr size_t OFF_P0    = OFF_C64   + (size_t)128*1764*64*2;   // [128][42*42] bf16 (pre, fully zeroed)
static constexpr size_t OFF_Y6    = OFF_P0    + (size_t)128*1764*2;      // [128][42*42] bf16 (fully zeroed)
static constexpr size_t OFF_END   = OFF_Y6    + (size_t)128*1764*2;
static constexpr size_t ZB1 = OFF_A32 - OFF_HT;     // HT+CT
static constexpr size_t ZB2 = OFF_END - OFF_P0;     // P0+Y6

// ---------------- zero init (grid-stride uint4) ----------------
__global__ void zero_k(uint4* __restrict__ p, size_t n){
  size_t i = (size_t)blockIdx.x*blockDim.x + threadIdx.x;
  uint4 z; z.x=0; z.y=0; z.z=0; z.w=0;
  for (; i < n; i += (size_t)gridDim.x*blockDim.x) p[i] = z;
}

// ---------------- zero the border ring of a [128][42][42][C] bf16 buffer ----------------
template<int C>
__global__ __launch_bounds__(256) void border_k(u16* __restrict__ buf){
  constexpr int CH = C/8;                       // 16B chunks per pixel
  int id = blockIdx.x*256 + threadIdx.x;
  int tot = 128*164*CH;
  if (id >= tot) return;
  int c8  = id % CH;
  int rem = id / CH;
  int i = rem % 164, b = rem / 164;
  int y, x;
  if      (i < 42){ y = 0;        x = i; }
  else if (i < 84){ y = 41;       x = i-42; }
  else if (i < 124){ y = i-84+1;  x = 0; }
  else             { y = i-124+1; x = 41; }
  us8v z = {0,0,0,0,0,0,0,0};
  *(us8v*)(buf + ((size_t)b*1764 + y*42 + x)*C + c8*8) = z;
}

// ---------------- xW[b][k] = sum_d x[b,d]*Wx[k,d] ----------------
__global__ __launch_bounds__(64) void xw_k(const float* __restrict__ x, const float* __restrict__ Wx,
                                           float* __restrict__ xw){
  int id = blockIdx.x;           // 128*10
  int b = id/10, k = id%10;
  int lane = threadIdx.x;
  float a = 0.f;
  for (int d = lane; d < 300; d += 64)
    a = fmaf(x[b*300+d], Wx[k*300+d], a);
  #pragma unroll
  for (int off=1; off<64; off<<=1) a += __shfl_xor(a, off);
  if (lane==0) xw[b*16+k] = a;
}

// ---------------- pack score weights into MFMA B-fragments ----------------
// wp[(((tz*10+ks)*4+kg)*16+col)*8+j] = bf16(W_tz[col*300 + ks*32+kg*8+j]) with zero pad
__global__ void repack_wpack_k(const float* __restrict__ Wh, const float* __restrict__ Wht,
                               u16* __restrict__ wp){
  int id = blockIdx.x*256 + threadIdx.x;
  if (id >= 20480) return;
  int j = id&7, col=(id>>3)&15, kg=(id>>7)&3, rest=id>>9;
  int ks = rest%10, tz = rest/10;
  int k = ks*32 + kg*8 + j;
  const float* src = tz ? Wht : Wh;
  float val = (col<10 && k<300) ? src[col*300+k] : 0.f;
  wp[id] = f2bf(val);
}

// ---------------- attention logits via MFMA ----------------
// Per 64-row slab: stage slab contiguously (f32->bf16) to LDS, then
// D[row][kweight] = SL[64x300] x W^T[300x10] with 10x mfma_16x16x32_bf16 per wave.
// Fragment maps (verified by conv_mfma): A row=l&15,k=(l>>4)*8+j; B col=l&15; D col=l&15,row=(l>>4)*4+reg.
DEV f32x4 slab_pass(const float* __restrict__ src, u16 (*SL)[328], const u16* __restrict__ wpack,
                    int tz, int w, int g, int c, int tid){
  // stage: 4800 float4, contiguous across 256 threads
  #pragma unroll
  for (int j=0;j<19;j++){
    int idx = j*256 + tid;
    if (idx < 4800){
      float4 q = *(const float4*)(src + idx*4);
      int f0 = idx*4;
      int row = f0/300, colp = f0 - row*300;
      uint2 pv; pv.x = pk2(q.x,q.y); pv.y = pk2(q.z,q.w);
      *(uint2*)(&SL[row][colp]) = pv;
    }
  }
  // zero-pad cols 300..327 (14 u32 per row)
  #pragma unroll
  for (int j=0;j<4;j++){
    int idx = j*256 + tid;
    if (idx < 896){
      int row = idx/14, cc = 300 + (idx - row*14)*2;
      *(unsigned int*)(&SL[row][cc]) = 0u;
    }
  }
  __syncthreads();
  f32x4 acc = (f32x4){0.f,0.f,0.f,0.f};
  const u16* wbase = wpack + (size_t)tz*5120;
  #pragma unroll
  for (int ks=0; ks<10; ks++){
    bf16x8 af = *(const bf16x8*)(&SL[w*16 + c][ks*32 + g*8]);
    bf16x8 bfr = *(const bf16x8*)(wbase + ((ks*4 + g)*16 + c)*8);
    acc = __builtin_amdgcn_mfma_f32_16x16x32_bf16(af, bfr, acc, 0, 0, 0);
  }
  __syncthreads();
  return acc;
}

__global__ __launch_bounds__(256) void score_mfma(const float* __restrict__ hs, const float* __restrict__ pht,
    const u16* __restrict__ wpack, const float* __restrict__ v,
    const float* __restrict__ xw, float* __restrict__ score){
  __shared__ u16 SL[64][328];                  // 41984 B -> 3 blocks/CU
  int tid = threadIdx.x;
  int w = tid>>6, l = tid&63;
  int g = l>>4, c = l&15;
  int rr0 = blockIdx.x*128;                    // 1024 blocks x 128 rows
  int b = rr0 >> 10;
  float vkw = (c<10) ? v[c] : 0.f;
  float xkw = (c<10) ? xw[b*16+c] : 0.f;
  #pragma unroll 1
  for (int s=0; s<2; s++){
    int rslab = rr0 + s*64;
    f32x4 accH = slab_pass(hs  + (size_t)rslab*300, SL, wpack, 0, w, g, c, tid);
    f32x4 accP = slab_pass(pht + (size_t)rslab*300, SL, wpack, 1, w, g, c, tid);
    #pragma unroll
    for (int r=0;r<4;r++){
      float t = vkw * tanhf(accH[r] + accP[r] + xkw);
      t += __shfl_xor(t,1); t += __shfl_xor(t,2); t += __shfl_xor(t,4); t += __shfl_xor(t,8);
      if (c==0) score[rslab + w*16 + g*4 + r] = t;
    }
  }
}

// ---------------- softmax over T=1024, in-place ----------------
__global__ __launch_bounds__(256) void softmax_k(float* __restrict__ score){
  int b = blockIdx.x, tid = threadIdx.x;
  float* row = score + (size_t)b*1024;
  __shared__ float red[256];
  float m = -3.0e38f;
  #pragma unroll
  for (int j=0;j<4;j++) m = fmaxf(m, row[tid + j*256]);
  red[tid]=m; __syncthreads();
  for (int s=128;s>0;s>>=1){ if(tid<s) red[tid]=fmaxf(red[tid],red[tid+s]); __syncthreads(); }
  m = red[0]; __syncthreads();
  float vals[4], sum=0.f;
  #pragma unroll
  for (int j=0;j<4;j++){ vals[j] = expf(row[tid + j*256] - m); sum += vals[j]; }
  red[tid]=sum; __syncthreads();
  for (int s=128;s>0;s>>=1){ if(tid<s) red[tid]+=red[tid+s]; __syncthreads(); }
  float inv = 1.f/red[0];
  #pragma unroll
  for (int j=0;j<4;j++) row[tid + j*256] = vals[j]*inv;
}

// ---------------- ht = sum_t s*h ; ct = sum_t s*c (atomic partials) ----------------
__global__ __launch_bounds__(128) void wsum_k(const float* __restrict__ hs, const float* __restrict__ pc,
    const float* __restrict__ s, float* __restrict__ ht, float* __restrict__ ct){
  int b = blockIdx.x, chunk = blockIdx.y;
  int wave = threadIdx.x>>6, lane = threadIdx.x&63;
  float ah[4]={0,0,0,0}, ac[4]={0,0,0,0}, ah2[4]={0,0,0,0}, ac2[4]={0,0,0,0};
  int d1 = lane*4, d2 = 256 + lane*4;
  bool has2 = d2 < 300;                    // lanes 0..10
  int t0 = chunk*64;
  for (int t = t0 + wave; t < t0+64; t += 2){
    float sv = s[b*1024 + t];
    const float* hr = hs + ((size_t)(b*1024 + t))*300;
    const float* cr = pc + ((size_t)(b*1024 + t))*300;
    float4 h4 = *(const float4*)(hr + d1);
    float4 c4 = *(const float4*)(cr + d1);
    ah[0]=fmaf(sv,h4.x,ah[0]); ah[1]=fmaf(sv,h4.y,ah[1]);
    ah[2]=fmaf(sv,h4.z,ah[2]); ah[3]=fmaf(sv,h4.w,ah[3]);
    ac[0]=fmaf(sv,c4.x,ac[0]); ac[1]=fmaf(sv,c4.y,ac[1]);
    ac[2]=fmaf(sv,c4.z,ac[2]); ac[3]=fmaf(sv,c4.w,ac[3]);
    if (has2){
      float4 h5 = *(const float4*)(hr + d2);
      float4 c5 = *(const float4*)(cr + d2);
      ah2[0]=fmaf(sv,h5.x,ah2[0]); ah2[1]=fmaf(sv,h5.y,ah2[1]);
      ah2[2]=fmaf(sv,h5.z,ah2[2]); ah2[3]=fmaf(sv,h5.w,ah2[3]);
      ac2[0]=fmaf(sv,c5.x,ac2[0]); ac2[1]=fmaf(sv,c5.y,ac2[1]);
      ac2[2]=fmaf(sv,c5.z,ac2[2]); ac2[3]=fmaf(sv,c5.w,ac2[3]);
    }
  }
  #pragma unroll
  for (int j=0;j<4;j++){
    atomicAdd(&ht[b*300 + d1 + j], ah[j]);
    atomicAdd(&ct[b*300 + d1 + j], ac[j]);
  }
  if (has2){
    #pragma unroll
    for (int j=0;j<4;j++){
      atomicAdd(&ht[b*300 + d2 + j], ah2[j]);
      atomicAdd(&ct[b*300 + d2 + j], ac2[j]);
    }
  }
}

// ---------------- generic dense layer ----------------
__global__ __launch_bounds__(256) void gemm_k(int mode, int K, int N,
    const float* __restrict__ inA, const float* __restrict__ inX,
    const float* __restrict__ W, const float* __restrict__ bias, float* __restrict__ out){
  __shared__ float aL[32][65];
  __shared__ float wL[32][65];
  int n0 = blockIdx.x*32, b0 = blockIdx.y*32;
  int tid = threadIdx.x;
  int lr = tid>>3, lk = (tid&7)*8;
  int bi = tid>>4, ni = tid&15;
  float a00=0,a01=0,a10=0,a11=0;
  for (int kc=0; kc<K; kc+=64){
    int brow = b0+lr;
    #pragma unroll
    for (int j=0;j<8;j++){
      int k = kc+lk+j;
      float vv = 0.f;
      if (k<K){
        if (mode==0) vv = (k<300) ? inA[brow*300+k] : inX[brow*300 + (k-300)];
        else         vv = inA[(size_t)brow*K + k];
      }
      aL[lr][lk+j] = vv;
    }
    int nrow = n0+lr;
    #pragma unroll
    for (int j=0;j<8;j++){
      int k = kc+lk+j;
      float vv = 0.f;
      if (nrow<N && k<K) vv = W[(size_t)nrow*K + k];
      wL[lr][lk+j] = vv;
    }
    __syncthreads();
    #pragma unroll
    for (int kk=0;kk<64;kk++){
      float x0 = aL[2*bi][kk], x1 = aL[2*bi+1][kk];
      float y0 = wL[2*ni][kk], y1 = wL[2*ni+1][kk];
      a00 = fmaf(x0,y0,a00); a01 = fmaf(x0,y1,a01);
      a10 = fmaf(x1,y0,a10); a11 = fmaf(x1,y1,a11);
    }
    __syncthreads();
  }
  int b = b0 + 2*bi, n = n0 + 2*ni;
  if (n < N){
    float bb = bias[n];
    out[(size_t)b*N+n]     = a00+bb;
    out[(size_t)(b+1)*N+n] = a10+bb;
  }
  if (n+1 < N){
    float bb = bias[n+1];
    out[(size_t)b*N+n+1]     = a01+bb;
    out[(size_t)(b+1)*N+n+1] = a11+bb;
  }
}

// ---------------- scatter pre (whx2) into padded P0 (bf16) ----------------
__global__ __launch_bounds__(256) void scat_k(const float* __restrict__ whx2, u16* __restrict__ p0){
  int id = blockIdx.x*256 + threadIdx.x;          // 128*1600
  int b = id/1600, p = id%1600;
  int y = p/40, x = p%40;
  p0[(size_t)b*1764 + (y+1)*42 + (x+1)] = f2bf(whx2[id]);
}

// ---------------- conv weight repack (direct kernels): w2[ci][k][co] f32 ----------------
__global__ void repack_k(const float* __restrict__ w, const float* __restrict__ bb,
                         const float* __restrict__ g, const float* __restrict__ be,
                         float* __restrict__ w2, float* __restrict__ par, int CI, int CO){
  int id = blockIdx.x*256 + threadIdx.x;
  int tot = CI*CO*9;
  if (id < tot){
    int co = id % CO;
    int rem = id / CO;
    int k = rem % 9, ci = rem / 9;
    w2[id] = w[(co*CI + ci)*9 + k];
  }
  if (id < CO){
    par[id]      = bb[id];
    par[CO+id]   = g[id] * (1.0f/sqrtf(1.00001f));
    par[2*CO+id] = be[id];
  }
}

// ---------------- conv weight repack (MFMA kernels): wB[co][dydx][ci] bf16 ----------------
__global__ void repack_mfma_k(const float* __restrict__ w, const float* __restrict__ bb,
                              const float* __restrict__ g, const float* __restrict__ be,
                              u16* __restrict__ wB, float* __restrict__ par, int CI, int CO){
  int id = blockIdx.x*256 + threadIdx.x;
  int tot = CI*CO*9;
  if (id < tot){
    int ci = id % CI;
    int rem = id / CI;
    int dydx = rem % 9, co = rem / 9;
    wB[id] = f2bf(w[(co*CI + ci)*9 + dydx]);
  }
  if (id < CO){
    par[id]      = bb[id];
    par[CO+id]   = g[id] * (1.0f/sqrtf(1.00001f));
    par[2*CO+id] = be[id];
  }
}

// ---------------- implicit-GEMM MFMA conv 3x3 SAME + bias + relu + bn ----------------
template<int CI, int CO>
__global__ __launch_bounds__(256) void conv_mfma(const u16* __restrict__ in, u16* __restrict__ out,
    const u16* __restrict__ wB, const float* __restrict__ par){
  constexpr int MF = CO/16;          // M-frags (cout groups)
  constexpr int KROW = CI*9;         // A row length in elems
  int tile = blockIdx.x;             // 0..24
  int b = blockIdx.y;
  int w = threadIdx.x>>6, l = threadIdx.x&63;
  int col = l & 15;
  int kg  = (l>>4)*8;
  int p = tile*64 + w*16 + col;      // output pixel 0..1599
  int y = p/40, x = p%40;
  const u16* inb = in + (size_t)b*1764*CI;
  f32x4 acc[MF];
  #pragma unroll
  for (int m=0;m<MF;m++) acc[m] = (f32x4){0.f,0.f,0.f,0.f};
  #pragma unroll
  for (int dy=0;dy<3;dy++)
  #pragma unroll
  for (int dx=0;dx<3;dx++){
    int dydx = dy*3+dx;
    const u16* bp = inb + (size_t)((y+dy)*42 + (x+dx))*CI + kg;
    const u16* ap = wB + (size_t)col*KROW + dydx*CI + kg;
    #pragma unroll
    for (int kc=0; kc<CI; kc+=32){
      bf16x8 bf = *(const bf16x8*)(bp + kc);
      #pragma unroll
      for (int m=0;m<MF;m++){
        bf16x8 af = *(const bf16x8*)(ap + (size_t)m*16*KROW + kc);
        acc[m] = __builtin_amdgcn_mfma_f32_16x16x32_bf16(af, bf, acc[m], 0, 0, 0);
      }
    }
  }
  u16* ob = out + (size_t)b*1764*CO + (size_t)((y+1)*42 + (x+1))*CO;
  #pragma unroll
  for (int m=0;m<MF;m++){
    int co0 = m*16 + (l>>4)*4;
    const float4 bia = *(const float4*)(par + co0);
    const float4 sc  = *(const float4*)(par + CO + co0);
    const float4 be  = *(const float4*)(par + 2*CO + co0);
    ushort4 s;
    s.x = f2bf(fmaxf(acc[m][0]+bia.x,0.f)*sc.x + be.x);
    s.y = f2bf(fmaxf(acc[m][1]+bia.y,0.f)*sc.y + be.y);
    s.z = f2bf(fmaxf(acc[m][2]+bia.z,0.f)*sc.z + be.z);
    s.w = f2bf(fmaxf(acc[m][3]+bia.w,0.f)*sc.w + be.w);
    *(ushort4*)(ob + co0) = s;
  }
}

// ---------------- conv1 direct 1->32 (tiny K, keep direct) ----------------
template<int CI, int CO, bool TT>
__global__ __launch_bounds__(256) void conv_main(const u16* __restrict__ in, u16* __restrict__ out,
    const float* __restrict__ w2, const float* __restrict__ par){
  int b = blockIdx.x;
  int wave = threadIdx.x >> 6;
  int lane = threadIdx.x & 63;
  int tile, co;
  if (TT){ tile = blockIdx.y*8 + wave*2 + (lane>>5); co = lane & 31; }
  else   { tile = blockIdx.y*4 + wave;               co = lane; }
  int y0 = (tile >> 3)*5, x0 = (tile & 7)*5;          // padded window origin
  const u16* inb = in + (size_t)b*1764*CI;
  float acc[25];
  #pragma unroll
  for (int p=0;p<25;p++) acc[p]=0.f;
  for (int ci=0; ci<CI; ci++){
    float win[49];
    #pragma unroll
    for (int r=0;r<7;r++)
      #pragma unroll
      for (int c=0;c<7;c++)
        win[r*7+c] = bf2f(inb[ ((y0+r)*42 + (x0+c))*CI + ci ]);
    float wk[9];
    #pragma unroll
    for (int k=0;k<9;k++) wk[k] = w2[(ci*9+k)*CO + co];
    #pragma unroll
    for (int py=0;py<5;py++)
      #pragma unroll
      for (int px=0;px<5;px++){
        float s = acc[py*5+px];
        #pragma unroll
        for (int dy=0;dy<3;dy++)
          #pragma unroll
          for (int dx=0;dx<3;dx++)
            s = fmaf(wk[dy*3+dx], win[(py+dy)*7 + (px+dx)], s);
        acc[py*5+px] = s;
      }
  }
  float bia = par[co], sc = par[CO+co], be = par[2*CO+co];
  u16* outb = out + (size_t)b*1764*CO;
  #pragma unroll
  for (int py=0;py<5;py++)
    #pragma unroll
    for (int px=0;px<5;px++){
      float vv = fmaxf(acc[py*5+px] + bia, 0.f)*sc + be;
      outb[ ((y0+py+1)*42 + (x0+px+1))*CO + co ] = f2bf(vv);
    }
}

// ---------------- c6: 32 -> 1 channel (vectorized input loads) ----------------
__global__ __launch_bounds__(256) void conv_c6(const u16* __restrict__ in, u16* __restrict__ y6,
    const float* __restrict__ w6, const float* __restrict__ par6){
  int id = blockIdx.x*256 + threadIdx.x;          // 128*1600
  int b = id/1600, p = id%1600;
  int y = p/40, x = p%40;
  const u16* inb = in + (size_t)b*1764*32;
  float acc = 0.f;
  #pragma unroll
  for (int dy=0;dy<3;dy++)
    #pragma unroll
    for (int dx=0;dx<3;dx++){
      const u16* q = inb + ((y+dy)*42 + (x+dx))*32;
      int k = dy*3+dx;
      #pragma unroll
      for (int g=0; g<4; g++){
        us8v vv8 = *(const us8v*)(q + g*8);
        #pragma unroll
        for (int j=0;j<8;j++)
          acc = fmaf(w6[(g*8+j)*9 + k], bf2f(vv8[j]), acc);
      }
    }
  float vv = fmaxf(acc + par6[0], 0.f)*par6[1] + par6[2];
  y6[(size_t)b*1764 + (y+1)*42 + (x+1)] = f2bf(vv);
}

// ---------------- pc: concat(pre, y6) 2 -> 1 channel, no relu ----------------
__global__ __launch_bounds__(256) void conv_pc(const u16* __restrict__ p0, const u16* __restrict__ y6,
    const float* __restrict__ pcw, const float* __restrict__ pcb,
    const float* __restrict__ pcg, const float* __restrict__ pcbe,
    float* __restrict__ out1600){
  int id = blockIdx.x*256 + threadIdx.x;          // 128*1600
  int b = id/1600, p = id%1600;
  int y = p/40, x = p%40;
  float acc = 0.f;
  #pragma unroll
  for (int dy=0;dy<3;dy++)
    #pragma unroll
    for (int dx=0;dx<3;dx++){
      size_t o = (size_t)b*1764 + (y+dy)*42 + (x+dx);
      acc = fmaf(pcw[dy*3+dx],     bf2f(p0[o]), acc);
      acc = fmaf(pcw[9 + dy*3+dx], bf2f(y6[o]), acc);
    }
  float sc = pcg[0] * (1.0f/sqrtf(1.00001f));
  out1600[id] = (acc + pcb[0])*sc + pcbe[0];
}

// ---------------- LSTM gating ----------------
__global__ __launch_bounds__(256) void gate_k(const float* __restrict__ whx3, const float* __restrict__ ct,
                                              float* __restrict__ outp){
  int id = blockIdx.x*256 + threadIdx.x;          // 128*300
  if (id >= 38400) return;
  int b = id/300, d = id%300;
  const float* r = whx3 + (size_t)b*1200;
  float ft = 1.f/(1.f+expf(-r[d]));
  float ot = 1.f/(1.f+expf(-r[300+d]));
  float it = 1.f/(1.f+expf(-r[600+d]));
  float ch = tanhf(r[900+d]);
  float c  = ft*ct[id] + it*ch;
  outp[id] = ot*tanhf(c);
}

extern "C" void kernel_launch(void* const* d_in, const int* in_sizes, int n_in,
                              void* d_out, int out_size, void* d_ws, size_t ws_size,
                              hipStream_t stream){
  const float* x    = (const float*)d_in[0];
  const float* hs   = (const float*)d_in[1];
  const float* pht  = (const float*)d_in[2];
  const float* pc   = (const float*)d_in[3];
  const float* W    = (const float*)d_in[4];
  const float* bb   = (const float*)d_in[5];
  const float* Wh   = (const float*)d_in[6];
  const float* Wx   = (const float*)d_in[7];
  const float* Wht  = (const float*)d_in[8];
  const float* v    = (const float*)d_in[9];
  const float* rbw  = (const float*)d_in[10];
  const float* rbb  = (const float*)d_in[11];
  const float* rpw  = (const float*)d_in[12];
  const float* rpb  = (const float*)d_in[13];
  const float *cw[6], *cb[6], *cg[6], *cbe[6];
  for (int i=0;i<6;i++){
    cw[i]=(const float*)d_in[14+4*i]; cb[i]=(const float*)d_in[15+4*i];
    cg[i]=(const float*)d_in[16+4*i]; cbe[i]=(const float*)d_in[17+4*i];
  }
  const float* pcw = (const float*)d_in[38];
  const float* pcb = (const float*)d_in[39];
  const float* pcg = (const float*)d_in[40];
  const float* pcbe= (const float*)d_in[41];

  char* ws = (char*)d_ws;
  float* score = (float*)(ws + OFF_SCORE);
  float* xw    = (float*)(ws + OFF_XW);
  float* whx1  = (float*)(ws + OFF_WHX1);
  float* whx2  = (float*)(ws + OFF_WHX2);
  float* o1600 = (float*)(ws + OFF_O1600);
  float* whx3  = (float*)(ws + OFF_WHX3);
  float* w21   = (float*)(ws + OFF_W21);
  u16*   wb2   = (u16*)  (ws + OFF_WB2);
  u16*   wb3   = (u16*)  (ws + OFF_WB3);
  u16*   wb4   = (u16*)  (ws + OFF_WB4);
  u16*   wb5   = (u16*)  (ws + OFF_WB5);
  float* w26   = (float*)(ws + OFF_W26);
  u16*   wpack = (u16*)  (ws + OFF_WPACK);
  float* par[6];
  for (int i=0;i<6;i++) par[i] = (float*)(ws + OFF_PAR + (size_t)i*768);
  float* ht = (float*)(ws + OFF_HT);
  float* ct = (float*)(ws + OFF_CT);
  u16* A32 = (u16*)(ws + OFF_A32);
  u16* B64 = (u16*)(ws + OFF_B64);
  u16* C64 = (u16*)(ws + OFF_C64);
  u16* P0  = (u16*)(ws + OFF_P0);
  u16* Y6  = (u16*)(ws + OFF_Y6);

  // 0) zero: atomic accumulators, P0/Y6 (fully), border rings of NHWC bufs
  zero_k<<<75, 256,0,stream>>>((uint4*)(ws + OFF_HT), ZB1/16);
  zero_k<<<221,256,0,stream>>>((uint4*)(ws + OFF_P0), ZB2/16);
  border_k<32><<<(128*164*4 +255)/256,256,0,stream>>>(A32);
  border_k<64><<<(128*164*8 +255)/256,256,0,stream>>>(B64);
  border_k<64><<<(128*164*8 +255)/256,256,0,stream>>>(C64);

  // 1) attention
  xw_k<<<1280,64,0,stream>>>(x, Wx, xw);
  repack_wpack_k<<<80,256,0,stream>>>(Wh, Wht, wpack);
  score_mfma<<<1024,256,0,stream>>>(hs, pht, wpack, v, xw, score);
  softmax_k<<<128,256,0,stream>>>(score);
  wsum_k<<<dim3(128,16),128,0,stream>>>(hs, pc, score, ht, ct);

  // 2) dense layers to pre
  gemm_k<<<dim3(38,4),256,0,stream>>>(0,  600, 1200, ht, x,      W,   bb,  whx1);
  gemm_k<<<dim3(50,4),256,0,stream>>>(1, 1200, 1600, whx1, nullptr, rbw, rbb, whx2);
  scat_k<<<800,256,0,stream>>>(whx2, P0);

  // 3) conv block
  repack_k<<<2,  256,0,stream>>>(cw[0],cb[0],cg[0],cbe[0], w21, par[0],  1, 32);
  repack_mfma_k<<<72, 256,0,stream>>>(cw[1],cb[1],cg[1],cbe[1], wb2, par[1], 32, 64);
  repack_mfma_k<<<144,256,0,stream>>>(cw[2],cb[2],cg[2],cbe[2], wb3, par[2], 64, 64);
  repack_mfma_k<<<144,256,0,stream>>>(cw[3],cb[3],cg[3],cbe[3], wb4, par[3], 64, 64);
  repack_mfma_k<<<72, 256,0,stream>>>(cw[4],cb[4],cg[4],cbe[4], wb5, par[4], 64, 32);
  repack_k<<<2,  256,0,stream>>>(cw[5],cb[5],cg[5],cbe[5], w26, par[5], 32,  1);

  conv_main<1,32,true><<<dim3(128,8),256,0,stream>>>(P0, A32, w21, par[0]);
  conv_mfma<32,64><<<dim3(25,128),256,0,stream>>>(A32, B64, wb2, par[1]);
  conv_mfma<64,64><<<dim3(25,128),256,0,stream>>>(B64, C64, wb3, par[2]);
  conv_mfma<64,64><<<dim3(25,128),256,0,stream>>>(C64, B64, wb4, par[3]);
  conv_mfma<64,32><<<dim3(25,128),256,0,stream>>>(B64, A32, wb5, par[4]);
  conv_c6<<<800,256,0,stream>>>(A32, Y6, w26, par[5]);
  conv_pc<<<800,256,0,stream>>>(P0, Y6, pcw, pcb, pcg, pcbe, o1600);

  // 4) final projection + gating
  gemm_k<<<dim3(38,4),256,0,stream>>>(1, 1600, 1200, o1600, nullptr, rpw, rpb, whx3);
  gate_k<<<150,256,0,stream>>>(whx3, ct, (float*)d_out);
}

// Round 7
// 570.826 us; speedup vs baseline: 3.0056x; 1.4979x over previous
//
#include <hip/hip_runtime.h>
#include <hip/hip_bf16.h>
#include <cstdint>
#include <cstddef>

typedef unsigned short u16;
typedef unsigned int u32;

#define DEV __device__ __forceinline__

DEV float bf2f(u16 u){ union{unsigned int i; float f;} c; c.i = ((unsigned)u)<<16; return c.f; }
DEV u16 f2bf(float f){ union{float f;unsigned int i;} c; c.f=f; unsigned int r = c.i + 0x7FFFu + ((c.i>>16)&1u); return (u16)(r>>16); }
DEV unsigned int pk2(float a, float b){
  __hip_bfloat162 t = __float22bfloat162_rn(float2{a,b});   // v_cvt_pk_bf16_f32
  union { __hip_bfloat162 h; unsigned int u; } cv; cv.h = t; return cv.u;
}

typedef __attribute__((ext_vector_type(8))) short bf16x8;
typedef __attribute__((ext_vector_type(4))) float f32x4;
typedef __attribute__((ext_vector_type(8))) unsigned short us8v;

// ---------------- workspace layout (bytes) ----------------
static constexpr size_t OFF_SCORE = 0;                                   // [128][1024] f32
static constexpr size_t OFF_XW    = OFF_SCORE + (size_t)128*1024*4;      // [128][16] f32
static constexpr size_t OFF_WHX1  = OFF_XW    + (size_t)128*16*4;        // [128][1200] f32
static constexpr size_t OFF_WHX2  = OFF_WHX1  + (size_t)128*1200*4;      // [128][1600] f32
static constexpr size_t OFF_O1600 = OFF_WHX2  + (size_t)128*1600*4;      // [128][1600] f32
static constexpr size_t OFF_WHX3  = OFF_O1600 + (size_t)128*1600*4;      // [128][1200] f32
static constexpr size_t OFF_W21   = OFF_WHX3  + (size_t)128*1200*4;      // conv1 w [ci][9][co] f32 (direct)
static constexpr size_t OFF_WB2   = OFF_W21   + (size_t)1*32*9*4;        // conv2 w [co=64][9][ci=32] bf16
static constexpr size_t OFF_WB3   = OFF_WB2   + (size_t)64*9*32*2;       // conv3 w [64][9][64] bf16
static constexpr size_t OFF_WB4   = OFF_WB3   + (size_t)64*9*64*2;       // conv4 w [64][9][64] bf16
static constexpr size_t OFF_WB5   = OFF_WB4   + (size_t)64*9*64*2;       // conv5 w [co=32][9][ci=64] bf16
static constexpr size_t OFF_W26   = OFF_WB5   + (size_t)32*9*64*2;       // conv6 w [ci][9][co=1] f32 (direct)
static constexpr size_t OFF_PAR   = OFF_W26   + (size_t)32*1*9*4;        // 6 x 768B: bias/scale/beta f32
static constexpr size_t OFF_WPACK = OFF_PAR   + (size_t)6*768;           // score B-frags: 2x10x4x16x8 bf16
static constexpr size_t OFF_HT    = OFF_WPACK + (size_t)20480*2;         // [128][300] f32 (atomic acc, zeroed)
static constexpr size_t OFF_CT    = OFF_HT    + (size_t)128*300*4;       // [128][300] f32 (atomic acc, zeroed)
static constexpr size_t OFF_A32   = OFF_CT    + (size_t)128*300*4;       // [128][42*42][32] bf16 (border-zeroed)
static constexpr size_t OFF_B64   = OFF_A32   + (size_t)128*1764*32*2;   // [128][42*42][64] bf16 (border-zeroed)
static constexpr size_t OFF_C64   = OFF_B64   + (size_t)128*1764*64*2;   // [128][42*42][64] bf16 (border-zeroed)
static constexpr size_t OFF_P0    = OFF_C64   + (size_t)128*1764*64*2;   // [128][42*42] bf16 (pre, fully zeroed)
static constexpr size_t OFF_Y6    = OFF_P0    + (size_t)128*1764*2;      // [128][42*42] bf16 (fully zeroed)
static constexpr size_t OFF_END   = OFF_Y6    + (size_t)128*1764*2;
static constexpr size_t ZB1 = OFF_A32 - OFF_HT;     // HT+CT
static constexpr size_t ZB2 = OFF_END - OFF_P0;     // P0+Y6

// ---------------- zero init (grid-stride uint4) ----------------
__global__ void zero_k(uint4* __restrict__ p, size_t n){
  size_t i = (size_t)blockIdx.x*blockDim.x + threadIdx.x;
  uint4 z; z.x=0; z.y=0; z.z=0; z.w=0;
  for (; i < n; i += (size_t)gridDim.x*blockDim.x) p[i] = z;
}

// ---------------- zero the border ring of a [128][42][42][C] bf16 buffer ----------------
template<int C>
__global__ __launch_bounds__(256) void border_k(u16* __restrict__ buf){
  constexpr int CH = C/8;                       // 16B chunks per pixel
  int id = blockIdx.x*256 + threadIdx.x;
  int tot = 128*164*CH;
  if (id >= tot) return;
  int c8  = id % CH;
  int rem = id / CH;
  int i = rem % 164, b = rem / 164;
  int y, x;
  if      (i < 42){ y = 0;        x = i; }
  else if (i < 84){ y = 41;       x = i-42; }
  else if (i < 124){ y = i-84+1;  x = 0; }
  else             { y = i-124+1; x = 41; }
  us8v z = {0,0,0,0,0,0,0,0};
  *(us8v*)(buf + ((size_t)b*1764 + y*42 + x)*C + c8*8) = z;
}

// ---------------- xW[b][k] = sum_d x[b,d]*Wx[k,d] ----------------
__global__ __launch_bounds__(64) void xw_k(const float* __restrict__ x, const float* __restrict__ Wx,
                                           float* __restrict__ xw){
  int id = blockIdx.x;           // 128*10
  int b = id/10, k = id%10;
  int lane = threadIdx.x;
  float a = 0.f;
  for (int d = lane; d < 300; d += 64)
    a = fmaf(x[b*300+d], Wx[k*300+d], a);
  #pragma unroll
  for (int off=1; off<64; off<<=1) a += __shfl_xor(a, off);
  if (lane==0) xw[b*16+k] = a;
}

// ---------------- pack score weights into MFMA B-fragments ----------------
__global__ void repack_wpack_k(const float* __restrict__ Wh, const float* __restrict__ Wht,
                               u16* __restrict__ wp){
  int id = blockIdx.x*256 + threadIdx.x;
  if (id >= 20480) return;
  int j = id&7, col=(id>>3)&15, kg=(id>>7)&3, rest=id>>9;
  int ks = rest%10, tz = rest/10;
  int k = ks*32 + kg*8 + j;
  const float* src = tz ? Wht : Wh;
  float val = (col<10 && k<300) ? src[col*300+k] : 0.f;
  wp[id] = f2bf(val);
}

// ---------------- attention logits via MFMA: one 32-row slab per block ----------------
// Stage H+P jointly (single barrier pair, 19 in-flight float4/thread), 20 MFMAs total,
// combine partials via small LDS buffer. Grid 4096.
__global__ __launch_bounds__(256) void score_mfma(const float* __restrict__ hs, const float* __restrict__ pht,
    const u16* __restrict__ wpack, const float* __restrict__ v,
    const float* __restrict__ xw, float* __restrict__ score){
  __shared__ u16 HL[32][328];
  __shared__ u16 PL[32][328];
  __shared__ float PS[2][32][18];
  int tid = threadIdx.x;
  int rr0 = blockIdx.x*32;
  int b = rr0 >> 10;
  const float* hsrc = hs  + (size_t)rr0*300;
  const float* psrc = pht + (size_t)rr0*300;
  // stage: 2400 float4 per tensor (300 f32 = 75 float4/row, 32 rows)
  #pragma unroll
  for (int rnd=0; rnd<10; rnd++){
    int idx = rnd*256 + tid;
    if (idx < 2400){
      float4 qh = *(const float4*)(hsrc + idx*4);
      float4 qp = *(const float4*)(psrc + idx*4);
      int row = idx/75, colp = (idx - row*75)*4;
      uint2 pvh; pvh.x = pk2(qh.x,qh.y); pvh.y = pk2(qh.z,qh.w);
      uint2 pvp; pvp.x = pk2(qp.x,qp.y); pvp.y = pk2(qp.z,qp.w);
      *(uint2*)(&HL[row][colp]) = pvh;
      *(uint2*)(&PL[row][colp]) = pvp;
    }
  }
  #pragma unroll
  for (int j=0;j<2;j++){
    int idx = j*256 + tid;
    if (idx < 448){
      int row = idx/14, cc = 300 + (idx - row*14)*2;
      *(u32*)(&HL[row][cc]) = 0u;
      *(u32*)(&PL[row][cc]) = 0u;
    }
  }
  __syncthreads();
  int w = tid>>6, l = tid&63;
  int c = l&15, g = l>>4;
  int tz = w>>1, rf = w&1;                      // tensor, row-frag
  const u16 (*SL)[328] = tz ? PL : HL;
  const u16* wbase = wpack + (size_t)tz*5120;
  f32x4 acc = (f32x4){0.f,0.f,0.f,0.f};
  #pragma unroll
  for (int ks=0; ks<10; ks++){
    bf16x8 af  = *(const bf16x8*)(&SL[rf*16 + c][ks*32 + g*8]);
    bf16x8 bfr = *(const bf16x8*)(wbase + ((ks*4 + g)*16 + c)*8);
    acc = __builtin_amdgcn_mfma_f32_16x16x32_bf16(af, bfr, acc, 0, 0, 0);
  }
  #pragma unroll
  for (int r=0;r<4;r++) PS[tz][rf*16 + g*4 + r][c] = acc[r];
  __syncthreads();
  if (tid < 32){
    float s = 0.f;
    #pragma unroll
    for (int k=0;k<10;k++)
      s += v[k]*tanhf(PS[0][tid][k] + PS[1][tid][k] + xw[b*16+k]);
    score[rr0 + tid] = s;
  }
}

// ---------------- softmax over T=1024, in-place ----------------
__global__ __launch_bounds__(256) void softmax_k(float* __restrict__ score){
  int b = blockIdx.x, tid = threadIdx.x;
  float* row = score + (size_t)b*1024;
  __shared__ float red[256];
  float m = -3.0e38f;
  #pragma unroll
  for (int j=0;j<4;j++) m = fmaxf(m, row[tid + j*256]);
  red[tid]=m; __syncthreads();
  for (int s=128;s>0;s>>=1){ if(tid<s) red[tid]=fmaxf(red[tid],red[tid+s]); __syncthreads(); }
  m = red[0]; __syncthreads();
  float vals[4], sum=0.f;
  #pragma unroll
  for (int j=0;j<4;j++){ vals[j] = expf(row[tid + j*256] - m); sum += vals[j]; }
  red[tid]=sum; __syncthreads();
  for (int s=128;s>0;s>>=1){ if(tid<s) red[tid]+=red[tid+s]; __syncthreads(); }
  float inv = 1.f/red[0];
  #pragma unroll
  for (int j=0;j<4;j++) row[tid + j*256] = vals[j]*inv;
}

// ---------------- ht = sum_t s*h ; ct = sum_t s*c (atomic partials) ----------------
__global__ __launch_bounds__(128) void wsum_k(const float* __restrict__ hs, const float* __restrict__ pc,
    const float* __restrict__ s, float* __restrict__ ht, float* __restrict__ ct){
  int b = blockIdx.x, chunk = blockIdx.y;
  int wave = threadIdx.x>>6, lane = threadIdx.x&63;
  float ah[4]={0,0,0,0}, ac[4]={0,0,0,0}, ah2[4]={0,0,0,0}, ac2[4]={0,0,0,0};
  int d1 = lane*4, d2 = 256 + lane*4;
  bool has2 = d2 < 300;                    // lanes 0..10
  int t0 = chunk*64;
  for (int t = t0 + wave; t < t0+64; t += 2){
    float sv = s[b*1024 + t];
    const float* hr = hs + ((size_t)(b*1024 + t))*300;
    const float* cr = pc + ((size_t)(b*1024 + t))*300;
    float4 h4 = *(const float4*)(hr + d1);
    float4 c4 = *(const float4*)(cr + d1);
    ah[0]=fmaf(sv,h4.x,ah[0]); ah[1]=fmaf(sv,h4.y,ah[1]);
    ah[2]=fmaf(sv,h4.z,ah[2]); ah[3]=fmaf(sv,h4.w,ah[3]);
    ac[0]=fmaf(sv,c4.x,ac[0]); ac[1]=fmaf(sv,c4.y,ac[1]);
    ac[2]=fmaf(sv,c4.z,ac[2]); ac[3]=fmaf(sv,c4.w,ac[3]);
    if (has2){
      float4 h5 = *(const float4*)(hr + d2);
      float4 c5 = *(const float4*)(cr + d2);
      ah2[0]=fmaf(sv,h5.x,ah2[0]); ah2[1]=fmaf(sv,h5.y,ah2[1]);
      ah2[2]=fmaf(sv,h5.z,ah2[2]); ah2[3]=fmaf(sv,h5.w,ah2[3]);
      ac2[0]=fmaf(sv,c5.x,ac2[0]); ac2[1]=fmaf(sv,c5.y,ac2[1]);
      ac2[2]=fmaf(sv,c5.z,ac2[2]); ac2[3]=fmaf(sv,c5.w,ac2[3]);
    }
  }
  #pragma unroll
  for (int j=0;j<4;j++){
    atomicAdd(&ht[b*300 + d1 + j], ah[j]);
    atomicAdd(&ct[b*300 + d1 + j], ac[j]);
  }
  if (has2){
    #pragma unroll
    for (int j=0;j<4;j++){
      atomicAdd(&ht[b*300 + d2 + j], ah2[j]);
      atomicAdd(&ct[b*300 + d2 + j], ac2[j]);
    }
  }
}

// ---------------- generic dense layer ----------------
__global__ __launch_bounds__(256) void gemm_k(int mode, int K, int N,
    const float* __restrict__ inA, const float* __restrict__ inX,
    const float* __restrict__ W, const float* __restrict__ bias, float* __restrict__ out){
  __shared__ float aL[32][65];
  __shared__ float wL[32][65];
  int n0 = blockIdx.x*32, b0 = blockIdx.y*32;
  int tid = threadIdx.x;
  int lr = tid>>3, lk = (tid&7)*8;
  int bi = tid>>4, ni = tid&15;
  float a00=0,a01=0,a10=0,a11=0;
  for (int kc=0; kc<K; kc+=64){
    int brow = b0+lr;
    #pragma unroll
    for (int j=0;j<8;j++){
      int k = kc+lk+j;
      float vv = 0.f;
      if (k<K){
        if (mode==0) vv = (k<300) ? inA[brow*300+k] : inX[brow*300 + (k-300)];
        else         vv = inA[(size_t)brow*K + k];
      }
      aL[lr][lk+j] = vv;
    }
    int nrow = n0+lr;
    #pragma unroll
    for (int j=0;j<8;j++){
      int k = kc+lk+j;
      float vv = 0.f;
      if (nrow<N && k<K) vv = W[(size_t)nrow*K + k];
      wL[lr][lk+j] = vv;
    }
    __syncthreads();
    #pragma unroll
    for (int kk=0;kk<64;kk++){
      float x0 = aL[2*bi][kk], x1 = aL[2*bi+1][kk];
      float y0 = wL[2*ni][kk], y1 = wL[2*ni+1][kk];
      a00 = fmaf(x0,y0,a00); a01 = fmaf(x0,y1,a01);
      a10 = fmaf(x1,y0,a10); a11 = fmaf(x1,y1,a11);
    }
    __syncthreads();
  }
  int b = b0 + 2*bi, n = n0 + 2*ni;
  if (n < N){
    float bb = bias[n];
    out[(size_t)b*N+n]     = a00+bb;
    out[(size_t)(b+1)*N+n] = a10+bb;
  }
  if (n+1 < N){
    float bb = bias[n+1];
    out[(size_t)b*N+n+1]     = a01+bb;
    out[(size_t)(b+1)*N+n+1] = a11+bb;
  }
}

// ---------------- scatter pre (whx2) into padded P0 (bf16) ----------------
__global__ __launch_bounds__(256) void scat_k(const float* __restrict__ whx2, u16* __restrict__ p0){
  int id = blockIdx.x*256 + threadIdx.x;          // 128*1600
  int b = id/1600, p = id%1600;
  int y = p/40, x = p%40;
  p0[(size_t)b*1764 + (y+1)*42 + (x+1)] = f2bf(whx2[id]);
}

// ---------------- conv weight repack (direct kernels): w2[ci][k][co] f32 ----------------
__global__ void repack_k(const float* __restrict__ w, const float* __restrict__ bb,
                         const float* __restrict__ g, const float* __restrict__ be,
                         float* __restrict__ w2, float* __restrict__ par, int CI, int CO){
  int id = blockIdx.x*256 + threadIdx.x;
  int tot = CI*CO*9;
  if (id < tot){
    int co = id % CO;
    int rem = id / CO;
    int k = rem % 9, ci = rem / 9;
    w2[id] = w[(co*CI + ci)*9 + k];
  }
  if (id < CO){
    par[id]      = bb[id];
    par[CO+id]   = g[id] * (1.0f/sqrtf(1.00001f));
    par[2*CO+id] = be[id];
  }
}

// ---------------- conv weight repack (MFMA kernels): wB[co][dydx][ci] bf16 ----------------
__global__ void repack_mfma_k(const float* __restrict__ w, const float* __restrict__ bb,
                              const float* __restrict__ g, const float* __restrict__ be,
                              u16* __restrict__ wB, float* __restrict__ par, int CI, int CO){
  int id = blockIdx.x*256 + threadIdx.x;
  int tot = CI*CO*9;
  if (id < tot){
    int ci = id % CI;
    int rem = id / CI;
    int dydx = rem % 9, co = rem / 9;
    wB[id] = f2bf(w[(co*CI + ci)*9 + dydx]);
  }
  if (id < CO){
    par[id]      = bb[id];
    par[CO+id]   = g[id] * (1.0f/sqrtf(1.00001f));
    par[2*CO+id] = be[id];
  }
}

// ---------------- LDS-tiled implicit-GEMM MFMA conv 3x3 + bias + relu + bn ----------------
// Block = 8x8 output pixel tile. Stage 10x10xCI window to LDS (channel-padded +8:
// 2-way-max bank aliasing, 16B aligned). Wave owns one 16-cout m-group (MF=4) or
// m-group x pixel-half (MF=2): weights read ONCE per block from L2.
template<int CI, int CO>
__global__ __launch_bounds__(256) void conv_tile(const u16* __restrict__ in, u16* __restrict__ out,
    const u16* __restrict__ wB, const float* __restrict__ par){
  constexpr int PCI  = CI + 8;           // padded LDS channel stride (u16)
  constexpr int MF   = CO/16;            // m-groups (4 or 2)
  constexpr int FPW  = MF;               // pixel-frags per wave (4 or 2)
  constexpr int KC   = CI/32;            // K-chunks
  constexpr int KROW = CI*9;
  constexpr int CH8  = CI/8;
  __shared__ u16 TIN[100*PCI];
  int tile = blockIdx.x;                 // 0..24 (5x5 tiles of 8x8)
  int b = blockIdx.y;
  int y0 = (tile/5)*8, x0 = (tile%5)*8;
  const u16* inb = in + (size_t)b*1764*CI;
  // stage 10x10 window
  for (int g = threadIdx.x; g < 100*CH8; g += 256){
    int pix = g/CH8, ch = g - pix*CH8;
    int r = pix/10, cc = pix - r*10;
    us8v vdat = *(const us8v*)(inb + ((size_t)(y0+r)*42 + (x0+cc))*CI + ch*8);
    *(us8v*)(&TIN[pix*PCI + ch*8]) = vdat;
  }
  __syncthreads();
  int w = threadIdx.x>>6, l = threadIdx.x&63;
  int c = l&15, kg = l>>4;
  int mg, f0;
  if (MF==4){ mg = w; f0 = 0; } else { mg = w&1; f0 = (w>>1)*2; }
  // per-lane LDS base (bytes) per frag: window pixel (ty+dy)*10+(tx+dx), dy=dx=0 part
  int pxb[FPW];
  #pragma unroll
  for (int fi=0; fi<FPW; fi++){
    int px = (f0+fi)*16 + c;
    int ty = px>>3, tx = px&7;
    pxb[fi] = (ty*10 + tx)*PCI + kg*8;
  }
  const u16* wrow = wB + (size_t)(mg*16 + c)*KROW;
  f32x4 acc[FPW];
  #pragma unroll
  for (int fi=0; fi<FPW; fi++) acc[fi] = (f32x4){0.f,0.f,0.f,0.f};
  #pragma unroll
  for (int dy=0;dy<3;dy++)
  #pragma unroll
  for (int dx=0;dx<3;dx++){
    int dydx = dy*3+dx;
    #pragma unroll
    for (int kc=0; kc<KC; kc++){
      bf16x8 af = *(const bf16x8*)(wrow + dydx*CI + kc*32 + kg*8);
      #pragma unroll
      for (int fi=0; fi<FPW; fi++){
        bf16x8 bf = *(const bf16x8*)(&TIN[pxb[fi] + (dy*10+dx)*PCI + kc*32]);
        acc[fi] = __builtin_amdgcn_mfma_f32_16x16x32_bf16(af, bf, acc[fi], 0, 0, 0);
      }
    }
  }
  u16* ob = out + (size_t)b*1764*CO;
  int co0 = mg*16 + kg*4;
  const float4 bia = *(const float4*)(par + co0);
  const float4 sc  = *(const float4*)(par + CO + co0);
  const float4 be  = *(const float4*)(par + 2*CO + co0);
  #pragma unroll
  for (int fi=0; fi<FPW; fi++){
    int px = (f0+fi)*16 + c;
    int y = y0 + (px>>3), x = x0 + (px&7);
    ushort4 s;
    s.x = f2bf(fmaxf(acc[fi][0]+bia.x,0.f)*sc.x + be.x);
    s.y = f2bf(fmaxf(acc[fi][1]+bia.y,0.f)*sc.y + be.y);
    s.z = f2bf(fmaxf(acc[fi][2]+bia.z,0.f)*sc.z + be.z);
    s.w = f2bf(fmaxf(acc[fi][3]+bia.w,0.f)*sc.w + be.w);
    *(ushort4*)(ob + (size_t)((y+1)*42 + (x+1))*CO + co0) = s;
  }
}

// ---------------- conv1 direct 1->32 (tiny K, keep direct) ----------------
template<int CI, int CO, bool TT>
__global__ __launch_bounds__(256) void conv_main(const u16* __restrict__ in, u16* __restrict__ out,
    const float* __restrict__ w2, const float* __restrict__ par){
  int b = blockIdx.x;
  int wave = threadIdx.x >> 6;
  int lane = threadIdx.x & 63;
  int tile, co;
  if (TT){ tile = blockIdx.y*8 + wave*2 + (lane>>5); co = lane & 31; }
  else   { tile = blockIdx.y*4 + wave;               co = lane; }
  int y0 = (tile >> 3)*5, x0 = (tile & 7)*5;          // padded window origin
  const u16* inb = in + (size_t)b*1764*CI;
  float acc[25];
  #pragma unroll
  for (int p=0;p<25;p++) acc[p]=0.f;
  for (int ci=0; ci<CI; ci++){
    float win[49];
    #pragma unroll
    for (int r=0;r<7;r++)
      #pragma unroll
      for (int c=0;c<7;c++)
        win[r*7+c] = bf2f(inb[ ((y0+r)*42 + (x0+c))*CI + ci ]);
    float wk[9];
    #pragma unroll
    for (int k=0;k<9;k++) wk[k] = w2[(ci*9+k)*CO + co];
    #pragma unroll
    for (int py=0;py<5;py++)
      #pragma unroll
      for (int px=0;px<5;px++){
        float s = acc[py*5+px];
        #pragma unroll
        for (int dy=0;dy<3;dy++)
          #pragma unroll
          for (int dx=0;dx<3;dx++)
            s = fmaf(wk[dy*3+dx], win[(py+dy)*7 + (px+dx)], s);
        acc[py*5+px] = s;
      }
  }
  float bia = par[co], sc = par[CO+co], be = par[2*CO+co];
  u16* outb = out + (size_t)b*1764*CO;
  #pragma unroll
  for (int py=0;py<5;py++)
    #pragma unroll
    for (int px=0;px<5;px++){
      float vv = fmaxf(acc[py*5+px] + bia, 0.f)*sc + be;
      outb[ ((y0+py+1)*42 + (x0+px+1))*CO + co ] = f2bf(vv);
    }
}

// ---------------- c6: 32 -> 1 channel (vectorized input loads) ----------------
__global__ __launch_bounds__(256) void conv_c6(const u16* __restrict__ in, u16* __restrict__ y6,
    const float* __restrict__ w6, const float* __restrict__ par6){
  int id = blockIdx.x*256 + threadIdx.x;          // 128*1600
  int b = id/1600, p = id%1600;
  int y = p/40, x = p%40;
  const u16* inb = in + (size_t)b*1764*32;
  float acc = 0.f;
  #pragma unroll
  for (int dy=0;dy<3;dy++)
    #pragma unroll
    for (int dx=0;dx<3;dx++){
      const u16* q = inb + ((y+dy)*42 + (x+dx))*32;
      int k = dy*3+dx;
      #pragma unroll
      for (int g=0; g<4; g++){
        us8v vv8 = *(const us8v*)(q + g*8);
        #pragma unroll
        for (int j=0;j<8;j++)
          acc = fmaf(w6[(g*8+j)*9 + k], bf2f(vv8[j]), acc);
      }
    }
  float vv = fmaxf(acc + par6[0], 0.f)*par6[1] + par6[2];
  y6[(size_t)b*1764 + (y+1)*42 + (x+1)] = f2bf(vv);
}

// ---------------- pc: concat(pre, y6) 2 -> 1 channel, no relu ----------------
__global__ __launch_bounds__(256) void conv_pc(const u16* __restrict__ p0, const u16* __restrict__ y6,
    const float* __restrict__ pcw, const float* __restrict__ pcb,
    const float* __restrict__ pcg, const float* __restrict__ pcbe,
    float* __restrict__ out1600){
  int id = blockIdx.x*256 + threadIdx.x;          // 128*1600
  int b = id/1600, p = id%1600;
  int y = p/40, x = p%40;
  float acc = 0.f;
  #pragma unroll
  for (int dy=0;dy<3;dy++)
    #pragma unroll
    for (int dx=0;dx<3;dx++){
      size_t o = (size_t)b*1764 + (y+dy)*42 + (x+dx);
      acc = fmaf(pcw[dy*3+dx],     bf2f(p0[o]), acc);
      acc = fmaf(pcw[9 + dy*3+dx], bf2f(y6[o]), acc);
    }
  float sc = pcg[0] * (1.0f/sqrtf(1.00001f));
  out1600[id] = (acc + pcb[0])*sc + pcbe[0];
}

// ---------------- LSTM gating ----------------
__global__ __launch_bounds__(256) void gate_k(const float* __restrict__ whx3, const float* __restrict__ ct,
                                              float* __restrict__ outp){
  int id = blockIdx.x*256 + threadIdx.x;          // 128*300
  if (id >= 38400) return;
  int b = id/300, d = id%300;
  const float* r = whx3 + (size_t)b*1200;
  float ft = 1.f/(1.f+expf(-r[d]));
  float ot = 1.f/(1.f+expf(-r[300+d]));
  float it = 1.f/(1.f+expf(-r[600+d]));
  float ch = tanhf(r[900+d]);
  float c  = ft*ct[id] + it*ch;
  outp[id] = ot*tanhf(c);
}

extern "C" void kernel_launch(void* const* d_in, const int* in_sizes, int n_in,
                              void* d_out, int out_size, void* d_ws, size_t ws_size,
                              hipStream_t stream){
  const float* x    = (const float*)d_in[0];
  const float* hs   = (const float*)d_in[1];
  const float* pht  = (const float*)d_in[2];
  const float* pc   = (const float*)d_in[3];
  const float* W    = (const float*)d_in[4];
  const float* bb   = (const float*)d_in[5];
  const float* Wh   = (const float*)d_in[6];
  const float* Wx   = (const float*)d_in[7];
  const float* Wht  = (const float*)d_in[8];
  const float* v    = (const float*)d_in[9];
  const float* rbw  = (const float*)d_in[10];
  const float* rbb  = (const float*)d_in[11];
  const float* rpw  = (const float*)d_in[12];
  const float* rpb  = (const float*)d_in[13];
  const float *cw[6], *cb[6], *cg[6], *cbe[6];
  for (int i=0;i<6;i++){
    cw[i]=(const float*)d_in[14+4*i]; cb[i]=(const float*)d_in[15+4*i];
    cg[i]=(const float*)d_in[16+4*i]; cbe[i]=(const float*)d_in[17+4*i];
  }
  const float* pcw = (const float*)d_in[38];
  const float* pcb = (const float*)d_in[39];
  const float* pcg = (const float*)d_in[40];
  const float* pcbe= (const float*)d_in[41];

  char* ws = (char*)d_ws;
  float* score = (float*)(ws + OFF_SCORE);
  float* xw    = (float*)(ws + OFF_XW);
  float* whx1  = (float*)(ws + OFF_WHX1);
  float* whx2  = (float*)(ws + OFF_WHX2);
  float* o1600 = (float*)(ws + OFF_O1600);
  float* whx3  = (float*)(ws + OFF_WHX3);
  float* w21   = (float*)(ws + OFF_W21);
  u16*   wb2   = (u16*)  (ws + OFF_WB2);
  u16*   wb3   = (u16*)  (ws + OFF_WB3);
  u16*   wb4   = (u16*)  (ws + OFF_WB4);
  u16*   wb5   = (u16*)  (ws + OFF_WB5);
  float* w26   = (float*)(ws + OFF_W26);
  u16*   wpack = (u16*)  (ws + OFF_WPACK);
  float* par[6];
  for (int i=0;i<6;i++) par[i] = (float*)(ws + OFF_PAR + (size_t)i*768);
  float* ht = (float*)(ws + OFF_HT);
  float* ct = (float*)(ws + OFF_CT);
  u16* A32 = (u16*)(ws + OFF_A32);
  u16* B64 = (u16*)(ws + OFF_B64);
  u16* C64 = (u16*)(ws + OFF_C64);
  u16* P0  = (u16*)(ws + OFF_P0);
  u16* Y6  = (u16*)(ws + OFF_Y6);

  // 0) zero: atomic accumulators, P0/Y6 (fully), border rings of NHWC bufs
  zero_k<<<75, 256,0,stream>>>((uint4*)(ws + OFF_HT), ZB1/16);
  zero_k<<<221,256,0,stream>>>((uint4*)(ws + OFF_P0), ZB2/16);
  border_k<32><<<(128*164*4 +255)/256,256,0,stream>>>(A32);
  border_k<64><<<(128*164*8 +255)/256,256,0,stream>>>(B64);
  border_k<64><<<(128*164*8 +255)/256,256,0,stream>>>(C64);

  // 1) attention
  xw_k<<<1280,64,0,stream>>>(x, Wx, xw);
  repack_wpack_k<<<80,256,0,stream>>>(Wh, Wht, wpack);
  score_mfma<<<4096,256,0,stream>>>(hs, pht, wpack, v, xw, score);
  softmax_k<<<128,256,0,stream>>>(score);
  wsum_k<<<dim3(128,16),128,0,stream>>>(hs, pc, score, ht, ct);

  // 2) dense layers to pre
  gemm_k<<<dim3(38,4),256,0,stream>>>(0,  600, 1200, ht, x,      W,   bb,  whx1);
  gemm_k<<<dim3(50,4),256,0,stream>>>(1, 1200, 1600, whx1, nullptr, rbw, rbb, whx2);
  scat_k<<<800,256,0,stream>>>(whx2, P0);

  // 3) conv block
  repack_k<<<2,  256,0,stream>>>(cw[0],cb[0],cg[0],cbe[0], w21, par[0],  1, 32);
  repack_mfma_k<<<72, 256,0,stream>>>(cw[1],cb[1],cg[1],cbe[1], wb2, par[1], 32, 64);
  repack_mfma_k<<<144,256,0,stream>>>(cw[2],cb[2],cg[2],cbe[2], wb3, par[2], 64, 64);
  repack_mfma_k<<<144,256,0,stream>>>(cw[3],cb[3],cg[3],cbe[3], wb4, par[3], 64, 64);
  repack_mfma_k<<<72, 256,0,stream>>>(cw[4],cb[4],cg[4],cbe[4], wb5, par[4], 64, 32);
  repack_k<<<2,  256,0,stream>>>(cw[5],cb[5],cg[5],cbe[5], w26, par[5], 32,  1);

  conv_main<1,32,true><<<dim3(128,8),256,0,stream>>>(P0, A32, w21, par[0]);
  conv_tile<32,64><<<dim3(25,128),256,0,stream>>>(A32, B64, wb2, par[1]);
  conv_tile<64,64><<<dim3(25,128),256,0,stream>>>(B64, C64, wb3, par[2]);
  conv_tile<64,64><<<dim3(25,128),256,0,stream>>>(C64, B64, wb4, par[3]);
  conv_tile<64,32><<<dim3(25,128),256,0,stream>>>(B64, A32, wb5, par[4]);
  conv_c6<<<800,256,0,stream>>>(A32, Y6, w26, par[5]);
  conv_pc<<<800,256,0,stream>>>(P0, Y6, pcw, pcb, pcg, pcbe, o1600);

  // 4) final projection + gating
  gemm_k<<<dim3(38,4),256,0,stream>>>(1, 1600, 1200, o1600, nullptr, rpw, rpb, whx3);
  gate_k<<<150,256,0,stream>>>(whx3, ct, (float*)d_out);
}

// Round 8
// 532.739 us; speedup vs baseline: 3.2205x; 1.0715x over previous
//
#include <hip/hip_runtime.h>
#include <hip/hip_bf16.h>
#include <cstdint>
#include <cstddef>

typedef unsigned short u16;
typedef unsigned int u32;

#define DEV __device__ __forceinline__

DEV float bf2f(u16 u){ union{unsigned int i; float f;} c; c.i = ((unsigned)u)<<16; return c.f; }
DEV u16 f2bf(float f){ union{float f;unsigned int i;} c; c.f=f; unsigned int r = c.i + 0x7FFFu + ((c.i>>16)&1u); return (u16)(r>>16); }
DEV unsigned int pk2(float a, float b){
  __hip_bfloat162 t = __float22bfloat162_rn(float2{a,b});   // v_cvt_pk_bf16_f32
  union { __hip_bfloat162 h; unsigned int u; } cv; cv.h = t; return cv.u;
}

typedef __attribute__((ext_vector_type(8))) short bf16x8;
typedef __attribute__((ext_vector_type(4))) float f32x4;
typedef __attribute__((ext_vector_type(8))) unsigned short us8v;

// ---------------- workspace layout (bytes) ----------------
static constexpr size_t OFF_SCORE = 0;                                   // [128][1024] f32 (unused now)
static constexpr size_t OFF_XW    = OFF_SCORE + (size_t)128*1024*4;      // [128][16] f32
static constexpr size_t OFF_WHX1  = OFF_XW    + (size_t)128*16*4;        // [128][1200] f32
static constexpr size_t OFF_WHX2  = OFF_WHX1  + (size_t)128*1200*4;      // [128][1600] f32
static constexpr size_t OFF_O1600 = OFF_WHX2  + (size_t)128*1600*4;      // [128][1600] f32
static constexpr size_t OFF_WHX3  = OFF_O1600 + (size_t)128*1600*4;      // [128][1200] f32
static constexpr size_t OFF_W21   = OFF_WHX3  + (size_t)128*1200*4;      // conv1 w [ci][9][co] f32 (direct)
static constexpr size_t OFF_WB2   = OFF_W21   + (size_t)1*32*9*4;        // conv2 w [co=64][9][ci=32] bf16
static constexpr size_t OFF_WB3   = OFF_WB2   + (size_t)64*9*32*2;       // conv3 w [64][9][64] bf16
static constexpr size_t OFF_WB4   = OFF_WB3   + (size_t)64*9*64*2;       // conv4 w [64][9][64] bf16
static constexpr size_t OFF_WB5   = OFF_WB4   + (size_t)64*9*64*2;       // conv5 w [co=32][9][ci=64] bf16
static constexpr size_t OFF_W26   = OFF_WB5   + (size_t)32*9*64*2;       // conv6 w [ci][9][co=1] f32 (direct)
static constexpr size_t OFF_PAR   = OFF_W26   + (size_t)32*1*9*4;        // 6 x 768B: bias/scale/beta f32
static constexpr size_t OFF_WPACK = OFF_PAR   + (size_t)6*768;           // score B-frags: 2x10x4x16x8 bf16
static constexpr size_t OFF_HT    = OFF_WPACK + (size_t)20480*2;         // [128][300] f32 (written by reduce)
static constexpr size_t OFF_CT    = OFF_HT    + (size_t)128*300*4;       // [128][300] f32 (written by reduce)
static constexpr size_t OFF_A32   = OFF_CT    + (size_t)128*300*4;       // [128][42*42][32] bf16 (border-zeroed)
static constexpr size_t OFF_B64   = OFF_A32   + (size_t)128*1764*32*2;   // [128][42*42][64] bf16 (border-zeroed)
static constexpr size_t OFF_C64   = OFF_B64   + (size_t)128*1764*64*2;   // [128][42*42][64] bf16 (border-zeroed)
static constexpr size_t OFF_P0    = OFF_C64   + (size_t)128*1764*64*2;   // [128][42*42] bf16 (pre, fully zeroed)
static constexpr size_t OFF_Y6    = OFF_P0    + (size_t)128*1764*2;      // [128][42*42] bf16 (fully zeroed)
static constexpr size_t OFF_PART  = OFF_Y6    + (size_t)128*1764*2;      // [128][32][608] f32 attn partials
static constexpr size_t OFF_END   = OFF_PART  + (size_t)128*32*608*4;
static constexpr size_t ZB2 = OFF_PART - OFF_P0;     // P0+Y6

// ---------------- zero init (grid-stride uint4) ----------------
__global__ void zero_k(uint4* __restrict__ p, size_t n){
  size_t i = (size_t)blockIdx.x*blockDim.x + threadIdx.x;
  uint4 z; z.x=0; z.y=0; z.z=0; z.w=0;
  for (; i < n; i += (size_t)gridDim.x*blockDim.x) p[i] = z;
}

// ---------------- zero the border ring of a [128][42][42][C] bf16 buffer ----------------
template<int C>
__global__ __launch_bounds__(256) void border_k(u16* __restrict__ buf){
  constexpr int CH = C/8;                       // 16B chunks per pixel
  int id = blockIdx.x*256 + threadIdx.x;
  int tot = 128*164*CH;
  if (id >= tot) return;
  int c8  = id % CH;
  int rem = id / CH;
  int i = rem % 164, b = rem / 164;
  int y, x;
  if      (i < 42){ y = 0;        x = i; }
  else if (i < 84){ y = 41;       x = i-42; }
  else if (i < 124){ y = i-84+1;  x = 0; }
  else             { y = i-124+1; x = 41; }
  us8v z = {0,0,0,0,0,0,0,0};
  *(us8v*)(buf + ((size_t)b*1764 + y*42 + x)*C + c8*8) = z;
}

// ---------------- xW[b][k] = sum_d x[b,d]*Wx[k,d] ----------------
__global__ __launch_bounds__(64) void xw_k(const float* __restrict__ x, const float* __restrict__ Wx,
                                           float* __restrict__ xw){
  int id = blockIdx.x;           // 128*10
  int b = id/10, k = id%10;
  int lane = threadIdx.x;
  float a = 0.f;
  for (int d = lane; d < 300; d += 64)
    a = fmaf(x[b*300+d], Wx[k*300+d], a);
  #pragma unroll
  for (int off=1; off<64; off<<=1) a += __shfl_xor(a, off);
  if (lane==0) xw[b*16+k] = a;
}

// ---------------- pack score weights into MFMA B-fragments ----------------
__global__ void repack_wpack_k(const float* __restrict__ Wh, const float* __restrict__ Wht,
                               u16* __restrict__ wp){
  int id = blockIdx.x*256 + threadIdx.x;
  if (id >= 20480) return;
  int j = id&7, col=(id>>3)&15, kg=(id>>7)&3, rest=id>>9;
  int ks = rest%10, tz = rest/10;
  int k = ks*32 + kg*8 + j;
  const float* src = tz ? Wht : Wh;
  float val = (col<10 && k<300) ? src[col*300+k] : 0.f;
  wp[id] = f2bf(val);
}

// ---------------- fused attention: score (MFMA) + chunk-softmax + weighted sums ----------------
// Block = one (b, 32-row chunk). Emits partials: m, l, hsum[300], csum[300].
// pc loads issued FIRST (deep queue, in flight across the whole block); h re-used from LDS.
__global__ __launch_bounds__(256) void attn_fused(const float* __restrict__ hs, const float* __restrict__ pht,
    const float* __restrict__ pc, const u16* __restrict__ wpack, const float* __restrict__ v,
    const float* __restrict__ xw, float* __restrict__ part){
  __shared__ u16 HL[32][328];
  __shared__ u16 PL[32][328];                 // pht during MFMA, then reused for pc
  __shared__ float PS[2][32][18];
  __shared__ float PP[32];
  __shared__ float ML[2];
  int tid = threadIdx.x;
  int chunk = blockIdx.x, b = blockIdx.y;
  int rr0 = (b<<10) + chunk*32;
  const float* hsrc = hs  + (size_t)rr0*300;
  const float* psrc = pht + (size_t)rr0*300;
  const float* csrc = pc  + (size_t)rr0*300;
  // issue C loads early into registers (needed last; hides under staging+MFMA)
  float4 creg[10];
  #pragma unroll
  for (int rnd=0; rnd<10; rnd++){
    int idx = rnd*256 + tid;
    if (idx < 2400) creg[rnd] = *(const float4*)(csrc + idx*4);
  }
  // stage H, P -> LDS bf16
  #pragma unroll
  for (int rnd=0; rnd<10; rnd++){
    int idx = rnd*256 + tid;
    if (idx < 2400){
      float4 qh = *(const float4*)(hsrc + idx*4);
      float4 qp = *(const float4*)(psrc + idx*4);
      int row = idx/75, colp = (idx - row*75)*4;
      uint2 pvh; pvh.x = pk2(qh.x,qh.y); pvh.y = pk2(qh.z,qh.w);
      uint2 pvp; pvp.x = pk2(qp.x,qp.y); pvp.y = pk2(qp.z,qp.w);
      *(uint2*)(&HL[row][colp]) = pvh;
      *(uint2*)(&PL[row][colp]) = pvp;
    }
  }
  #pragma unroll
  for (int j=0;j<2;j++){
    int idx = j*256 + tid;
    if (idx < 448){
      int row = idx/14, cc = 300 + (idx - row*14)*2;
      *(u32*)(&HL[row][cc]) = 0u;
      *(u32*)(&PL[row][cc]) = 0u;
    }
  }
  __syncthreads();
  // MFMA score phase
  {
    int w = tid>>6, l = tid&63;
    int c = l&15, g = l>>4;
    int tz = w>>1, rf = w&1;
    const u16 (*SL)[328] = tz ? PL : HL;
    const u16* wbase = wpack + (size_t)tz*5120;
    f32x4 acc = (f32x4){0.f,0.f,0.f,0.f};
    #pragma unroll
    for (int ks=0; ks<10; ks++){
      bf16x8 af  = *(const bf16x8*)(&SL[rf*16 + c][ks*32 + g*8]);
      bf16x8 bfr = *(const bf16x8*)(wbase + ((ks*4 + g)*16 + c)*8);
      acc = __builtin_amdgcn_mfma_f32_16x16x32_bf16(af, bfr, acc, 0, 0, 0);
    }
    #pragma unroll
    for (int r=0;r<4;r++) PS[tz][rf*16 + g*4 + r][c] = acc[r];
  }
  __syncthreads();                            // PS done; PL free for reuse
  // write C (bf16) into PL space
  #pragma unroll
  for (int rnd=0; rnd<10; rnd++){
    int idx = rnd*256 + tid;
    if (idx < 2400){
      int row = idx/75, colp = (idx - row*75)*4;
      uint2 pv; pv.x = pk2(creg[rnd].x, creg[rnd].y); pv.y = pk2(creg[rnd].z, creg[rnd].w);
      *(uint2*)(&PL[row][colp]) = pv;
    }
  }
  // chunk softmax stats on wave 0 (lanes 0..31)
  if (tid < 32){
    float s = 0.f;
    #pragma unroll
    for (int k=0;k<10;k++)
      s += v[k]*tanhf(PS[0][tid][k] + PS[1][tid][k] + xw[b*16+k]);
    float m = s;
    #pragma unroll
    for (int off=1; off<32; off<<=1) m = fmaxf(m, __shfl_xor(m, off));
    float p = expf(s - m);
    float l = p;
    #pragma unroll
    for (int off=1; off<32; off<<=1) l += __shfl_xor(l, off);
    PP[tid] = p;
    if (tid==0){ ML[0]=m; ML[1]=l; }
  }
  __syncthreads();
  // weighted sums from LDS; write partials
  float* pp = part + ((size_t)b*32 + chunk)*608;
  if (tid < 150){
    int d = tid*2;
    float h0=0,h1=0,c0=0,c1=0;
    #pragma unroll
    for (int t=0;t<32;t++){
      float p = PP[t];
      u32 hw = *(const u32*)(&HL[t][d]);
      u32 cw = *(const u32*)(&PL[t][d]);
      h0 = fmaf(p, bf2f((u16)hw),       h0);
      h1 = fmaf(p, bf2f((u16)(hw>>16)), h1);
      c0 = fmaf(p, bf2f((u16)cw),       c0);
      c1 = fmaf(p, bf2f((u16)(cw>>16)), c1);
    }
    *(float2*)(pp + 4 + d)   = float2{h0,h1};
    *(float2*)(pp + 308 + d) = float2{c0,c1};
  }
  if (tid==0){ pp[0]=ML[0]; pp[1]=ML[1]; }
}

// ---------------- combine 32 chunk-partials per batch -> ht, ct ----------------
__global__ __launch_bounds__(192) void attn_reduce(const float* __restrict__ part,
    float* __restrict__ ht, float* __restrict__ ct){
  int b = blockIdx.x;
  int tid = threadIdx.x;
  const float* pb = part + (size_t)b*32*608;
  float M = -3.0e38f;
  #pragma unroll
  for (int j=0;j<32;j++) M = fmaxf(M, pb[j*608]);
  float L = 0.f;
  #pragma unroll
  for (int j=0;j<32;j++) L += pb[j*608+1]*expf(pb[j*608]-M);
  if (tid < 150){
    int d = tid*2;
    float a0=0,a1=0,b0=0,b1=0;
    #pragma unroll
    for (int j=0;j<32;j++){
      float w = expf(pb[j*608]-M);
      float2 hh = *(const float2*)(pb + j*608 + 4 + d);
      float2 cc = *(const float2*)(pb + j*608 + 308 + d);
      a0 = fmaf(w,hh.x,a0); a1 = fmaf(w,hh.y,a1);
      b0 = fmaf(w,cc.x,b0); b1 = fmaf(w,cc.y,b1);
    }
    float inv = 1.f/L;
    *(float2*)(ht + (size_t)b*300 + d) = float2{a0*inv, a1*inv};
    *(float2*)(ct + (size_t)b*300 + d) = float2{b0*inv, b1*inv};
  }
}

// ---------------- generic dense layer ----------------
__global__ __launch_bounds__(256) void gemm_k(int mode, int K, int N,
    const float* __restrict__ inA, const float* __restrict__ inX,
    const float* __restrict__ W, const float* __restrict__ bias, float* __restrict__ out){
  __shared__ float aL[32][65];
  __shared__ float wL[32][65];
  int n0 = blockIdx.x*32, b0 = blockIdx.y*32;
  int tid = threadIdx.x;
  int lr = tid>>3, lk = (tid&7)*8;
  int bi = tid>>4, ni = tid&15;
  float a00=0,a01=0,a10=0,a11=0;
  for (int kc=0; kc<K; kc+=64){
    int brow = b0+lr;
    #pragma unroll
    for (int j=0;j<8;j++){
      int k = kc+lk+j;
      float vv = 0.f;
      if (k<K){
        if (mode==0) vv = (k<300) ? inA[brow*300+k] : inX[brow*300 + (k-300)];
        else         vv = inA[(size_t)brow*K + k];
      }
      aL[lr][lk+j] = vv;
    }
    int nrow = n0+lr;
    #pragma unroll
    for (int j=0;j<8;j++){
      int k = kc+lk+j;
      float vv = 0.f;
      if (nrow<N && k<K) vv = W[(size_t)nrow*K + k];
      wL[lr][lk+j] = vv;
    }
    __syncthreads();
    #pragma unroll
    for (int kk=0;kk<64;kk++){
      float x0 = aL[2*bi][kk], x1 = aL[2*bi+1][kk];
      float y0 = wL[2*ni][kk], y1 = wL[2*ni+1][kk];
      a00 = fmaf(x0,y0,a00); a01 = fmaf(x0,y1,a01);
      a10 = fmaf(x1,y0,a10); a11 = fmaf(x1,y1,a11);
    }
    __syncthreads();
  }
  int b = b0 + 2*bi, n = n0 + 2*ni;
  if (n < N){
    float bb = bias[n];
    out[(size_t)b*N+n]     = a00+bb;
    out[(size_t)(b+1)*N+n] = a10+bb;
  }
  if (n+1 < N){
    float bb = bias[n+1];
    out[(size_t)b*N+n+1]     = a01+bb;
    out[(size_t)(b+1)*N+n+1] = a11+bb;
  }
}

// ---------------- scatter pre (whx2) into padded P0 (bf16) ----------------
__global__ __launch_bounds__(256) void scat_k(const float* __restrict__ whx2, u16* __restrict__ p0){
  int id = blockIdx.x*256 + threadIdx.x;          // 128*1600
  int b = id/1600, p = id%1600;
  int y = p/40, x = p%40;
  p0[(size_t)b*1764 + (y+1)*42 + (x+1)] = f2bf(whx2[id]);
}

// ---------------- conv weight repack (direct kernels): w2[ci][k][co] f32 ----------------
__global__ void repack_k(const float* __restrict__ w, const float* __restrict__ bb,
                         const float* __restrict__ g, const float* __restrict__ be,
                         float* __restrict__ w2, float* __restrict__ par, int CI, int CO){
  int id = blockIdx.x*256 + threadIdx.x;
  int tot = CI*CO*9;
  if (id < tot){
    int co = id % CO;
    int rem = id / CO;
    int k = rem % 9, ci = rem / 9;
    w2[id] = w[(co*CI + ci)*9 + k];
  }
  if (id < CO){
    par[id]      = bb[id];
    par[CO+id]   = g[id] * (1.0f/sqrtf(1.00001f));
    par[2*CO+id] = be[id];
  }
}

// ---------------- conv weight repack (MFMA kernels): wB[co][dydx][ci] bf16 ----------------
__global__ void repack_mfma_k(const float* __restrict__ w, const float* __restrict__ bb,
                              const float* __restrict__ g, const float* __restrict__ be,
                              u16* __restrict__ wB, float* __restrict__ par, int CI, int CO){
  int id = blockIdx.x*256 + threadIdx.x;
  int tot = CI*CO*9;
  if (id < tot){
    int ci = id % CI;
    int rem = id / CI;
    int dydx = rem % 9, co = rem / 9;
    wB[id] = f2bf(w[(co*CI + ci)*9 + dydx]);
  }
  if (id < CO){
    par[id]      = bb[id];
    par[CO+id]   = g[id] * (1.0f/sqrtf(1.00001f));
    par[2*CO+id] = be[id];
  }
}

// ---------------- LDS-tiled implicit-GEMM MFMA conv 3x3 + bias + relu + bn ----------------
template<int CI, int CO>
__global__ __launch_bounds__(256) void conv_tile(const u16* __restrict__ in, u16* __restrict__ out,
    const u16* __restrict__ wB, const float* __restrict__ par){
  constexpr int PCI  = CI + 8;           // padded LDS channel stride (u16)
  constexpr int MF   = CO/16;            // m-groups (4 or 2)
  constexpr int FPW  = MF;               // pixel-frags per wave (4 or 2)
  constexpr int KC   = CI/32;            // K-chunks
  constexpr int KROW = CI*9;
  constexpr int CH8  = CI/8;
  __shared__ u16 TIN[100*PCI];
  int tile = blockIdx.x;                 // 0..24 (5x5 tiles of 8x8)
  int b = blockIdx.y;
  int y0 = (tile/5)*8, x0 = (tile%5)*8;
  const u16* inb = in + (size_t)b*1764*CI;
  for (int g = threadIdx.x; g < 100*CH8; g += 256){
    int pix = g/CH8, ch = g - pix*CH8;
    int r = pix/10, cc = pix - r*10;
    us8v vdat = *(const us8v*)(inb + ((size_t)(y0+r)*42 + (x0+cc))*CI + ch*8);
    *(us8v*)(&TIN[pix*PCI + ch*8]) = vdat;
  }
  __syncthreads();
  int w = threadIdx.x>>6, l = threadIdx.x&63;
  int c = l&15, kg = l>>4;
  int mg, f0;
  if (MF==4){ mg = w; f0 = 0; } else { mg = w&1; f0 = (w>>1)*2; }
  int pxb[FPW];
  #pragma unroll
  for (int fi=0; fi<FPW; fi++){
    int px = (f0+fi)*16 + c;
    int ty = px>>3, tx = px&7;
    pxb[fi] = (ty*10 + tx)*PCI + kg*8;
  }
  const u16* wrow = wB + (size_t)(mg*16 + c)*KROW;
  f32x4 acc[FPW];
  #pragma unroll
  for (int fi=0; fi<FPW; fi++) acc[fi] = (f32x4){0.f,0.f,0.f,0.f};
  #pragma unroll
  for (int dy=0;dy<3;dy++)
  #pragma unroll
  for (int dx=0;dx<3;dx++){
    int dydx = dy*3+dx;
    #pragma unroll
    for (int kc=0; kc<KC; kc++){
      bf16x8 af = *(const bf16x8*)(wrow + dydx*CI + kc*32 + kg*8);
      #pragma unroll
      for (int fi=0; fi<FPW; fi++){
        bf16x8 bf = *(const bf16x8*)(&TIN[pxb[fi] + (dy*10+dx)*PCI + kc*32]);
        acc[fi] = __builtin_amdgcn_mfma_f32_16x16x32_bf16(af, bf, acc[fi], 0, 0, 0);
      }
    }
  }
  u16* ob = out + (size_t)b*1764*CO;
  int co0 = mg*16 + kg*4;
  const float4 bia = *(const float4*)(par + co0);
  const float4 sc  = *(const float4*)(par + CO + co0);
  const float4 be  = *(const float4*)(par + 2*CO + co0);
  #pragma unroll
  for (int fi=0; fi<FPW; fi++){
    int px = (f0+fi)*16 + c;
    int y = y0 + (px>>3), x = x0 + (px&7);
    ushort4 s;
    s.x = f2bf(fmaxf(acc[fi][0]+bia.x,0.f)*sc.x + be.x);
    s.y = f2bf(fmaxf(acc[fi][1]+bia.y,0.f)*sc.y + be.y);
    s.z = f2bf(fmaxf(acc[fi][2]+bia.z,0.f)*sc.z + be.z);
    s.w = f2bf(fmaxf(acc[fi][3]+bia.w,0.f)*sc.w + be.w);
    *(ushort4*)(ob + (size_t)((y+1)*42 + (x+1))*CO + co0) = s;
  }
}

// ---------------- conv1 direct 1->32 (tiny K, keep direct) ----------------
template<int CI, int CO, bool TT>
__global__ __launch_bounds__(256) void conv_main(const u16* __restrict__ in, u16* __restrict__ out,
    const float* __restrict__ w2, const float* __restrict__ par){
  int b = blockIdx.x;
  int wave = threadIdx.x >> 6;
  int lane = threadIdx.x & 63;
  int tile, co;
  if (TT){ tile = blockIdx.y*8 + wave*2 + (lane>>5); co = lane & 31; }
  else   { tile = blockIdx.y*4 + wave;               co = lane; }
  int y0 = (tile >> 3)*5, x0 = (tile & 7)*5;          // padded window origin
  const u16* inb = in + (size_t)b*1764*CI;
  float acc[25];
  #pragma unroll
  for (int p=0;p<25;p++) acc[p]=0.f;
  for (int ci=0; ci<CI; ci++){
    float win[49];
    #pragma unroll
    for (int r=0;r<7;r++)
      #pragma unroll
      for (int c=0;c<7;c++)
        win[r*7+c] = bf2f(inb[ ((y0+r)*42 + (x0+c))*CI + ci ]);
    float wk[9];
    #pragma unroll
    for (int k=0;k<9;k++) wk[k] = w2[(ci*9+k)*CO + co];
    #pragma unroll
    for (int py=0;py<5;py++)
      #pragma unroll
      for (int px=0;px<5;px++){
        float s = acc[py*5+px];
        #pragma unroll
        for (int dy=0;dy<3;dy++)
          #pragma unroll
          for (int dx=0;dx<3;dx++)
            s = fmaf(wk[dy*3+dx], win[(py+dy)*7 + (px+dx)], s);
        acc[py*5+px] = s;
      }
  }
  float bia = par[co], sc = par[CO+co], be = par[2*CO+co];
  u16* outb = out + (size_t)b*1764*CO;
  #pragma unroll
  for (int py=0;py<5;py++)
    #pragma unroll
    for (int px=0;px<5;px++){
      float vv = fmaxf(acc[py*5+px] + bia, 0.f)*sc + be;
      outb[ ((y0+py+1)*42 + (x0+px+1))*CO + co ] = f2bf(vv);
    }
}

// ---------------- c6: 32 -> 1 channel (vectorized input loads) ----------------
__global__ __launch_bounds__(256) void conv_c6(const u16* __restrict__ in, u16* __restrict__ y6,
    const float* __restrict__ w6, const float* __restrict__ par6){
  int id = blockIdx.x*256 + threadIdx.x;          // 128*1600
  int b = id/1600, p = id%1600;
  int y = p/40, x = p%40;
  const u16* inb = in + (size_t)b*1764*32;
  float acc = 0.f;
  #pragma unroll
  for (int dy=0;dy<3;dy++)
    #pragma unroll
    for (int dx=0;dx<3;dx++){
      const u16* q = inb + ((y+dy)*42 + (x+dx))*32;
      int k = dy*3+dx;
      #pragma unroll
      for (int g=0; g<4; g++){
        us8v vv8 = *(const us8v*)(q + g*8);
        #pragma unroll
        for (int j=0;j<8;j++)
          acc = fmaf(w6[(g*8+j)*9 + k], bf2f(vv8[j]), acc);
      }
    }
  float vv = fmaxf(acc + par6[0], 0.f)*par6[1] + par6[2];
  y6[(size_t)b*1764 + (y+1)*42 + (x+1)] = f2bf(vv);
}

// ---------------- pc: concat(pre, y6) 2 -> 1 channel, no relu ----------------
__global__ __launch_bounds__(256) void conv_pc(const u16* __restrict__ p0, const u16* __restrict__ y6,
    const float* __restrict__ pcw, const float* __restrict__ pcb,
    const float* __restrict__ pcg, const float* __restrict__ pcbe,
    float* __restrict__ out1600){
  int id = blockIdx.x*256 + threadIdx.x;          // 128*1600
  int b = id/1600, p = id%1600;
  int y = p/40, x = p%40;
  float acc = 0.f;
  #pragma unroll
  for (int dy=0;dy<3;dy++)
    #pragma unroll
    for (int dx=0;dx<3;dx++){
      size_t o = (size_t)b*1764 + (y+dy)*42 + (x+dx);
      acc = fmaf(pcw[dy*3+dx],     bf2f(p0[o]), acc);
      acc = fmaf(pcw[9 + dy*3+dx], bf2f(y6[o]), acc);
    }
  float sc = pcg[0] * (1.0f/sqrtf(1.00001f));
  out1600[id] = (acc + pcb[0])*sc + pcbe[0];
}

// ---------------- LSTM gating ----------------
__global__ __launch_bounds__(256) void gate_k(const float* __restrict__ whx3, const float* __restrict__ ct,
                                              float* __restrict__ outp){
  int id = blockIdx.x*256 + threadIdx.x;          // 128*300
  if (id >= 38400) return;
  int b = id/300, d = id%300;
  const float* r = whx3 + (size_t)b*1200;
  float ft = 1.f/(1.f+expf(-r[d]));
  float ot = 1.f/(1.f+expf(-r[300+d]));
  float it = 1.f/(1.f+expf(-r[600+d]));
  float ch = tanhf(r[900+d]);
  float c  = ft*ct[id] + it*ch;
  outp[id] = ot*tanhf(c);
}

extern "C" void kernel_launch(void* const* d_in, const int* in_sizes, int n_in,
                              void* d_out, int out_size, void* d_ws, size_t ws_size,
                              hipStream_t stream){
  const float* x    = (const float*)d_in[0];
  const float* hs   = (const float*)d_in[1];
  const float* pht  = (const float*)d_in[2];
  const float* pc   = (const float*)d_in[3];
  const float* W    = (const float*)d_in[4];
  const float* bb   = (const float*)d_in[5];
  const float* Wh   = (const float*)d_in[6];
  const float* Wx   = (const float*)d_in[7];
  const float* Wht  = (const float*)d_in[8];
  const float* v    = (const float*)d_in[9];
  const float* rbw  = (const float*)d_in[10];
  const float* rbb  = (const float*)d_in[11];
  const float* rpw  = (const float*)d_in[12];
  const float* rpb  = (const float*)d_in[13];
  const float *cw[6], *cb[6], *cg[6], *cbe[6];
  for (int i=0;i<6;i++){
    cw[i]=(const float*)d_in[14+4*i]; cb[i]=(const float*)d_in[15+4*i];
    cg[i]=(const float*)d_in[16+4*i]; cbe[i]=(const float*)d_in[17+4*i];
  }
  const float* pcw = (const float*)d_in[38];
  const float* pcb = (const float*)d_in[39];
  const float* pcg = (const float*)d_in[40];
  const float* pcbe= (const float*)d_in[41];

  char* ws = (char*)d_ws;
  float* xw    = (float*)(ws + OFF_XW);
  float* whx1  = (float*)(ws + OFF_WHX1);
  float* whx2  = (float*)(ws + OFF_WHX2);
  float* o1600 = (float*)(ws + OFF_O1600);
  float* whx3  = (float*)(ws + OFF_WHX3);
  float* w21   = (float*)(ws + OFF_W21);
  u16*   wb2   = (u16*)  (ws + OFF_WB2);
  u16*   wb3   = (u16*)  (ws + OFF_WB3);
  u16*   wb4   = (u16*)  (ws + OFF_WB4);
  u16*   wb5   = (u16*)  (ws + OFF_WB5);
  float* w26   = (float*)(ws + OFF_W26);
  u16*   wpack = (u16*)  (ws + OFF_WPACK);
  float* part  = (float*)(ws + OFF_PART);
  float* par[6];
  for (int i=0;i<6;i++) par[i] = (float*)(ws + OFF_PAR + (size_t)i*768);
  float* ht = (float*)(ws + OFF_HT);
  float* ct = (float*)(ws + OFF_CT);
  u16* A32 = (u16*)(ws + OFF_A32);
  u16* B64 = (u16*)(ws + OFF_B64);
  u16* C64 = (u16*)(ws + OFF_C64);
  u16* P0  = (u16*)(ws + OFF_P0);
  u16* Y6  = (u16*)(ws + OFF_Y6);

  // 0) zero: P0/Y6 (fully), border rings of NHWC bufs (ht/ct/part fully overwritten each call)
  zero_k<<<221,256,0,stream>>>((uint4*)(ws + OFF_P0), ZB2/16);
  border_k<32><<<(128*164*4 +255)/256,256,0,stream>>>(A32);
  border_k<64><<<(128*164*8 +255)/256,256,0,stream>>>(B64);
  border_k<64><<<(128*164*8 +255)/256,256,0,stream>>>(C64);

  // 1) fused attention
  xw_k<<<1280,64,0,stream>>>(x, Wx, xw);
  repack_wpack_k<<<80,256,0,stream>>>(Wh, Wht, wpack);
  attn_fused<<<dim3(32,128),256,0,stream>>>(hs, pht, pc, wpack, v, xw, part);
  attn_reduce<<<128,192,0,stream>>>(part, ht, ct);

  // 2) dense layers to pre
  gemm_k<<<dim3(38,4),256,0,stream>>>(0,  600, 1200, ht, x,      W,   bb,  whx1);
  gemm_k<<<dim3(50,4),256,0,stream>>>(1, 1200, 1600, whx1, nullptr, rbw, rbb, whx2);
  scat_k<<<800,256,0,stream>>>(whx2, P0);

  // 3) conv block
  repack_k<<<2,  256,0,stream>>>(cw[0],cb[0],cg[0],cbe[0], w21, par[0],  1, 32);
  repack_mfma_k<<<72, 256,0,stream>>>(cw[1],cb[1],cg[1],cbe[1], wb2, par[1], 32, 64);
  repack_mfma_k<<<144,256,0,stream>>>(cw[2],cb[2],cg[2],cbe[2], wb3, par[2], 64, 64);
  repack_mfma_k<<<144,256,0,stream>>>(cw[3],cb[3],cg[3],cbe[3], wb4, par[3], 64, 64);
  repack_mfma_k<<<72, 256,0,stream>>>(cw[4],cb[4],cg[4],cbe[4], wb5, par[4], 64, 32);
  repack_k<<<2,  256,0,stream>>>(cw[5],cb[5],cg[5],cbe[5], w26, par[5], 32,  1);

  conv_main<1,32,true><<<dim3(128,8),256,0,stream>>>(P0, A32, w21, par[0]);
  conv_tile<32,64><<<dim3(25,128),256,0,stream>>>(A32, B64, wb2, par[1]);
  conv_tile<64,64><<<dim3(25,128),256,0,stream>>>(B64, C64, wb3, par[2]);
  conv_tile<64,64><<<dim3(25,128),256,0,stream>>>(C64, B64, wb4, par[3]);
  conv_tile<64,32><<<dim3(25,128),256,0,stream>>>(B64, A32, wb5, par[4]);
  conv_c6<<<800,256,0,stream>>>(A32, Y6, w26, par[5]);
  conv_pc<<<800,256,0,stream>>>(P0, Y6, pcw, pcb, pcg, pcbe, o1600);

  // 4) final projection + gating
  gemm_k<<<dim3(38,4),256,0,stream>>>(1, 1600, 1200, o1600, nullptr, rpw, rpb, whx3);
  gate_k<<<150,256,0,stream>>>(whx3, ct, (float*)d_out);
}

// Round 9
// 358.237 us; speedup vs baseline: 4.7893x; 1.4871x over previous
//
#include <hip/hip_runtime.h>
#include <hip/hip_bf16.h>
#include <cstdint>
#include <cstddef>

typedef unsigned short u16;
typedef unsigned int u32;

#define DEV __device__ __forceinline__

DEV float bf2f(u16 u){ union{unsigned int i; float f;} c; c.i = ((unsigned)u)<<16; return c.f; }
DEV u16 f2bf(float f){ union{float f;unsigned int i;} c; c.f=f; unsigned int r = c.i + 0x7FFFu + ((c.i>>16)&1u); return (u16)(r>>16); }
DEV unsigned int pk2(float a, float b){
  __hip_bfloat162 t = __float22bfloat162_rn(float2{a,b});   // v_cvt_pk_bf16_f32
  union { __hip_bfloat162 h; unsigned int u; } cv; cv.h = t; return cv.u;
}

typedef __attribute__((ext_vector_type(8))) short bf16x8;
typedef __attribute__((ext_vector_type(4))) float f32x4;
typedef __attribute__((ext_vector_type(8))) unsigned short us8v;

// ---------------- workspace layout (bytes, all 16B aligned) ----------------
static constexpr size_t OFF_XW    = 0;                                   // [128][16] f32
static constexpr size_t OFF_WHX2  = 8192;                                // [128][1600] f32
static constexpr size_t OFF_WHX3  = OFF_WHX2 + (size_t)128*1600*4;       // [128][1200] f32
static constexpr size_t OFF_W21   = OFF_WHX3 + (size_t)128*1200*4;       // conv1 w [ci][k][co] f32
static constexpr size_t OFF_WB2   = OFF_W21  + (size_t)288*4;            // conv2 w bf16
static constexpr size_t OFF_WB3   = OFF_WB2  + (size_t)18432*2;
static constexpr size_t OFF_WB4   = OFF_WB3  + (size_t)36864*2;
static constexpr size_t OFF_WB5   = OFF_WB4  + (size_t)36864*2;
static constexpr size_t OFF_W26   = OFF_WB5  + (size_t)18432*2;          // conv6 w f32 [ci][k]
static constexpr size_t OFF_PAR   = OFF_W26  + (size_t)288*4;            // 6 x 768B
static constexpr size_t OFF_WPACK = OFF_PAR  + (size_t)6*768;            // score B-frags bf16
static constexpr size_t OFF_WB1G  = OFF_WPACK+ (size_t)20480*2;          // gemm1 W [1216][608] bf16
static constexpr size_t OFF_RBWB  = OFF_WB1G + (size_t)1216*608*2;       // gemm2 W [1600][1216] bf16
static constexpr size_t OFF_RPWB  = OFF_RBWB + (size_t)1600*1216*2;      // gemm3 W [1216][1600] bf16
static constexpr size_t OFF_CAT   = OFF_RPWB + (size_t)1216*1600*2;      // [128][608] bf16 (concat ht,x)
static constexpr size_t OFF_WHX1B = OFF_CAT  + (size_t)128*608*2;        // [128][1216] bf16
static constexpr size_t OFF_O16B  = OFF_WHX1B+ (size_t)128*1216*2;       // [128][1600] bf16
static constexpr size_t OFF_CT    = OFF_O16B + (size_t)128*1600*2;       // [128][300] f32
static constexpr size_t OFF_A32   = OFF_CT   + (size_t)128*300*4;        // [128][1764][32] bf16
static constexpr size_t OFF_B64   = OFF_A32  + (size_t)128*1764*32*2;    // [128][1764][64] bf16
static constexpr size_t OFF_C64   = OFF_B64  + (size_t)128*1764*64*2;    // [128][1764][64] bf16
static constexpr size_t OFF_P0    = OFF_C64  + (size_t)128*1764*64*2;    // [128][1764] bf16
static constexpr size_t OFF_Y6    = OFF_P0   + (size_t)128*1764*2;       // [128][1764] bf16
static constexpr size_t OFF_PART  = OFF_C64;  // attn partials alias C64 (dead before conv3 writes)

// ---------------- zero rings of P0/Y6 + cat pad ----------------
DEV void ring0(u16* buf, int j){
  int b = j/164, i = j%164;
  int y, x;
  if      (i < 42){ y = 0;        x = i; }
  else if (i < 84){ y = 41;       x = i-42; }
  else if (i < 124){ y = i-84+1;  x = 0; }
  else             { y = i-124+1; x = 41; }
  buf[(size_t)b*1764 + y*42 + x] = 0;
}
__global__ __launch_bounds__(256) void zero_mega(u16* __restrict__ p0, u16* __restrict__ y6,
                                                 u16* __restrict__ catb){
  int id = blockIdx.x*256 + threadIdx.x;
  if (id < 20992) ring0(p0, id);
  else if (id < 41984) ring0(y6, id-20992);
  else if (id < 42112){
    int b = id - 41984;
    us8v z = {0,0,0,0,0,0,0,0};
    *(us8v*)(catb + (size_t)b*608 + 600) = z;
  }
}

// ---------------- mega repack: all weights + BN pars ----------------
struct RArgs {
  const float* cw[6]; const float* cb[6]; const float* cg[6]; const float* cbe[6];
  const float* Wh; const float* Wht; const float* Wg; const float* rbw; const float* rpw;
  float* w21; float* w26; float* par;
  u16 *wb2, *wb3, *wb4, *wb5, *wpack, *Wb1, *rbwb, *rpwb;
};
DEV void cvW(const float* w, u16* dst, size_t j, int CI){
  int ci = j % CI; size_t rem = j / CI; int dydx = rem % 9; int co = rem / 9;
  dst[j] = f2bf(w[((size_t)co*CI + ci)*9 + dydx]);
}
__global__ __launch_bounds__(256) void mega_repack(RArgs a){
  const float isc = 1.0f/sqrtf(1.00001f);
  for (size_t id = (size_t)blockIdx.x*256 + threadIdx.x; id < 4762947ull;
       id += (size_t)gridDim.x*256){
    if (id < 288){
      int co = id % 32; size_t rem = id / 32; int k = rem % 9;
      a.w21[id] = a.cw[0][co*9 + k];
    } else if (id < 18720){ cvW(a.cw[1], a.wb2, id-288, 32); }
    else if (id < 55584){ cvW(a.cw[2], a.wb3, id-18720, 64); }
    else if (id < 92448){ cvW(a.cw[3], a.wb4, id-55584, 64); }
    else if (id < 110880){ cvW(a.cw[4], a.wb5, id-92448, 64); }
    else if (id < 111168){
      size_t j = id - 110880;              // w26 identity [ci*9+k]
      a.w26[j] = a.cw[5][j];
    } else if (id < 131648){
      size_t j = id - 111168;              // wpack
      int jj = j&7, col=(int)((j>>3)&15), kg=(int)((j>>7)&3); size_t rest=j>>9;
      int ks = (int)(rest%10), tz = (int)(rest/10);
      int k = ks*32 + kg*8 + jj;
      const float* src = tz ? a.Wht : a.Wh;
      a.wpack[j] = f2bf((col<10 && k<300)? src[col*300+k] : 0.f);
    } else if (id < 870976){
      size_t j = id - 131648; int k = (int)(j % 608); int n = (int)(j / 608);
      a.Wb1[j] = f2bf((n<1200 && k<600)? a.Wg[(size_t)n*600+k] : 0.f);
    } else if (id < 2816576){
      size_t j = id - 870976; int k = (int)(j % 1216); int n = (int)(j / 1216);
      a.rbwb[j] = f2bf((k<1200)? a.rbw[(size_t)n*1200+k] : 0.f);
    } else if (id < 4762176){
      size_t j = id - 2816576; int k = (int)(j % 1600); int n = (int)(j / 1600);
      a.rpwb[j] = f2bf((n<1200)? a.rpw[(size_t)n*1600+k] : 0.f);
    } else {
      size_t j = id - 4762176;             // 771 par entries
      int ci, CO; size_t base;
      if (j < 96){ ci=0; CO=32; base=0; }
      else if (j < 288){ ci=1; CO=64; base=96; }
      else if (j < 480){ ci=2; CO=64; base=288; }
      else if (j < 672){ ci=3; CO=64; base=480; }
      else if (j < 768){ ci=4; CO=32; base=672; }
      else { ci=5; CO=1; base=768; }
      size_t jj = j - base; int t = (int)(jj / CO); int c = (int)(jj % CO);
      float* p = a.par + (size_t)ci*192;
      p[t*CO + c] = (t==0)? a.cb[ci][c] : (t==1)? a.cg[ci][c]*isc : a.cbe[ci][c];
    }
  }
}

// ---------------- xW[b][k] = sum_d x[b,d]*Wx[k,d] ----------------
__global__ __launch_bounds__(64) void xw_k(const float* __restrict__ x, const float* __restrict__ Wx,
                                           float* __restrict__ xw){
  int id = blockIdx.x;           // 128*10
  int b = id/10, k = id%10;
  int lane = threadIdx.x;
  float a = 0.f;
  for (int d = lane; d < 300; d += 64)
    a = fmaf(x[b*300+d], Wx[k*300+d], a);
  #pragma unroll
  for (int off=1; off<64; off<<=1) a += __shfl_xor(a, off);
  if (lane==0) xw[b*16+k] = a;
}

// ---------------- fused attention ----------------
__global__ __launch_bounds__(256,3) void attn_fused(const float* __restrict__ hs, const float* __restrict__ pht,
    const float* __restrict__ pc, const u16* __restrict__ wpack, const float* __restrict__ v,
    const float* __restrict__ xw, float* __restrict__ part){
  __shared__ u16 HL[32][328];
  __shared__ u16 PL[32][328];                 // pht during MFMA, then reused for pc
  __shared__ float PS[2][32][18];
  __shared__ float PP[32];
  __shared__ float ML[2];
  int tid = threadIdx.x;
  int chunk = blockIdx.x, b = blockIdx.y;
  int rr0 = (b<<10) + chunk*32;
  const float* hsrc = hs  + (size_t)rr0*300;
  const float* psrc = pht + (size_t)rr0*300;
  const float* csrc = pc  + (size_t)rr0*300;
  float4 creg[10];
  #pragma unroll
  for (int rnd=0; rnd<10; rnd++){
    int idx = rnd*256 + tid;
    if (idx < 2400) creg[rnd] = *(const float4*)(csrc + idx*4);
  }
  #pragma unroll
  for (int rnd=0; rnd<10; rnd++){
    int idx = rnd*256 + tid;
    if (idx < 2400){
      float4 qh = *(const float4*)(hsrc + idx*4);
      float4 qp = *(const float4*)(psrc + idx*4);
      int row = idx/75, colp = (idx - row*75)*4;
      uint2 pvh; pvh.x = pk2(qh.x,qh.y); pvh.y = pk2(qh.z,qh.w);
      uint2 pvp; pvp.x = pk2(qp.x,qp.y); pvp.y = pk2(qp.z,qp.w);
      *(uint2*)(&HL[row][colp]) = pvh;
      *(uint2*)(&PL[row][colp]) = pvp;
    }
  }
  #pragma unroll
  for (int j=0;j<2;j++){
    int idx = j*256 + tid;
    if (idx < 448){
      int row = idx/14, cc = 300 + (idx - row*14)*2;
      *(u32*)(&HL[row][cc]) = 0u;
      *(u32*)(&PL[row][cc]) = 0u;
    }
  }
  __syncthreads();
  {
    int w = tid>>6, l = tid&63;
    int c = l&15, g = l>>4;
    int tz = w>>1, rf = w&1;
    const u16 (*SL)[328] = tz ? PL : HL;
    const u16* wbase = wpack + (size_t)tz*5120;
    f32x4 acc = (f32x4){0.f,0.f,0.f,0.f};
    #pragma unroll
    for (int ks=0; ks<10; ks++){
      bf16x8 af  = *(const bf16x8*)(&SL[rf*16 + c][ks*32 + g*8]);
      bf16x8 bfr = *(const bf16x8*)(wbase + ((ks*4 + g)*16 + c)*8);
      acc = __builtin_amdgcn_mfma_f32_16x16x32_bf16(af, bfr, acc, 0, 0, 0);
    }
    #pragma unroll
    for (int r=0;r<4;r++) PS[tz][rf*16 + g*4 + r][c] = acc[r];
  }
  __syncthreads();                            // PS done; PL free for reuse
  #pragma unroll
  for (int rnd=0; rnd<10; rnd++){
    int idx = rnd*256 + tid;
    if (idx < 2400){
      int row = idx/75, colp = (idx - row*75)*4;
      uint2 pv; pv.x = pk2(creg[rnd].x, creg[rnd].y); pv.y = pk2(creg[rnd].z, creg[rnd].w);
      *(uint2*)(&PL[row][colp]) = pv;
    }
  }
  if (tid < 32){
    float s = 0.f;
    #pragma unroll
    for (int k=0;k<10;k++)
      s += v[k]*tanhf(PS[0][tid][k] + PS[1][tid][k] + xw[b*16+k]);
    float m = s;
    #pragma unroll
    for (int off=1; off<32; off<<=1) m = fmaxf(m, __shfl_xor(m, off));
    float p = expf(s - m);
    float l = p;
    #pragma unroll
    for (int off=1; off<32; off<<=1) l += __shfl_xor(l, off);
    PP[tid] = p;
    if (tid==0){ ML[0]=m; ML[1]=l; }
  }
  __syncthreads();
  float* pp = part + ((size_t)b*32 + chunk)*608;
  if (tid < 150){
    int d = tid*2;
    float h0=0,h1=0,c0=0,c1=0;
    #pragma unroll
    for (int t=0;t<32;t++){
      float p = PP[t];
      u32 hw = *(const u32*)(&HL[t][d]);
      u32 cw = *(const u32*)(&PL[t][d]);
      h0 = fmaf(p, bf2f((u16)hw),       h0);
      h1 = fmaf(p, bf2f((u16)(hw>>16)), h1);
      c0 = fmaf(p, bf2f((u16)cw),       c0);
      c1 = fmaf(p, bf2f((u16)(cw>>16)), c1);
    }
    *(float2*)(pp + 4 + d)   = float2{h0,h1};
    *(float2*)(pp + 308 + d) = float2{c0,c1};
  }
  if (tid==0){ pp[0]=ML[0]; pp[1]=ML[1]; }
}

// ---------------- combine chunk-partials -> ct (f32) + cat600b (bf16: [ht|x]) ----------------
__global__ __launch_bounds__(192) void attn_reduce(const float* __restrict__ part,
    const float* __restrict__ x, float* __restrict__ ct, u16* __restrict__ catb){
  int b = blockIdx.x;
  int tid = threadIdx.x;
  const float* pb = part + (size_t)b*32*608;
  float M = -3.0e38f;
  #pragma unroll
  for (int j=0;j<32;j++) M = fmaxf(M, pb[j*608]);
  float L = 0.f;
  #pragma unroll
  for (int j=0;j<32;j++) L += pb[j*608+1]*expf(pb[j*608]-M);
  if (tid < 150){
    int d = tid*2;
    float a0=0,a1=0,b0=0,b1=0;
    #pragma unroll
    for (int j=0;j<32;j++){
      float w = expf(pb[j*608]-M);
      float2 hh = *(const float2*)(pb + j*608 + 4 + d);
      float2 cc = *(const float2*)(pb + j*608 + 308 + d);
      a0 = fmaf(w,hh.x,a0); a1 = fmaf(w,hh.y,a1);
      b0 = fmaf(w,cc.x,b0); b1 = fmaf(w,cc.y,b1);
    }
    float inv = 1.f/L;
    *(float2*)(ct + (size_t)b*300 + d) = float2{b0*inv, b1*inv};
    *(u32*)(catb + (size_t)b*608 + d)       = pk2(a0*inv, a1*inv);
    *(u32*)(catb + (size_t)b*608 + 300 + d) = pk2(x[(size_t)b*300 + d], x[(size_t)b*300 + d + 1]);
  }
}

// ---------------- MFMA dense layer: out[b][n] = bias[n] + sum_k inB[b,k]*Wb[n,k] ----------------
// Split-K over the 4 waves; LDS reduce; wave 0 epilogue. A=W rows, B=batch cols.
template<int KP, bool OUTBF>
__global__ __launch_bounds__(256) void gemm_mfma(int NW, int NB, int ldo,
    const u16* __restrict__ inB, const u16* __restrict__ Wb,
    const float* __restrict__ bias, void* __restrict__ outp){
  __shared__ float red[4][64][4];
  int w = threadIdx.x>>6, l = threadIdx.x&63;
  int c = l&15, g = l>>4;
  int n0 = blockIdx.x*16;
  int b0 = blockIdx.y*16;
  const u16* arow = Wb  + (size_t)(n0 + c)*KP + g*8;
  const u16* brow = inB + (size_t)(b0 + c)*KP + g*8;
  f32x4 acc = (f32x4){0.f,0.f,0.f,0.f};
  for (int ks = w; ks < KP/32; ks += 4){
    bf16x8 af = *(const bf16x8*)(arow + ks*32);
    bf16x8 bf = *(const bf16x8*)(brow + ks*32);
    acc = __builtin_amdgcn_mfma_f32_16x16x32_bf16(af, bf, acc, 0, 0, 0);
  }
  #pragma unroll
  for (int r=0;r<4;r++) red[w][l][r] = acc[r];
  __syncthreads();
  if (w==0){
    float s0 = red[0][l][0]+red[1][l][0]+red[2][l][0]+red[3][l][0];
    float s1 = red[0][l][1]+red[1][l][1]+red[2][l][1]+red[3][l][1];
    float s2 = red[0][l][2]+red[1][l][2]+red[2][l][2]+red[3][l][2];
    float s3 = red[0][l][3]+red[1][l][3]+red[2][l][3]+red[3][l][3];
    int b = b0 + c, nb = n0 + g*4;
    if (nb < NW){
      float4 bi;
      if (nb < NB) bi = *(const float4*)(bias + nb);
      else { bi.x=0; bi.y=0; bi.z=0; bi.w=0; }
      float o0=s0+bi.x, o1=s1+bi.y, o2=s2+bi.z, o3=s3+bi.w;
      if (OUTBF){
        ushort4 st; st.x=f2bf(o0); st.y=f2bf(o1); st.z=f2bf(o2); st.w=f2bf(o3);
        *(ushort4*)((u16*)outp + (size_t)b*ldo + nb) = st;
      } else {
        float4 st; st.x=o0; st.y=o1; st.z=o2; st.w=o3;
        *(float4*)((float*)outp + (size_t)b*ldo + nb) = st;
      }
    }
  }
}

// ---------------- scat (whx2 -> P0 bf16) + border rings of NHWC bufs ----------------
DEV void bzero(u16* buf, int j, int CH, int C){
  int c8 = j % CH; int rem = j / CH;
  int i = rem % 164, b = rem / 164;
  int y, x;
  if      (i < 42){ y = 0;        x = i; }
  else if (i < 84){ y = 41;       x = i-42; }
  else if (i < 124){ y = i-84+1;  x = 0; }
  else             { y = i-124+1; x = 41; }
  us8v z = {0,0,0,0,0,0,0,0};
  *(us8v*)(buf + ((size_t)b*1764 + y*42 + x)*C + c8*8) = z;
}
__global__ __launch_bounds__(256) void scat_border(const float* __restrict__ whx2, u16* __restrict__ p0,
    u16* __restrict__ A32, u16* __restrict__ B64, u16* __restrict__ C64){
  int id = blockIdx.x*256 + threadIdx.x;
  if (id < 204800){
    int b = id/1600, p = id%1600;
    int y = p/40, x = p%40;
    p0[(size_t)b*1764 + (y+1)*42 + (x+1)] = f2bf(whx2[id]);
  } else if (id < 288768){ bzero(A32, id-204800, 4, 32); }
  else if (id < 456704){ bzero(B64, id-288768, 8, 64); }
  else { bzero(C64, id-456704, 8, 64); }
}

// ---------------- LDS-tiled implicit-GEMM MFMA conv 3x3 + bias + relu + bn ----------------
template<int CI, int CO>
__global__ __launch_bounds__(256) void conv_tile(const u16* __restrict__ in, u16* __restrict__ out,
    const u16* __restrict__ wB, const float* __restrict__ par){
  constexpr int PCI  = CI + 8;
  constexpr int MF   = CO/16;
  constexpr int FPW  = MF;
  constexpr int KC   = CI/32;
  constexpr int KROW = CI*9;
  constexpr int CH8  = CI/8;
  __shared__ u16 TIN[100*PCI];
  int tile = blockIdx.x;
  int b = blockIdx.y;
  int y0 = (tile/5)*8, x0 = (tile%5)*8;
  const u16* inb = in + (size_t)b*1764*CI;
  for (int g = threadIdx.x; g < 100*CH8; g += 256){
    int pix = g/CH8, ch = g - pix*CH8;
    int r = pix/10, cc = pix - r*10;
    us8v vdat = *(const us8v*)(inb + ((size_t)(y0+r)*42 + (x0+cc))*CI + ch*8);
    *(us8v*)(&TIN[pix*PCI + ch*8]) = vdat;
  }
  __syncthreads();
  int w = threadIdx.x>>6, l = threadIdx.x&63;
  int c = l&15, kg = l>>4;
  int mg, f0;
  if (MF==4){ mg = w; f0 = 0; } else { mg = w&1; f0 = (w>>1)*2; }
  int pxb[FPW];
  #pragma unroll
  for (int fi=0; fi<FPW; fi++){
    int px = (f0+fi)*16 + c;
    int ty = px>>3, tx = px&7;
    pxb[fi] = (ty*10 + tx)*PCI + kg*8;
  }
  const u16* wrow = wB + (size_t)(mg*16 + c)*KROW;
  f32x4 acc[FPW];
  #pragma unroll
  for (int fi=0; fi<FPW; fi++) acc[fi] = (f32x4){0.f,0.f,0.f,0.f};
  #pragma unroll
  for (int dy=0;dy<3;dy++)
  #pragma unroll
  for (int dx=0;dx<3;dx++){
    int dydx = dy*3+dx;
    #pragma unroll
    for (int kc=0; kc<KC; kc++){
      bf16x8 af = *(const bf16x8*)(wrow + dydx*CI + kc*32 + kg*8);
      #pragma unroll
      for (int fi=0; fi<FPW; fi++){
        bf16x8 bf = *(const bf16x8*)(&TIN[pxb[fi] + (dy*10+dx)*PCI + kc*32]);
        acc[fi] = __builtin_amdgcn_mfma_f32_16x16x32_bf16(af, bf, acc[fi], 0, 0, 0);
      }
    }
  }
  u16* ob = out + (size_t)b*1764*CO;
  int co0 = mg*16 + kg*4;
  const float4 bia = *(const float4*)(par + co0);
  const float4 sc  = *(const float4*)(par + CO + co0);
  const float4 be  = *(const float4*)(par + 2*CO + co0);
  #pragma unroll
  for (int fi=0; fi<FPW; fi++){
    int px = (f0+fi)*16 + c;
    int y = y0 + (px>>3), x = x0 + (px&7);
    ushort4 s;
    s.x = f2bf(fmaxf(acc[fi][0]+bia.x,0.f)*sc.x + be.x);
    s.y = f2bf(fmaxf(acc[fi][1]+bia.y,0.f)*sc.y + be.y);
    s.z = f2bf(fmaxf(acc[fi][2]+bia.z,0.f)*sc.z + be.z);
    s.w = f2bf(fmaxf(acc[fi][3]+bia.w,0.f)*sc.w + be.w);
    *(ushort4*)(ob + (size_t)((y+1)*42 + (x+1))*CO + co0) = s;
  }
}

// ---------------- conv1 direct 1->32 ----------------
template<int CI, int CO, bool TT>
__global__ __launch_bounds__(256) void conv_main(const u16* __restrict__ in, u16* __restrict__ out,
    const float* __restrict__ w2, const float* __restrict__ par){
  int b = blockIdx.x;
  int wave = threadIdx.x >> 6;
  int lane = threadIdx.x & 63;
  int tile, co;
  if (TT){ tile = blockIdx.y*8 + wave*2 + (lane>>5); co = lane & 31; }
  else   { tile = blockIdx.y*4 + wave;               co = lane; }
  int y0 = (tile >> 3)*5, x0 = (tile & 7)*5;
  const u16* inb = in + (size_t)b*1764*CI;
  float acc[25];
  #pragma unroll
  for (int p=0;p<25;p++) acc[p]=0.f;
  for (int ci=0; ci<CI; ci++){
    float win[49];
    #pragma unroll
    for (int r=0;r<7;r++)
      #pragma unroll
      for (int c=0;c<7;c++)
        win[r*7+c] = bf2f(inb[ ((y0+r)*42 + (x0+c))*CI + ci ]);
    float wk[9];
    #pragma unroll
    for (int k=0;k<9;k++) wk[k] = w2[(ci*9+k)*CO + co];
    #pragma unroll
    for (int py=0;py<5;py++)
      #pragma unroll
      for (int px=0;px<5;px++){
        float s = acc[py*5+px];
        #pragma unroll
        for (int dy=0;dy<3;dy++)
          #pragma unroll
          for (int dx=0;dx<3;dx++)
            s = fmaf(wk[dy*3+dx], win[(py+dy)*7 + (px+dx)], s);
        acc[py*5+px] = s;
      }
  }
  float bia = par[co], sc = par[CO+co], be = par[2*CO+co];
  u16* outb = out + (size_t)b*1764*CO;
  #pragma unroll
  for (int py=0;py<5;py++)
    #pragma unroll
    for (int px=0;px<5;px++){
      float vv = fmaxf(acc[py*5+px] + bia, 0.f)*sc + be;
      outb[ ((y0+py+1)*42 + (x0+px+1))*CO + co ] = f2bf(vv);
    }
}

// ---------------- c6: 32 -> 1 channel ----------------
__global__ __launch_bounds__(256) void conv_c6(const u16* __restrict__ in, u16* __restrict__ y6,
    const float* __restrict__ w6, const float* __restrict__ par6){
  int id = blockIdx.x*256 + threadIdx.x;          // 128*1600
  int b = id/1600, p = id%1600;
  int y = p/40, x = p%40;
  const u16* inb = in + (size_t)b*1764*32;
  float acc = 0.f;
  #pragma unroll
  for (int dy=0;dy<3;dy++)
    #pragma unroll
    for (int dx=0;dx<3;dx++){
      const u16* q = inb + ((y+dy)*42 + (x+dx))*32;
      int k = dy*3+dx;
      #pragma unroll
      for (int g=0; g<4; g++){
        us8v vv8 = *(const us8v*)(q + g*8);
        #pragma unroll
        for (int j=0;j<8;j++)
          acc = fmaf(w6[(g*8+j)*9 + k], bf2f(vv8[j]), acc);
      }
    }
  float vv = fmaxf(acc + par6[0], 0.f)*par6[1] + par6[2];
  y6[(size_t)b*1764 + (y+1)*42 + (x+1)] = f2bf(vv);
}

// ---------------- pc: concat(pre, y6) 2 -> 1, no relu; writes bf16 for gemm3 ----------------
__global__ __launch_bounds__(256) void conv_pc(const u16* __restrict__ p0, const u16* __restrict__ y6,
    const float* __restrict__ pcw, const float* __restrict__ pcb,
    const float* __restrict__ pcg, const float* __restrict__ pcbe,
    u16* __restrict__ o16b){
  int id = blockIdx.x*256 + threadIdx.x;          // 128*1600
  int b = id/1600, p = id%1600;
  int y = p/40, x = p%40;
  float acc = 0.f;
  #pragma unroll
  for (int dy=0;dy<3;dy++)
    #pragma unroll
    for (int dx=0;dx<3;dx++){
      size_t o = (size_t)b*1764 + (y+dy)*42 + (x+dx);
      acc = fmaf(pcw[dy*3+dx],     bf2f(p0[o]), acc);
      acc = fmaf(pcw[9 + dy*3+dx], bf2f(y6[o]), acc);
    }
  float sc = pcg[0] * (1.0f/sqrtf(1.00001f));
  o16b[id] = f2bf((acc + pcb[0])*sc + pcbe[0]);
}

// ---------------- LSTM gating ----------------
__global__ __launch_bounds__(256) void gate_k(const float* __restrict__ whx3, const float* __restrict__ ct,
                                              float* __restrict__ outp){
  int id = blockIdx.x*256 + threadIdx.x;          // 128*300
  if (id >= 38400) return;
  int b = id/300, d = id%300;
  const float* r = whx3 + (size_t)b*1200;
  float ft = 1.f/(1.f+expf(-r[d]));
  float ot = 1.f/(1.f+expf(-r[300+d]));
  float it = 1.f/(1.f+expf(-r[600+d]));
  float ch = tanhf(r[900+d]);
  float c  = ft*ct[id] + it*ch;
  outp[id] = ot*tanhf(c);
}

extern "C" void kernel_launch(void* const* d_in, const int* in_sizes, int n_in,
                              void* d_out, int out_size, void* d_ws, size_t ws_size,
                              hipStream_t stream){
  const float* x    = (const float*)d_in[0];
  const float* hs   = (const float*)d_in[1];
  const float* pht  = (const float*)d_in[2];
  const float* pc   = (const float*)d_in[3];
  const float* W    = (const float*)d_in[4];
  const float* bb   = (const float*)d_in[5];
  const float* Wh   = (const float*)d_in[6];
  const float* Wx   = (const float*)d_in[7];
  const float* Wht  = (const float*)d_in[8];
  const float* v    = (const float*)d_in[9];
  const float* rbw  = (const float*)d_in[10];
  const float* rbb  = (const float*)d_in[11];
  const float* rpw  = (const float*)d_in[12];
  const float* rpb  = (const float*)d_in[13];
  const float *cw[6], *cb[6], *cg[6], *cbe[6];
  for (int i=0;i<6;i++){
    cw[i]=(const float*)d_in[14+4*i]; cb[i]=(const float*)d_in[15+4*i];
    cg[i]=(const float*)d_in[16+4*i]; cbe[i]=(const float*)d_in[17+4*i];
  }
  const float* pcw = (const float*)d_in[38];
  const float* pcb = (const float*)d_in[39];
  const float* pcg = (const float*)d_in[40];
  const float* pcbe= (const float*)d_in[41];

  char* ws = (char*)d_ws;
  float* xw    = (float*)(ws + OFF_XW);
  float* whx2  = (float*)(ws + OFF_WHX2);
  float* whx3  = (float*)(ws + OFF_WHX3);
  float* w21   = (float*)(ws + OFF_W21);
  u16*   wb2   = (u16*)  (ws + OFF_WB2);
  u16*   wb3   = (u16*)  (ws + OFF_WB3);
  u16*   wb4   = (u16*)  (ws + OFF_WB4);
  u16*   wb5   = (u16*)  (ws + OFF_WB5);
  float* w26   = (float*)(ws + OFF_W26);
  u16*   wpack = (u16*)  (ws + OFF_WPACK);
  u16*   wb1g  = (u16*)  (ws + OFF_WB1G);
  u16*   rbwb  = (u16*)  (ws + OFF_RBWB);
  u16*   rpwb  = (u16*)  (ws + OFF_RPWB);
  u16*   catb  = (u16*)  (ws + OFF_CAT);
  u16*   whx1b = (u16*)  (ws + OFF_WHX1B);
  u16*   o16b  = (u16*)  (ws + OFF_O16B);
  float* part  = (float*)(ws + OFF_PART);
  float* parb  = (float*)(ws + OFF_PAR);
  float* ct = (float*)(ws + OFF_CT);
  u16* A32 = (u16*)(ws + OFF_A32);
  u16* B64 = (u16*)(ws + OFF_B64);
  u16* C64 = (u16*)(ws + OFF_C64);
  u16* P0  = (u16*)(ws + OFF_P0);
  u16* Y6  = (u16*)(ws + OFF_Y6);

  RArgs ra;
  for (int i=0;i<6;i++){ ra.cw[i]=cw[i]; ra.cb[i]=cb[i]; ra.cg[i]=cg[i]; ra.cbe[i]=cbe[i]; }
  ra.Wh=Wh; ra.Wht=Wht; ra.Wg=W; ra.rbw=rbw; ra.rpw=rpw;
  ra.w21=w21; ra.w26=w26; ra.par=parb;
  ra.wb2=wb2; ra.wb3=wb3; ra.wb4=wb4; ra.wb5=wb5; ra.wpack=wpack;
  ra.Wb1=wb1g; ra.rbwb=rbwb; ra.rpwb=rpwb;

  // 0) init + repack
  zero_mega<<<165,256,0,stream>>>(P0, Y6, catb);
  mega_repack<<<2048,256,0,stream>>>(ra);

  // 1) fused attention (PART aliases C64; dead before conv3 writes it)
  xw_k<<<1280,64,0,stream>>>(x, Wx, xw);
  attn_fused<<<dim3(32,128),256,0,stream>>>(hs, pht, pc, wpack, v, xw, part);
  attn_reduce<<<128,192,0,stream>>>(part, x, ct, catb);

  // 2) dense layers (MFMA)
  gemm_mfma< 608,true ><<<dim3(76,8), 256,0,stream>>>(1216, 1200, 1216, catb,  wb1g, bb,  whx1b);
  gemm_mfma<1216,false><<<dim3(100,8),256,0,stream>>>(1600, 1600, 1600, whx1b, rbwb, rbb, whx2);
  scat_border<<<2440,256,0,stream>>>(whx2, P0, A32, B64, C64);

  // 3) conv block
  conv_main<1,32,true><<<dim3(128,8),256,0,stream>>>(P0, A32, w21, parb);
  conv_tile<32,64><<<dim3(25,128),256,0,stream>>>(A32, B64, wb2, parb + 192);
  conv_tile<64,64><<<dim3(25,128),256,0,stream>>>(B64, C64, wb3, parb + 384);
  conv_tile<64,64><<<dim3(25,128),256,0,stream>>>(C64, B64, wb4, parb + 576);
  conv_tile<64,32><<<dim3(25,128),256,0,stream>>>(B64, A32, wb5, parb + 768);
  conv_c6<<<800,256,0,stream>>>(A32, Y6, w26, parb + 960);
  conv_pc<<<800,256,0,stream>>>(P0, Y6, pcw, pcb, pcg, pcbe, o16b);

  // 4) final projection + gating
  gemm_mfma<1600,false><<<dim3(75,8),256,0,stream>>>(1200, 1200, 1200, o16b, rpwb, rpb, whx3);
  gate_k<<<150,256,0,stream>>>(whx3, ct, (float*)d_out);
}